// Round 20
// baseline (275.943 us; speedup 1.0000x reference)
//
#include <hip/hip_runtime.h>
#include <hip/hip_bf16.h>
#include <cstdint>

#define S_LEN 2048
#define HIDDEN 2560
#define NH 32
#define NKV 8
#define HD 128
#define GS 128

typedef __attribute__((ext_vector_type(8))) _Float16 half8v;    // 8 x fp16
typedef __attribute__((ext_vector_type(2))) _Float16 half2v;    // 2 x fp16
typedef __attribute__((ext_vector_type(4))) float f32x4;
typedef unsigned int uint;
typedef unsigned short ushort;

__device__ inline ushort f2h(float f) {
    _Float16 h = (_Float16)f;
    return __builtin_bit_cast(ushort, h);
}
__device__ inline float h2f(ushort u) {
    return (float)__builtin_bit_cast(_Float16, u);
}
__device__ inline uint pk2(ushort a, ushort b) { return (uint)a | ((uint)b << 16); }

// async global->LDS, 16B per lane; lds base must be wave-uniform
__device__ __attribute__((always_inline)) inline void gl_lds16(const void* g, void* l) {
    __builtin_amdgcn_global_load_lds(
        (const __attribute__((address_space(1))) unsigned int*)g,
        (__attribute__((address_space(3))) unsigned int*)l, 16, 0, 0);
}

#define WAIT_LGKM0  asm volatile("s_waitcnt lgkmcnt(0)" ::: "memory")
#define WAIT_VM(N)  asm volatile("s_waitcnt vmcnt(" #N ")" ::: "memory")
#define RAW_BARRIER { __builtin_amdgcn_s_barrier(); __builtin_amdgcn_sched_barrier(0); }

// ---------------------------------------------------------------------------
// X -> fp16. One block per row, 320 thr x 8 els.
// ---------------------------------------------------------------------------
__global__ __launch_bounds__(320) void xcvt_kernel(
    const float* __restrict__ X, ushort* __restrict__ Xf)
{
    const int row = blockIdx.x;
    const int t   = threadIdx.x;
    const size_t base = (size_t)row * HIDDEN + t * 8;
    float4 a = *(const float4*)&X[base];
    float4 b = *(const float4*)&X[base + 4];
    uint4 hw = {pk2(f2h(a.x), f2h(a.y)), pk2(f2h(a.z), f2h(a.w)),
                pk2(f2h(b.x), f2h(b.y)), pk2(f2h(b.z), f2h(b.w))};
    *(uint4*)&Xf[base] = hw;
}

// ===========================================================================
// QKV weight dequant prepass (unchanged — verified numerics).
// ===========================================================================
__global__ __launch_bounds__(256) void wdq_kernel(
    const int* __restrict__ q_qw, const float* __restrict__ q_sc, const int* __restrict__ q_qz,
    const int* __restrict__ k_qw, const float* __restrict__ k_sc, const int* __restrict__ k_qz,
    const int* __restrict__ v_qw, const float* __restrict__ v_sc, const int* __restrict__ v_qz,
    ushort* __restrict__ WT)
{
    __shared__ __align__(16) char Ts[16384];

    const int bx = blockIdx.x;
    const int kt = blockIdx.y;
    const int t  = threadIdx.x;

    int nloc0, wtbase, Nw;
    const int* QW; const float* SC; const int* QZ;
    if (bx < 64)      { Nw = NH * HD;  nloc0 = bx * 64;        wtbase = bx * 64;
                        QW = q_qw; SC = q_sc; QZ = q_qz; }
    else if (bx < 80) { Nw = NKV * HD; nloc0 = (bx - 64) * 64; wtbase = 4096 + nloc0;
                        QW = k_qw; SC = k_sc; QZ = k_qz; }
    else              { Nw = NKV * HD; nloc0 = (bx - 80) * 64; wtbase = 5120 + nloc0;
                        QW = v_qw; SC = v_sc; QZ = v_qz; }

    const int k80 = kt * 16;
    const int nn  = t & 63;
    const float scf = SC[(size_t)kt * Nw + nloc0 + nn];
    const float zf  = (float)QZ[(size_t)kt * Nw + nloc0 + nn];
    ushort sch = f2h(scf);
    float schf = h2f(sch);
    ushort msc = f2h(-128.0f * schf);
    ushort nzs = f2h(-(zf * schf));
    half2v S2 = {__builtin_bit_cast(_Float16, sch), __builtin_bit_cast(_Float16, sch)};
    half2v M2 = {__builtin_bit_cast(_Float16, msc), __builtin_bit_cast(_Float16, msc)};
    half2v Z2 = {__builtin_bit_cast(_Float16, nzs), __builtin_bit_cast(_Float16, nzs)};

#pragma unroll
    for (int i = 0; i < 4; ++i) {
        int kw = i * 4 + (t >> 6);
        uint q = (uint)QW[(size_t)(k80 + kw) * Nw + nloc0 + nn];
        uint xn = q & 0x0F0F0F0Fu;
        uint yn = (q >> 4) & 0x0F0F0F0Fu;
        uint W0 = __builtin_amdgcn_perm(yn, xn, 0x0C040C00u);
        uint W1 = __builtin_amdgcn_perm(yn, xn, 0x0C050C01u);
        uint W2 = __builtin_amdgcn_perm(yn, xn, 0x0C060C02u);
        uint W3 = __builtin_amdgcn_perm(yn, xn, 0x0C070C03u);
        uint e0 = (W0 << 3) | 0x58005800u;
        uint e1 = (W1 << 3) | 0x58005800u;
        uint e2 = (W2 << 3) | 0x58005800u;
        uint e3 = (W3 << 3) | 0x58005800u;
        half2v w0 = __builtin_bit_cast(half2v, e0) * S2 + M2; w0 = w0 + Z2;
        half2v w1 = __builtin_bit_cast(half2v, e1) * S2 + M2; w1 = w1 + Z2;
        half2v w2 = __builtin_bit_cast(half2v, e2) * S2 + M2; w2 = w2 + Z2;
        half2v w3 = __builtin_bit_cast(half2v, e3) * S2 + M2; w3 = w3 + Z2;
        uint4 dw = {__builtin_bit_cast(uint, w0), __builtin_bit_cast(uint, w1),
                    __builtin_bit_cast(uint, w2), __builtin_bit_cast(uint, w3)};
        *(uint4*)(Ts + nn * 256 + ((kw * 16) ^ ((nn & 7) << 4))) = dw;
    }
    __syncthreads();
    const int kc = t & 15;
#pragma unroll
    for (int i = 0; i < 4; ++i) {
        int nr = i * 16 + (t >> 4);
        uint4 v = *(const uint4*)(Ts + nr * 256 + ((kc * 16) ^ ((nr & 7) << 4)));
        *(uint4*)&WT[(size_t)(wtbase + nr) * HIDDEN + kt * 128 + kc * 8] = v;
    }
}

// ===========================================================================
// Fused Q/K/V MFMA GEMM on fp16 WT (N-persistent XCD swizzle).
// CHANGE: Q epilogue scale folds log2(e) so attention can use exp2 directly.
// ===========================================================================
__global__ __launch_bounds__(256) void qkv11_kernel(
    const ushort* __restrict__ Xf, const ushort* __restrict__ WT,
    const float* __restrict__ q_b, const float* __restrict__ k_b,
    const float* __restrict__ v_b,
    const float* __restrict__ cosb, const float* __restrict__ sinb,
    ushort* __restrict__ Qf, ushort* __restrict__ Kf,
    ushort* __restrict__ Vrm)
{
    __shared__ __align__(16) char LDSB[65536];
    ushort* A0 = (ushort*)(LDSB);
    ushort* A1 = (ushort*)(LDSB + 16384);
    ushort* B0 = (ushort*)(LDSB + 32768);
    ushort* B1 = (ushort*)(LDSB + 49152);

    const int t  = threadIdx.x;
    const int w  = t >> 6;
    const int l  = t & 63;
    const int lg = l >> 4;
    const int lr = l & 15;
    const int wr = w >> 1;
    const int wc = w & 1;
    const int K  = HIDDEN;

    const int bid  = blockIdx.x;
    const int xcd  = bid & 7;
    const int j    = bid >> 3;
    const int nblk = xcd * 6 + (j >> 4);
    const int m0   = (j & 15) * 128;
    const int wtrow = nblk * 128;

    int region, nbase;
    const float* BI;
    if (nblk < 32)      { region = 0; nbase = nblk * 128;        BI = q_b; }
    else if (nblk < 40) { region = 1; nbase = (nblk - 32) * 128; BI = k_b; }
    else                { region = 2; nbase = (nblk - 40) * 128; BI = v_b; }

    const int ldsAw = w * 1024;
    size_t aoff[4], boff[4];
#pragma unroll
    for (int i = 0; i < 4; ++i) {
        int slot = i * 256 + t;
        int rm = slot >> 3, rc = slot & 7;
        aoff[i] = (size_t)(m0 + rm) * K + (size_t)((rc ^ (rm & 7)) * 8);
        boff[i] = (size_t)(wtrow + rm) * K + (size_t)((rc ^ (rm & 7)) * 8);
    }

    int ncm[4];
#pragma unroll
    for (int nf = 0; nf < 4; ++nf)
        ncm[nf] = wc * 32 + (nf & 1) * 16 + lr + ((nf & 2) ? 64 : 0);

    const int xorA = (lr & 7) << 4;
    int aroff[4][2], broff[4][2];
#pragma unroll
    for (int mf = 0; mf < 4; ++mf)
#pragma unroll
        for (int ks = 0; ks < 2; ++ks)
            aroff[mf][ks] = (((wr * 64 + mf * 16 + lr) * 128) + lg * 16 + ks * 64) ^ xorA;
#pragma unroll
    for (int nf = 0; nf < 4; ++nf)
#pragma unroll
        for (int ks = 0; ks < 2; ++ks)
            broff[nf][ks] = ((ncm[nf] * 128) + lg * 16 + ks * 64) ^ xorA;

    f32x4 macc[4][4];
#pragma unroll
    for (int mf = 0; mf < 4; ++mf)
#pragma unroll
        for (int nf = 0; nf < 4; ++nf) macc[mf][nf] = f32x4{0.f, 0.f, 0.f, 0.f};

#define QKV_STAGE(AH, BH, k0) { \
    gl_lds16(Xf + (k0) + aoff[0], (char*)(AH) + ldsAw); \
    gl_lds16(Xf + (k0) + aoff[1], (char*)(AH) + 4096 + ldsAw); \
    gl_lds16(Xf + (k0) + aoff[2], (char*)(AH) + 8192 + ldsAw); \
    gl_lds16(Xf + (k0) + aoff[3], (char*)(AH) + 12288 + ldsAw); \
    gl_lds16(WT + (k0) + boff[0], (char*)(BH) + ldsAw); \
    gl_lds16(WT + (k0) + boff[1], (char*)(BH) + 4096 + ldsAw); \
    gl_lds16(WT + (k0) + boff[2], (char*)(BH) + 8192 + ldsAw); \
    gl_lds16(WT + (k0) + boff[3], (char*)(BH) + 12288 + ldsAw); }

#define QKV_COMPUTE(AH, BT) { \
    _Pragma("unroll") \
    for (int ks = 0; ks < 2; ++ks) { \
        half8v av[4], bv[4]; \
        _Pragma("unroll") \
        for (int mf = 0; mf < 4; ++mf) \
            av[mf] = *(const half8v*)((const char*)(AH) + aroff[mf][ks]); \
        _Pragma("unroll") \
        for (int nf = 0; nf < 4; ++nf) \
            bv[nf] = *(const half8v*)((const char*)(BT) + broff[nf][ks]); \
        _Pragma("unroll") \
        for (int mf = 0; mf < 4; ++mf) \
            _Pragma("unroll") \
            for (int nf = 0; nf < 4; ++nf) \
                macc[mf][nf] = __builtin_amdgcn_mfma_f32_16x16x32_f16(av[mf], bv[nf], macc[mf][nf], 0, 0, 0); \
    } }

    QKV_STAGE(A0, B0, 0);
    WAIT_VM(0);
    RAW_BARRIER;

    for (int g = 0; g < 19; ++g) {
        QKV_STAGE(A1, B1, (2 * g + 1) * 64);
        QKV_COMPUTE(A0, B0);
        WAIT_VM(0);
        RAW_BARRIER;
        QKV_STAGE(A0, B0, (2 * g + 2) * 64);
        QKV_COMPUTE(A1, B1);
        WAIT_VM(0);
        RAW_BARRIER;
    }
    QKV_STAGE(A1, B1, 39 * 64);
    QKV_COMPUTE(A0, B0);
    WAIT_VM(0);
    RAW_BARRIER;
    QKV_COMPUTE(A1, B1);

#pragma unroll
    for (int nf = 0; nf < 4; ++nf) {
        float bv = BI[nbase + ncm[nf]];
#pragma unroll
        for (int mf = 0; mf < 4; ++mf)
#pragma unroll
            for (int r = 0; r < 4; ++r) macc[mf][nf][r] += bv;
    }

    if (region == 2) {
#pragma unroll
        for (int mf = 0; mf < 4; ++mf)
#pragma unroll
            for (int r = 0; r < 4; ++r) {
                int row = m0 + wr * 64 + mf * 16 + lg * 4 + r;
#pragma unroll
                for (int nf = 0; nf < 4; ++nf)
                    Vrm[(size_t)row * (NKV * HD) + nbase + ncm[nf]] = f2h(macc[mf][nf][r]);
            }
    } else {
        ushort* OF = (region == 0) ? Qf : Kf;
        const int No = (region == 0) ? NH * HD : NKV * HD;
        // Q scale folds 1/sqrt(HD) AND log2(e) -> attention uses exp2 directly
        const float osc = (region == 0)
            ? 0.08838834764831845f * 1.44269504088896341f : 1.0f;
#pragma unroll
        for (int mf = 0; mf < 4; ++mf)
#pragma unroll
            for (int r = 0; r < 4; ++r) {
                int row = m0 + wr * 64 + mf * 16 + lg * 4 + r;
                const float* cb = &cosb[(size_t)row * HD];
                const float* sb = &sinb[(size_t)row * HD];
#pragma unroll
                for (int nf = 0; nf < 2; ++nf) {
                    int d = wc * 32 + nf * 16 + lr;
                    float a = macc[mf][nf][r];
                    float b = macc[mf][nf + 2][r];
                    float o1 = (a * cb[d]      - b * sb[d])      * osc;
                    float o2 = (b * cb[d + 64] + a * sb[d + 64]) * osc;
                    OF[(size_t)row * No + nbase + d]      = f2h(o1);
                    OF[(size_t)row * No + nbase + d + 64] = f2h(o2);
                }
            }
    }
#undef QKV_STAGE
#undef QKV_COMPUTE
}

// ---------------------------------------------------------------------------
// V transpose (unchanged).
// ---------------------------------------------------------------------------
__global__ __launch_bounds__(256) void vtrans_kernel(
    const ushort* __restrict__ Vrm, ushort* __restrict__ VfT)
{
    __shared__ ushort Ts[64][65];
    const int s0 = blockIdx.x * 64;
    const int n0 = blockIdx.y * 64;
    const int t  = threadIdx.x;
    {
        int r = t >> 2, c0 = (t & 3) * 16;
        uint4 v0 = *(const uint4*)&Vrm[(size_t)(s0 + r) * (NKV * HD) + n0 + c0];
        uint4 v1 = *(const uint4*)&Vrm[(size_t)(s0 + r) * (NKV * HD) + n0 + c0 + 8];
        const ushort* pv = (const ushort*)&v0;
#pragma unroll
        for (int j = 0; j < 8; ++j) Ts[r][c0 + j] = pv[j];
        pv = (const ushort*)&v1;
#pragma unroll
        for (int j = 0; j < 8; ++j) Ts[r][c0 + 8 + j] = pv[j];
    }
    __syncthreads();
    {
        int rn = t >> 2, cs0 = (t & 3) * 16;
        ushort ob[16];
#pragma unroll
        for (int j = 0; j < 16; ++j) ob[j] = Ts[cs0 + j][rn];
        ushort* dst = &VfT[(size_t)(n0 + rn) * S_LEN + s0 + cs0];
        *(uint4*)dst = ((uint4*)ob)[0];
        *(uint4*)(dst + 8) = ((uint4*)ob)[1];
    }
}

// ===========================================================================
// O-projection (unchanged — control).
// ===========================================================================
__global__ __launch_bounds__(256) void oproj8_kernel(
    const ushort* __restrict__ Xb, const int* __restrict__ QW,
    const float* __restrict__ SC, const int* __restrict__ QZ,
    float* __restrict__ Y)
{
    __shared__ __align__(16) char LDSB[65536];
    ushort* A0 = (ushort*)(LDSB);
    ushort* A1 = (ushort*)(LDSB + 16384);
    ushort* B0 = (ushort*)(LDSB + 32768);
    ushort* B1 = (ushort*)(LDSB + 49152);

    const int t  = threadIdx.x;
    const int w  = t >> 6;
    const int l  = t & 63;
    const int lg = l >> 4;
    const int lr = l & 15;
    const int wr = w >> 1;
    const int wc = w & 1;
    const int K  = NH * HD;
    const int N  = HIDDEN;

    const int bid = blockIdx.x;
    const int swz = (bid & 7) * 40 + (bid >> 3);
    const int n0  = (swz % 20) * 128;
    const int m0  = (swz / 20) * 128;

    const int ldsAw = w * 1024;
    size_t aoff[4];
#pragma unroll
    for (int i = 0; i < 4; ++i) {
        int slot = i * 256 + t;
        int am = slot >> 3, ac = slot & 7;
        aoff[i] = (size_t)(m0 + am) * K + (size_t)((ac ^ (am & 7)) * 8);
    }
    const int bn  = t & 127;
    const int bk0 = (t >> 7) * 4;
    int bwoff[4];
#pragma unroll
    for (int j = 0; j < 4; ++j)
        bwoff[j] = (bn * 128 + (bk0 + j) * 16) ^ ((bn & 7) << 4);

    const int xorA = (lr & 7) << 4;
    int aroff[4][2], broff[4][2];
#pragma unroll
    for (int mf = 0; mf < 4; ++mf)
#pragma unroll
        for (int ks = 0; ks < 2; ++ks)
            aroff[mf][ks] = (((wr * 64 + mf * 16 + lr) * 128) + lg * 16 + ks * 64) ^ xorA;
#pragma unroll
    for (int nf = 0; nf < 4; ++nf)
#pragma unroll
        for (int ks = 0; ks < 2; ++ks)
            broff[nf][ks] = (((wc * 64 + nf * 16 + lr) * 128) + lg * 16 + ks * 64) ^ xorA;

    f32x4 macc[4][4];
#pragma unroll
    for (int mf = 0; mf < 4; ++mf)
#pragma unroll
        for (int nf = 0; nf < 4; ++nf) macc[mf][nf] = f32x4{0.f, 0.f, 0.f, 0.f};
    uint qr[4];
    float scf, zf;

#define OP_QW(tile) { int g8 = (tile) * 8; int gg = (tile) >> 1; \
    _Pragma("unroll") \
    for (int j = 0; j < 4; ++j) \
        qr[j] = (uint)QW[(size_t)(g8 + bk0 + j) * N + n0 + bn]; \
    scf = SC[(size_t)gg * N + n0 + bn]; \
    zf  = (float)QZ[(size_t)gg * N + n0 + bn]; }

#define OP_STAGE_A(AH, k0) { \
    gl_lds16(Xb + (k0) + aoff[0], (char*)(AH) + ldsAw); \
    gl_lds16(Xb + (k0) + aoff[1], (char*)(AH) + 4096 + ldsAw); \
    gl_lds16(Xb + (k0) + aoff[2], (char*)(AH) + 8192 + ldsAw); \
    gl_lds16(Xb + (k0) + aoff[3], (char*)(AH) + 12288 + ldsAw); }

#define OP_BWRITE(BT) { \
    ushort sch = f2h(scf); \
    float schf = h2f(sch); \
    ushort msc = f2h(-128.0f * schf); \
    ushort nzs = f2h(-(zf * schf)); \
    half2v S2 = {__builtin_bit_cast(_Float16, sch), __builtin_bit_cast(_Float16, sch)}; \
    half2v M2 = {__builtin_bit_cast(_Float16, msc), __builtin_bit_cast(_Float16, msc)}; \
    half2v Z2 = {__builtin_bit_cast(_Float16, nzs), __builtin_bit_cast(_Float16, nzs)}; \
    _Pragma("unroll") \
    for (int j = 0; j < 4; ++j) { \
        uint q = qr[j]; \
        uint xn = q & 0x0F0F0F0Fu; \
        uint yn = (q >> 4) & 0x0F0F0F0Fu; \
        uint4 dw; \
        uint W0 = __builtin_amdgcn_perm(yn, xn, 0x0C040C00u); \
        uint W1 = __builtin_amdgcn_perm(yn, xn, 0x0C050C01u); \
        uint W2 = __builtin_amdgcn_perm(yn, xn, 0x0C060C02u); \
        uint W3 = __builtin_amdgcn_perm(yn, xn, 0x0C070C03u); \
        uint e0 = (W0 << 3) | 0x58005800u; \
        uint e1 = (W1 << 3) | 0x58005800u; \
        uint e2 = (W2 << 3) | 0x58005800u; \
        uint e3 = (W3 << 3) | 0x58005800u; \
        half2v w0 = __builtin_bit_cast(half2v, e0) * S2 + M2; w0 = w0 + Z2; \
        half2v w1 = __builtin_bit_cast(half2v, e1) * S2 + M2; w1 = w1 + Z2; \
        half2v w2 = __builtin_bit_cast(half2v, e2) * S2 + M2; w2 = w2 + Z2; \
        half2v w3 = __builtin_bit_cast(half2v, e3) * S2 + M2; w3 = w3 + Z2; \
        dw.x = __builtin_bit_cast(uint, w0); \
        dw.y = __builtin_bit_cast(uint, w1); \
        dw.z = __builtin_bit_cast(uint, w2); \
        dw.w = __builtin_bit_cast(uint, w3); \
        *(uint4*)((char*)(BT) + bwoff[j]) = dw; \
    } }

#define OP_COMPUTE(AH, BT) { \
    _Pragma("unroll") \
    for (int ks = 0; ks < 2; ++ks) { \
        half8v av[4], bv[4]; \
        _Pragma("unroll") \
        for (int mf = 0; mf < 4; ++mf) \
            av[mf] = *(const half8v*)((const char*)(AH) + aroff[mf][ks]); \
        _Pragma("unroll") \
        for (int nf = 0; nf < 4; ++nf) \
            bv[nf] = *(const half8v*)((const char*)(BT) + broff[nf][ks]); \
        _Pragma("unroll") \
        for (int mf = 0; mf < 4; ++mf) \
            _Pragma("unroll") \
            for (int nf = 0; nf < 4; ++nf) \
                macc[mf][nf] = __builtin_amdgcn_mfma_f32_16x16x32_f16(av[mf], bv[nf], macc[mf][nf], 0, 0, 0); \
    } }

    OP_QW(0);
    OP_BWRITE(B0);
    OP_STAGE_A(A0, 0);
    OP_QW(1);
    WAIT_LGKM0;
    WAIT_VM(6);
    RAW_BARRIER;

    for (int g = 0; g < 31; ++g) {
        OP_STAGE_A(A1, (2 * g + 1) * 64);
        OP_COMPUTE(A0, B0);
        OP_BWRITE(B1);
        OP_QW(2 * g + 2);
        WAIT_LGKM0;
        WAIT_VM(6);
        RAW_BARRIER;
        OP_STAGE_A(A0, (2 * g + 2) * 64);
        OP_COMPUTE(A1, B1);
        OP_BWRITE(B0);
        OP_QW(2 * g + 3);
        WAIT_LGKM0;
        WAIT_VM(6);
        RAW_BARRIER;
    }
    OP_STAGE_A(A1, 63 * 64);
    OP_COMPUTE(A0, B0);
    OP_BWRITE(B1);
    WAIT_LGKM0;
    WAIT_VM(0);
    RAW_BARRIER;
    OP_COMPUTE(A1, B1);

#pragma unroll
    for (int mf = 0; mf < 4; ++mf)
#pragma unroll
        for (int r = 0; r < 4; ++r) {
            int row = m0 + wr * 64 + mf * 16 + lg * 4 + r;
#pragma unroll
            for (int nf = 0; nf < 4; ++nf)
                Y[(size_t)row * N + n0 + wc * 64 + nf * 16 + lr] = macc[mf][nf][r];
        }
#undef OP_QW
#undef OP_STAGE_A
#undef OP_BWRITE
#undef OP_COMPUTE
}

// ---------------------------------------------------------------------------
// Causal GQA flash attention, fp16 MFMA, swapped operands; dbuf K/V staging.
// NEW: (1) band-pairing for perfect load balance — block y handles q-band
// blockIdx.y and band 31-blockIdx.y sequentially (66 tiles every block);
// (2) exp2-based softmax (Q pre-scaled by log2e in qkv epilogue).
// ---------------------------------------------------------------------------
__global__ __launch_bounds__(256) void attn_mfma_kernel(
    const ushort* __restrict__ Qh,   // [S][NH*HD] fp16, roped, *log2e/sqrt(HD)
    const ushort* __restrict__ Kh,   // [S][NKV*HD] fp16, roped
    const ushort* __restrict__ Vt,   // [NKV*HD][S] fp16 (transposed)
    ushort* __restrict__ AO)         // [S][NH*HD] fp16
{
    __shared__ ushort Ks0[32 * 128];           // swz ^((row&7)<<4)
    __shared__ ushort Ks1[32 * 128];
    __shared__ ushort Vs0[128 * 32];           // swz ^(((dim>>1)&3)<<4)
    __shared__ ushort Vs1[128 * 32];
    __shared__ __align__(16) char PsB[4 * 1280];  // P: 16 rows x 80B per wave

    const int h  = blockIdx.x;
    const int t  = threadIdx.x;
    const int w  = t >> 6;
    const int l  = t & 63;
    const int lg = l >> 4;
    const int lr = l & 15;
    const int kvh = h >> 2;
    char* pw = PsB + w * 1280;

#define ATTN_STAGE(KB, VB, k0) { \
    _Pragma("unroll") \
    for (int i = 0; i < 2; ++i) { \
        int slot = w * 128 + i * 64 + l; \
        int mr = slot >> 4, c = slot & 15; \
        size_t goff = (size_t)((k0) + mr) * (NKV * HD) + kvh * HD + ((c ^ (mr & 7)) * 8); \
        gl_lds16(Kh + goff, (char*)(KB) + (w * 128 + i * 64) * 16); \
    } \
    _Pragma("unroll") \
    for (int i = 0; i < 2; ++i) { \
        int slot = w * 128 + i * 64 + l; \
        int dim = slot >> 2, c = slot & 3; \
        size_t goff = (size_t)(kvh * HD + dim) * S_LEN + (k0) + ((c ^ ((dim >> 1) & 3)) * 8); \
        gl_lds16(Vt + goff, (char*)(VB) + (w * 128 + i * 64) * 16); \
    } }

#define ATTN_TILE(KSF, VSS, k0) \
    if ((k0) <= qw + 15) { \
        f32x4 s_[2]; \
        s_[0] = f32x4{0.f, 0.f, 0.f, 0.f}; \
        s_[1] = f32x4{0.f, 0.f, 0.f, 0.f}; \
        _Pragma("unroll") \
        for (int d = 0; d < 4; ++d) { \
            _Pragma("unroll") \
            for (int nt2 = 0; nt2 < 2; ++nt2) { \
                int row = nt2 * 16 + lr; \
                int off = row * 256 + ((d * 64 + lg * 16) ^ ((row & 7) << 4)); \
                half8v kf = *(const half8v*)((const char*)(KSF) + off); \
                s_[nt2] = __builtin_amdgcn_mfma_f32_16x16x32_f16(kf, qf[d], s_[nt2], 0, 0, 0); \
            } \
        } \
        float sv[8]; \
        _Pragma("unroll") \
        for (int nt2 = 0; nt2 < 2; ++nt2) \
            _Pragma("unroll") \
            for (int r = 0; r < 4; ++r) { \
                int kv = (k0) + nt2 * 16 + lg * 4 + r; \
                sv[nt2 * 4 + r] = (kv <= q) ? s_[nt2][r] : -1e30f; \
            } \
        float mx = sv[0]; \
        _Pragma("unroll") \
        for (int j = 1; j < 8; ++j) mx = fmaxf(mx, sv[j]); \
        mx = fmaxf(mx, __shfl_xor(mx, 16)); \
        mx = fmaxf(mx, __shfl_xor(mx, 32)); \
        float mnew = fmaxf(m, mx); \
        float resc = exp2f(m - mnew); \
        m = mnew; \
        float p_[8], ps = 0.f; \
        _Pragma("unroll") \
        for (int j = 0; j < 8; ++j) { p_[j] = exp2f(sv[j] - mnew); ps += p_[j]; } \
        ps += __shfl_xor(ps, 16); \
        ps += __shfl_xor(ps, 32); \
        lsum = lsum * resc + ps; \
        _Pragma("unroll") \
        for (int dt = 0; dt < 8; ++dt) \
            _Pragma("unroll") \
            for (int r = 0; r < 4; ++r) o[dt][r] *= resc; \
        uint2 w0_ = {pk2(f2h(p_[0]), f2h(p_[1])), pk2(f2h(p_[2]), f2h(p_[3]))}; \
        uint2 w1_ = {pk2(f2h(p_[4]), f2h(p_[5])), pk2(f2h(p_[6]), f2h(p_[7]))}; \
        *(uint2*)(pw + lr * 80 + lg * 8)      = w0_; \
        *(uint2*)(pw + lr * 80 + 32 + lg * 8) = w1_; \
        asm volatile("s_waitcnt lgkmcnt(0)" ::: "memory"); \
        half8v pf = *(const half8v*)(pw + lr * 80 + lg * 16); \
        _Pragma("unroll") \
        for (int dt = 0; dt < 8; ++dt) { \
            int dim = dt * 16 + lr; \
            half8v vf = *(const half8v*)((const char*)(VSS) + dim * 64 + ((lg * 16) ^ (((dim >> 1) & 3) << 4))); \
            o[dt] = __builtin_amdgcn_mfma_f32_16x16x32_f16(vf, pf, o[dt], 0, 0, 0); \
        } \
    }

#pragma unroll 1
    for (int pass = 0; pass < 2; ++pass) {
        const int qb = (pass == 0) ? (int)blockIdx.y : 31 - (int)blockIdx.y;
        const int s0 = qb * 64;
        const int qw = s0 + w * 16;
        const int q  = qw + lr;          // this lane's q-row

        half8v qf[4];
#pragma unroll
        for (int d = 0; d < 4; ++d) {
            size_t off = (size_t)q * (NH * HD) + h * HD + d * 32 + lg * 8;
            qf[d] = *(const half8v*)&Qh[off];
        }

        f32x4 o[8];
#pragma unroll
        for (int i = 0; i < 8; ++i) o[i] = f32x4{0.f, 0.f, 0.f, 0.f};
        float m = -1e30f, lsum = 0.f;

        const int ntiles = qb * 2 + 2;   // always even

        ATTN_STAGE(Ks0, Vs0, 0);
        WAIT_VM(0);
        RAW_BARRIER;

        for (int kt = 0; kt < ntiles; kt += 2) {
            if (kt + 1 < ntiles) ATTN_STAGE(Ks1, Vs1, (kt + 1) * 32);
            ATTN_TILE(Ks0, Vs0, kt * 32);
            WAIT_VM(0);
            RAW_BARRIER;
            if (kt + 2 < ntiles) ATTN_STAGE(Ks0, Vs0, (kt + 2) * 32);
            ATTN_TILE(Ks1, Vs1, (kt + 1) * 32);
            WAIT_VM(0);
            RAW_BARRIER;
        }

        float inv = 1.f / lsum;
        ushort* dst = &AO[(size_t)q * (NH * HD) + h * HD];
#pragma unroll
        for (int dt = 0; dt < 8; ++dt) {
            uint2 ov = {pk2(f2h(o[dt][0] * inv), f2h(o[dt][1] * inv)),
                        pk2(f2h(o[dt][2] * inv), f2h(o[dt][3] * inv))};
            *(uint2*)(dst + dt * 16 + lg * 4) = ov;
        }
    }
#undef ATTN_STAGE
#undef ATTN_TILE
}

// ---------------------------------------------------------------------------
extern "C" void kernel_launch(void* const* d_in, const int* in_sizes, int n_in,
                              void* d_out, int out_size, void* d_ws, size_t ws_size,
                              hipStream_t stream)
{
    const float* x    = (const float*)d_in[0];
    const float* cosb = (const float*)d_in[1];
    const float* sinb = (const float*)d_in[2];
    const float* q_sc = (const float*)d_in[3];
    const float* q_b  = (const float*)d_in[4];
    const float* k_sc = (const float*)d_in[5];
    const float* k_b  = (const float*)d_in[6];
    const float* v_sc = (const float*)d_in[7];
    const float* v_b  = (const float*)d_in[8];
    const float* o_sc = (const float*)d_in[9];
    const int* q_qw   = (const int*)d_in[10];
    const int* q_qz   = (const int*)d_in[11];
    const int* k_qw   = (const int*)d_in[12];
    const int* k_qz   = (const int*)d_in[13];
    const int* v_qw   = (const int*)d_in[14];
    const int* v_qz   = (const int*)d_in[15];
    const int* o_qw   = (const int*)d_in[16];
    const int* o_qz   = (const int*)d_in[17];
    float* out = (float*)d_out;

    // ws layout (MB):
    //   0..10   Xf16   [AOf16 (16MB) aliases 0..16 after qkv11]
    //   10..40  WT fp16 [6144][2560]  (dead after qkv11)
    //   40..56  Qf | 56..60 Kf | 60..64 Vrm | 64..68 VfT
    char* ws = (char*)d_ws;
    ushort* Xf   = (ushort*)ws;
    ushort* AOf  = (ushort*)ws;                                  // alias
    ushort* WT   = (ushort*)(ws + (size_t)10 * 1024 * 1024);
    ushort* Qf   = (ushort*)(ws + (size_t)40 * 1024 * 1024);
    ushort* Kf   = (ushort*)(ws + (size_t)56 * 1024 * 1024);
    ushort* Vrm  = (ushort*)(ws + (size_t)60 * 1024 * 1024);
    ushort* VfT  = (ushort*)(ws + (size_t)64 * 1024 * 1024);

    xcvt_kernel<<<S_LEN, 320, 0, stream>>>(x, Xf);

    wdq_kernel<<<dim3(96, 20), 256, 0, stream>>>(
        q_qw, q_sc, q_qz, k_qw, k_sc, k_qz, v_qw, v_sc, v_qz, WT);

    qkv11_kernel<<<768, 256, 0, stream>>>(
        Xf, WT, q_b, k_b, v_b, cosb, sinb, Qf, Kf, Vrm);

    vtrans_kernel<<<dim3(S_LEN / 64, (NKV * HD) / 64), 256, 0, stream>>>(Vrm, VfT);

    attn_mfma_kernel<<<dim3(NH, 16), 256, 0, stream>>>(Qf, Kf, VfT, AOf);

    oproj8_kernel<<<320, 256, 0, stream>>>(
        AOf, o_qw, o_sc, o_qz, out);
}

// Round 21
// 265.330 us; speedup vs baseline: 1.0400x; 1.0400x over previous
//
#include <hip/hip_runtime.h>
#include <hip/hip_bf16.h>
#include <cstdint>

#define S_LEN 2048
#define HIDDEN 2560
#define NH 32
#define NKV 8
#define HD 128
#define GS 128

typedef __attribute__((ext_vector_type(8))) _Float16 half8v;    // 8 x fp16
typedef __attribute__((ext_vector_type(2))) _Float16 half2v;    // 2 x fp16
typedef __attribute__((ext_vector_type(4))) float f32x4;
typedef unsigned int uint;
typedef unsigned short ushort;

__device__ inline ushort f2h(float f) {
    _Float16 h = (_Float16)f;
    return __builtin_bit_cast(ushort, h);
}
__device__ inline float h2f(ushort u) {
    return (float)__builtin_bit_cast(_Float16, u);
}
__device__ inline uint pk2(ushort a, ushort b) { return (uint)a | ((uint)b << 16); }

// async global->LDS, 16B per lane; lds base must be wave-uniform
__device__ __attribute__((always_inline)) inline void gl_lds16(const void* g, void* l) {
    __builtin_amdgcn_global_load_lds(
        (const __attribute__((address_space(1))) unsigned int*)g,
        (__attribute__((address_space(3))) unsigned int*)l, 16, 0, 0);
}

#define WAIT_LGKM0  asm volatile("s_waitcnt lgkmcnt(0)" ::: "memory")
#define WAIT_VM(N)  asm volatile("s_waitcnt vmcnt(" #N ")" ::: "memory")
#define RAW_BARRIER { __builtin_amdgcn_s_barrier(); __builtin_amdgcn_sched_barrier(0); }

// ---------------------------------------------------------------------------
// X -> fp16. One block per row, 320 thr x 8 els.
// ---------------------------------------------------------------------------
__global__ __launch_bounds__(320) void xcvt_kernel(
    const float* __restrict__ X, ushort* __restrict__ Xf)
{
    const int row = blockIdx.x;
    const int t   = threadIdx.x;
    const size_t base = (size_t)row * HIDDEN + t * 8;
    float4 a = *(const float4*)&X[base];
    float4 b = *(const float4*)&X[base + 4];
    uint4 hw = {pk2(f2h(a.x), f2h(a.y)), pk2(f2h(a.z), f2h(a.w)),
                pk2(f2h(b.x), f2h(b.y)), pk2(f2h(b.z), f2h(b.w))};
    *(uint4*)&Xf[base] = hw;
}

// ===========================================================================
// QKV weight dequant prepass (unchanged — verified numerics).
// ===========================================================================
__global__ __launch_bounds__(256) void wdq_kernel(
    const int* __restrict__ q_qw, const float* __restrict__ q_sc, const int* __restrict__ q_qz,
    const int* __restrict__ k_qw, const float* __restrict__ k_sc, const int* __restrict__ k_qz,
    const int* __restrict__ v_qw, const float* __restrict__ v_sc, const int* __restrict__ v_qz,
    ushort* __restrict__ WT)
{
    __shared__ __align__(16) char Ts[16384];

    const int bx = blockIdx.x;
    const int kt = blockIdx.y;
    const int t  = threadIdx.x;

    int nloc0, wtbase, Nw;
    const int* QW; const float* SC; const int* QZ;
    if (bx < 64)      { Nw = NH * HD;  nloc0 = bx * 64;        wtbase = bx * 64;
                        QW = q_qw; SC = q_sc; QZ = q_qz; }
    else if (bx < 80) { Nw = NKV * HD; nloc0 = (bx - 64) * 64; wtbase = 4096 + nloc0;
                        QW = k_qw; SC = k_sc; QZ = k_qz; }
    else              { Nw = NKV * HD; nloc0 = (bx - 80) * 64; wtbase = 5120 + nloc0;
                        QW = v_qw; SC = v_sc; QZ = v_qz; }

    const int k80 = kt * 16;
    const int nn  = t & 63;
    const float scf = SC[(size_t)kt * Nw + nloc0 + nn];
    const float zf  = (float)QZ[(size_t)kt * Nw + nloc0 + nn];
    ushort sch = f2h(scf);
    float schf = h2f(sch);
    ushort msc = f2h(-128.0f * schf);
    ushort nzs = f2h(-(zf * schf));
    half2v S2 = {__builtin_bit_cast(_Float16, sch), __builtin_bit_cast(_Float16, sch)};
    half2v M2 = {__builtin_bit_cast(_Float16, msc), __builtin_bit_cast(_Float16, msc)};
    half2v Z2 = {__builtin_bit_cast(_Float16, nzs), __builtin_bit_cast(_Float16, nzs)};

#pragma unroll
    for (int i = 0; i < 4; ++i) {
        int kw = i * 4 + (t >> 6);
        uint q = (uint)QW[(size_t)(k80 + kw) * Nw + nloc0 + nn];
        uint xn = q & 0x0F0F0F0Fu;
        uint yn = (q >> 4) & 0x0F0F0F0Fu;
        uint W0 = __builtin_amdgcn_perm(yn, xn, 0x0C040C00u);
        uint W1 = __builtin_amdgcn_perm(yn, xn, 0x0C050C01u);
        uint W2 = __builtin_amdgcn_perm(yn, xn, 0x0C060C02u);
        uint W3 = __builtin_amdgcn_perm(yn, xn, 0x0C070C03u);
        uint e0 = (W0 << 3) | 0x58005800u;
        uint e1 = (W1 << 3) | 0x58005800u;
        uint e2 = (W2 << 3) | 0x58005800u;
        uint e3 = (W3 << 3) | 0x58005800u;
        half2v w0 = __builtin_bit_cast(half2v, e0) * S2 + M2; w0 = w0 + Z2;
        half2v w1 = __builtin_bit_cast(half2v, e1) * S2 + M2; w1 = w1 + Z2;
        half2v w2 = __builtin_bit_cast(half2v, e2) * S2 + M2; w2 = w2 + Z2;
        half2v w3 = __builtin_bit_cast(half2v, e3) * S2 + M2; w3 = w3 + Z2;
        uint4 dw = {__builtin_bit_cast(uint, w0), __builtin_bit_cast(uint, w1),
                    __builtin_bit_cast(uint, w2), __builtin_bit_cast(uint, w3)};
        *(uint4*)(Ts + nn * 256 + ((kw * 16) ^ ((nn & 7) << 4))) = dw;
    }
    __syncthreads();
    const int kc = t & 15;
#pragma unroll
    for (int i = 0; i < 4; ++i) {
        int nr = i * 16 + (t >> 4);
        uint4 v = *(const uint4*)(Ts + nr * 256 + ((kc * 16) ^ ((nr & 7) << 4)));
        *(uint4*)&WT[(size_t)(wtbase + nr) * HIDDEN + kt * 128 + kc * 8] = v;
    }
}

// ===========================================================================
// Fused Q/K/V MFMA GEMM on fp16 WT (N-persistent XCD swizzle).
// Q epilogue scale folds log2(e) so attention can use exp2 directly.
// ===========================================================================
__global__ __launch_bounds__(256) void qkv11_kernel(
    const ushort* __restrict__ Xf, const ushort* __restrict__ WT,
    const float* __restrict__ q_b, const float* __restrict__ k_b,
    const float* __restrict__ v_b,
    const float* __restrict__ cosb, const float* __restrict__ sinb,
    ushort* __restrict__ Qf, ushort* __restrict__ Kf,
    ushort* __restrict__ Vrm)
{
    __shared__ __align__(16) char LDSB[65536];
    ushort* A0 = (ushort*)(LDSB);
    ushort* A1 = (ushort*)(LDSB + 16384);
    ushort* B0 = (ushort*)(LDSB + 32768);
    ushort* B1 = (ushort*)(LDSB + 49152);

    const int t  = threadIdx.x;
    const int w  = t >> 6;
    const int l  = t & 63;
    const int lg = l >> 4;
    const int lr = l & 15;
    const int wr = w >> 1;
    const int wc = w & 1;
    const int K  = HIDDEN;

    const int bid  = blockIdx.x;
    const int xcd  = bid & 7;
    const int j    = bid >> 3;
    const int nblk = xcd * 6 + (j >> 4);
    const int m0   = (j & 15) * 128;
    const int wtrow = nblk * 128;

    int region, nbase;
    const float* BI;
    if (nblk < 32)      { region = 0; nbase = nblk * 128;        BI = q_b; }
    else if (nblk < 40) { region = 1; nbase = (nblk - 32) * 128; BI = k_b; }
    else                { region = 2; nbase = (nblk - 40) * 128; BI = v_b; }

    const int ldsAw = w * 1024;
    size_t aoff[4], boff[4];
#pragma unroll
    for (int i = 0; i < 4; ++i) {
        int slot = i * 256 + t;
        int rm = slot >> 3, rc = slot & 7;
        aoff[i] = (size_t)(m0 + rm) * K + (size_t)((rc ^ (rm & 7)) * 8);
        boff[i] = (size_t)(wtrow + rm) * K + (size_t)((rc ^ (rm & 7)) * 8);
    }

    int ncm[4];
#pragma unroll
    for (int nf = 0; nf < 4; ++nf)
        ncm[nf] = wc * 32 + (nf & 1) * 16 + lr + ((nf & 2) ? 64 : 0);

    const int xorA = (lr & 7) << 4;
    int aroff[4][2], broff[4][2];
#pragma unroll
    for (int mf = 0; mf < 4; ++mf)
#pragma unroll
        for (int ks = 0; ks < 2; ++ks)
            aroff[mf][ks] = (((wr * 64 + mf * 16 + lr) * 128) + lg * 16 + ks * 64) ^ xorA;
#pragma unroll
    for (int nf = 0; nf < 4; ++nf)
#pragma unroll
        for (int ks = 0; ks < 2; ++ks)
            broff[nf][ks] = ((ncm[nf] * 128) + lg * 16 + ks * 64) ^ xorA;

    f32x4 macc[4][4];
#pragma unroll
    for (int mf = 0; mf < 4; ++mf)
#pragma unroll
        for (int nf = 0; nf < 4; ++nf) macc[mf][nf] = f32x4{0.f, 0.f, 0.f, 0.f};

#define QKV_STAGE(AH, BH, k0) { \
    gl_lds16(Xf + (k0) + aoff[0], (char*)(AH) + ldsAw); \
    gl_lds16(Xf + (k0) + aoff[1], (char*)(AH) + 4096 + ldsAw); \
    gl_lds16(Xf + (k0) + aoff[2], (char*)(AH) + 8192 + ldsAw); \
    gl_lds16(Xf + (k0) + aoff[3], (char*)(AH) + 12288 + ldsAw); \
    gl_lds16(WT + (k0) + boff[0], (char*)(BH) + ldsAw); \
    gl_lds16(WT + (k0) + boff[1], (char*)(BH) + 4096 + ldsAw); \
    gl_lds16(WT + (k0) + boff[2], (char*)(BH) + 8192 + ldsAw); \
    gl_lds16(WT + (k0) + boff[3], (char*)(BH) + 12288 + ldsAw); }

#define QKV_COMPUTE(AH, BT) { \
    _Pragma("unroll") \
    for (int ks = 0; ks < 2; ++ks) { \
        half8v av[4], bv[4]; \
        _Pragma("unroll") \
        for (int mf = 0; mf < 4; ++mf) \
            av[mf] = *(const half8v*)((const char*)(AH) + aroff[mf][ks]); \
        _Pragma("unroll") \
        for (int nf = 0; nf < 4; ++nf) \
            bv[nf] = *(const half8v*)((const char*)(BT) + broff[nf][ks]); \
        _Pragma("unroll") \
        for (int mf = 0; mf < 4; ++mf) \
            _Pragma("unroll") \
            for (int nf = 0; nf < 4; ++nf) \
                macc[mf][nf] = __builtin_amdgcn_mfma_f32_16x16x32_f16(av[mf], bv[nf], macc[mf][nf], 0, 0, 0); \
    } }

    QKV_STAGE(A0, B0, 0);
    WAIT_VM(0);
    RAW_BARRIER;

    for (int g = 0; g < 19; ++g) {
        QKV_STAGE(A1, B1, (2 * g + 1) * 64);
        QKV_COMPUTE(A0, B0);
        WAIT_VM(0);
        RAW_BARRIER;
        QKV_STAGE(A0, B0, (2 * g + 2) * 64);
        QKV_COMPUTE(A1, B1);
        WAIT_VM(0);
        RAW_BARRIER;
    }
    QKV_STAGE(A1, B1, 39 * 64);
    QKV_COMPUTE(A0, B0);
    WAIT_VM(0);
    RAW_BARRIER;
    QKV_COMPUTE(A1, B1);

#pragma unroll
    for (int nf = 0; nf < 4; ++nf) {
        float bv = BI[nbase + ncm[nf]];
#pragma unroll
        for (int mf = 0; mf < 4; ++mf)
#pragma unroll
            for (int r = 0; r < 4; ++r) macc[mf][nf][r] += bv;
    }

    if (region == 2) {
#pragma unroll
        for (int mf = 0; mf < 4; ++mf)
#pragma unroll
            for (int r = 0; r < 4; ++r) {
                int row = m0 + wr * 64 + mf * 16 + lg * 4 + r;
#pragma unroll
                for (int nf = 0; nf < 4; ++nf)
                    Vrm[(size_t)row * (NKV * HD) + nbase + ncm[nf]] = f2h(macc[mf][nf][r]);
            }
    } else {
        ushort* OF = (region == 0) ? Qf : Kf;
        const int No = (region == 0) ? NH * HD : NKV * HD;
        // Q scale folds 1/sqrt(HD) AND log2(e) -> attention uses exp2 directly
        const float osc = (region == 0)
            ? 0.08838834764831845f * 1.44269504088896341f : 1.0f;
#pragma unroll
        for (int mf = 0; mf < 4; ++mf)
#pragma unroll
            for (int r = 0; r < 4; ++r) {
                int row = m0 + wr * 64 + mf * 16 + lg * 4 + r;
                const float* cb = &cosb[(size_t)row * HD];
                const float* sb = &sinb[(size_t)row * HD];
#pragma unroll
                for (int nf = 0; nf < 2; ++nf) {
                    int d = wc * 32 + nf * 16 + lr;
                    float a = macc[mf][nf][r];
                    float b = macc[mf][nf + 2][r];
                    float o1 = (a * cb[d]      - b * sb[d])      * osc;
                    float o2 = (b * cb[d + 64] + a * sb[d + 64]) * osc;
                    OF[(size_t)row * No + nbase + d]      = f2h(o1);
                    OF[(size_t)row * No + nbase + d + 64] = f2h(o2);
                }
            }
    }
#undef QKV_STAGE
#undef QKV_COMPUTE
}

// ---------------------------------------------------------------------------
// V transpose (unchanged).
// ---------------------------------------------------------------------------
__global__ __launch_bounds__(256) void vtrans_kernel(
    const ushort* __restrict__ Vrm, ushort* __restrict__ VfT)
{
    __shared__ ushort Ts[64][65];
    const int s0 = blockIdx.x * 64;
    const int n0 = blockIdx.y * 64;
    const int t  = threadIdx.x;
    {
        int r = t >> 2, c0 = (t & 3) * 16;
        uint4 v0 = *(const uint4*)&Vrm[(size_t)(s0 + r) * (NKV * HD) + n0 + c0];
        uint4 v1 = *(const uint4*)&Vrm[(size_t)(s0 + r) * (NKV * HD) + n0 + c0 + 8];
        const ushort* pv = (const ushort*)&v0;
#pragma unroll
        for (int j = 0; j < 8; ++j) Ts[r][c0 + j] = pv[j];
        pv = (const ushort*)&v1;
#pragma unroll
        for (int j = 0; j < 8; ++j) Ts[r][c0 + 8 + j] = pv[j];
    }
    __syncthreads();
    {
        int rn = t >> 2, cs0 = (t & 3) * 16;
        ushort ob[16];
#pragma unroll
        for (int j = 0; j < 16; ++j) ob[j] = Ts[cs0 + j][rn];
        ushort* dst = &VfT[(size_t)(n0 + rn) * S_LEN + s0 + cs0];
        *(uint4*)dst = ((uint4*)ob)[0];
        *(uint4*)(dst + 8) = ((uint4*)ob)[1];
    }
}

// ===========================================================================
// O-projection (unchanged — control).
// ===========================================================================
__global__ __launch_bounds__(256) void oproj8_kernel(
    const ushort* __restrict__ Xb, const int* __restrict__ QW,
    const float* __restrict__ SC, const int* __restrict__ QZ,
    float* __restrict__ Y)
{
    __shared__ __align__(16) char LDSB[65536];
    ushort* A0 = (ushort*)(LDSB);
    ushort* A1 = (ushort*)(LDSB + 16384);
    ushort* B0 = (ushort*)(LDSB + 32768);
    ushort* B1 = (ushort*)(LDSB + 49152);

    const int t  = threadIdx.x;
    const int w  = t >> 6;
    const int l  = t & 63;
    const int lg = l >> 4;
    const int lr = l & 15;
    const int wr = w >> 1;
    const int wc = w & 1;
    const int K  = NH * HD;
    const int N  = HIDDEN;

    const int bid = blockIdx.x;
    const int swz = (bid & 7) * 40 + (bid >> 3);
    const int n0  = (swz % 20) * 128;
    const int m0  = (swz / 20) * 128;

    const int ldsAw = w * 1024;
    size_t aoff[4];
#pragma unroll
    for (int i = 0; i < 4; ++i) {
        int slot = i * 256 + t;
        int am = slot >> 3, ac = slot & 7;
        aoff[i] = (size_t)(m0 + am) * K + (size_t)((ac ^ (am & 7)) * 8);
    }
    const int bn  = t & 127;
    const int bk0 = (t >> 7) * 4;
    int bwoff[4];
#pragma unroll
    for (int j = 0; j < 4; ++j)
        bwoff[j] = (bn * 128 + (bk0 + j) * 16) ^ ((bn & 7) << 4);

    const int xorA = (lr & 7) << 4;
    int aroff[4][2], broff[4][2];
#pragma unroll
    for (int mf = 0; mf < 4; ++mf)
#pragma unroll
        for (int ks = 0; ks < 2; ++ks)
            aroff[mf][ks] = (((wr * 64 + mf * 16 + lr) * 128) + lg * 16 + ks * 64) ^ xorA;
#pragma unroll
    for (int nf = 0; nf < 4; ++nf)
#pragma unroll
        for (int ks = 0; ks < 2; ++ks)
            broff[nf][ks] = (((wc * 64 + nf * 16 + lr) * 128) + lg * 16 + ks * 64) ^ xorA;

    f32x4 macc[4][4];
#pragma unroll
    for (int mf = 0; mf < 4; ++mf)
#pragma unroll
        for (int nf = 0; nf < 4; ++nf) macc[mf][nf] = f32x4{0.f, 0.f, 0.f, 0.f};
    uint qr[4];
    float scf, zf;

#define OP_QW(tile) { int g8 = (tile) * 8; int gg = (tile) >> 1; \
    _Pragma("unroll") \
    for (int j = 0; j < 4; ++j) \
        qr[j] = (uint)QW[(size_t)(g8 + bk0 + j) * N + n0 + bn]; \
    scf = SC[(size_t)gg * N + n0 + bn]; \
    zf  = (float)QZ[(size_t)gg * N + n0 + bn]; }

#define OP_STAGE_A(AH, k0) { \
    gl_lds16(Xb + (k0) + aoff[0], (char*)(AH) + ldsAw); \
    gl_lds16(Xb + (k0) + aoff[1], (char*)(AH) + 4096 + ldsAw); \
    gl_lds16(Xb + (k0) + aoff[2], (char*)(AH) + 8192 + ldsAw); \
    gl_lds16(Xb + (k0) + aoff[3], (char*)(AH) + 12288 + ldsAw); }

#define OP_BWRITE(BT) { \
    ushort sch = f2h(scf); \
    float schf = h2f(sch); \
    ushort msc = f2h(-128.0f * schf); \
    ushort nzs = f2h(-(zf * schf)); \
    half2v S2 = {__builtin_bit_cast(_Float16, sch), __builtin_bit_cast(_Float16, sch)}; \
    half2v M2 = {__builtin_bit_cast(_Float16, msc), __builtin_bit_cast(_Float16, msc)}; \
    half2v Z2 = {__builtin_bit_cast(_Float16, nzs), __builtin_bit_cast(_Float16, nzs)}; \
    _Pragma("unroll") \
    for (int j = 0; j < 4; ++j) { \
        uint q = qr[j]; \
        uint xn = q & 0x0F0F0F0Fu; \
        uint yn = (q >> 4) & 0x0F0F0F0Fu; \
        uint4 dw; \
        uint W0 = __builtin_amdgcn_perm(yn, xn, 0x0C040C00u); \
        uint W1 = __builtin_amdgcn_perm(yn, xn, 0x0C050C01u); \
        uint W2 = __builtin_amdgcn_perm(yn, xn, 0x0C060C02u); \
        uint W3 = __builtin_amdgcn_perm(yn, xn, 0x0C070C03u); \
        uint e0 = (W0 << 3) | 0x58005800u; \
        uint e1 = (W1 << 3) | 0x58005800u; \
        uint e2 = (W2 << 3) | 0x58005800u; \
        uint e3 = (W3 << 3) | 0x58005800u; \
        half2v w0 = __builtin_bit_cast(half2v, e0) * S2 + M2; w0 = w0 + Z2; \
        half2v w1 = __builtin_bit_cast(half2v, e1) * S2 + M2; w1 = w1 + Z2; \
        half2v w2 = __builtin_bit_cast(half2v, e2) * S2 + M2; w2 = w2 + Z2; \
        half2v w3 = __builtin_bit_cast(half2v, e3) * S2 + M2; w3 = w3 + Z2; \
        dw.x = __builtin_bit_cast(uint, w0); \
        dw.y = __builtin_bit_cast(uint, w1); \
        dw.z = __builtin_bit_cast(uint, w2); \
        dw.w = __builtin_bit_cast(uint, w3); \
        *(uint4*)((char*)(BT) + bwoff[j]) = dw; \
    } }

#define OP_COMPUTE(AH, BT) { \
    _Pragma("unroll") \
    for (int ks = 0; ks < 2; ++ks) { \
        half8v av[4], bv[4]; \
        _Pragma("unroll") \
        for (int mf = 0; mf < 4; ++mf) \
            av[mf] = *(const half8v*)((const char*)(AH) + aroff[mf][ks]); \
        _Pragma("unroll") \
        for (int nf = 0; nf < 4; ++nf) \
            bv[nf] = *(const half8v*)((const char*)(BT) + broff[nf][ks]); \
        _Pragma("unroll") \
        for (int mf = 0; mf < 4; ++mf) \
            _Pragma("unroll") \
            for (int nf = 0; nf < 4; ++nf) \
                macc[mf][nf] = __builtin_amdgcn_mfma_f32_16x16x32_f16(av[mf], bv[nf], macc[mf][nf], 0, 0, 0); \
    } }

    OP_QW(0);
    OP_BWRITE(B0);
    OP_STAGE_A(A0, 0);
    OP_QW(1);
    WAIT_LGKM0;
    WAIT_VM(6);
    RAW_BARRIER;

    for (int g = 0; g < 31; ++g) {
        OP_STAGE_A(A1, (2 * g + 1) * 64);
        OP_COMPUTE(A0, B0);
        OP_BWRITE(B1);
        OP_QW(2 * g + 2);
        WAIT_LGKM0;
        WAIT_VM(6);
        RAW_BARRIER;
        OP_STAGE_A(A0, (2 * g + 2) * 64);
        OP_COMPUTE(A1, B1);
        OP_BWRITE(B0);
        OP_QW(2 * g + 3);
        WAIT_LGKM0;
        WAIT_VM(6);
        RAW_BARRIER;
    }
    OP_STAGE_A(A1, 63 * 64);
    OP_COMPUTE(A0, B0);
    OP_BWRITE(B1);
    WAIT_LGKM0;
    WAIT_VM(0);
    RAW_BARRIER;
    OP_COMPUTE(A1, B1);

#pragma unroll
    for (int mf = 0; mf < 4; ++mf)
#pragma unroll
        for (int r = 0; r < 4; ++r) {
            int row = m0 + wr * 64 + mf * 16 + lg * 4 + r;
#pragma unroll
            for (int nf = 0; nf < 4; ++nf)
                Y[(size_t)row * N + n0 + wc * 64 + nf * 16 + lr] = macc[mf][nf][r];
        }
#undef OP_QW
#undef OP_STAGE_A
#undef OP_BWRITE
#undef OP_COMPUTE
}

// ---------------------------------------------------------------------------
// Causal GQA flash attention, fp16 MFMA, swapped operands; dbuf K/V staging.
// Round-19 grid (32x32, reversed-qb dispatch) RESTORED; exp2 softmax kept
// (Q pre-scaled by log2e in qkv epilogue).
// ---------------------------------------------------------------------------
__global__ __launch_bounds__(256) void attn_mfma_kernel(
    const ushort* __restrict__ Qh,   // [S][NH*HD] fp16, roped, *log2e/sqrt(HD)
    const ushort* __restrict__ Kh,   // [S][NKV*HD] fp16, roped
    const ushort* __restrict__ Vt,   // [NKV*HD][S] fp16 (transposed)
    ushort* __restrict__ AO)         // [S][NH*HD] fp16
{
    __shared__ ushort Ks0[32 * 128];           // swz ^((row&7)<<4)
    __shared__ ushort Ks1[32 * 128];
    __shared__ ushort Vs0[128 * 32];           // swz ^(((dim>>1)&3)<<4)
    __shared__ ushort Vs1[128 * 32];
    __shared__ __align__(16) char PsB[4 * 1280];  // P: 16 rows x 80B per wave

    const int h  = blockIdx.x;
    const int qb = gridDim.y - 1 - blockIdx.y;   // long blocks dispatch first
    const int s0 = qb * 64;
    const int t  = threadIdx.x;
    const int w  = t >> 6;
    const int l  = t & 63;
    const int lg = l >> 4;
    const int lr = l & 15;
    const int kvh = h >> 2;
    const int qw = s0 + w * 16;
    const int q  = qw + lr;          // this lane's q-row

    half8v qf[4];
#pragma unroll
    for (int d = 0; d < 4; ++d) {
        size_t off = (size_t)q * (NH * HD) + h * HD + d * 32 + lg * 8;
        qf[d] = *(const half8v*)&Qh[off];
    }

    f32x4 o[8];
#pragma unroll
    for (int i = 0; i < 8; ++i) o[i] = f32x4{0.f, 0.f, 0.f, 0.f};
    float m = -1e30f, lsum = 0.f;
    char* pw = PsB + w * 1280;

#define ATTN_STAGE(KB, VB, k0) { \
    _Pragma("unroll") \
    for (int i = 0; i < 2; ++i) { \
        int slot = w * 128 + i * 64 + l; \
        int mr = slot >> 4, c = slot & 15; \
        size_t goff = (size_t)((k0) + mr) * (NKV * HD) + kvh * HD + ((c ^ (mr & 7)) * 8); \
        gl_lds16(Kh + goff, (char*)(KB) + (w * 128 + i * 64) * 16); \
    } \
    _Pragma("unroll") \
    for (int i = 0; i < 2; ++i) { \
        int slot = w * 128 + i * 64 + l; \
        int dim = slot >> 2, c = slot & 3; \
        size_t goff = (size_t)(kvh * HD + dim) * S_LEN + (k0) + ((c ^ ((dim >> 1) & 3)) * 8); \
        gl_lds16(Vt + goff, (char*)(VB) + (w * 128 + i * 64) * 16); \
    } }

#define ATTN_TILE(KSF, VSS, k0) \
    if ((k0) <= qw + 15) { \
        f32x4 s_[2]; \
        s_[0] = f32x4{0.f, 0.f, 0.f, 0.f}; \
        s_[1] = f32x4{0.f, 0.f, 0.f, 0.f}; \
        _Pragma("unroll") \
        for (int d = 0; d < 4; ++d) { \
            _Pragma("unroll") \
            for (int nt2 = 0; nt2 < 2; ++nt2) { \
                int row = nt2 * 16 + lr; \
                int off = row * 256 + ((d * 64 + lg * 16) ^ ((row & 7) << 4)); \
                half8v kf = *(const half8v*)((const char*)(KSF) + off); \
                s_[nt2] = __builtin_amdgcn_mfma_f32_16x16x32_f16(kf, qf[d], s_[nt2], 0, 0, 0); \
            } \
        } \
        float sv[8]; \
        _Pragma("unroll") \
        for (int nt2 = 0; nt2 < 2; ++nt2) \
            _Pragma("unroll") \
            for (int r = 0; r < 4; ++r) { \
                int kv = (k0) + nt2 * 16 + lg * 4 + r; \
                sv[nt2 * 4 + r] = (kv <= q) ? s_[nt2][r] : -1e30f; \
            } \
        float mx = sv[0]; \
        _Pragma("unroll") \
        for (int j = 1; j < 8; ++j) mx = fmaxf(mx, sv[j]); \
        mx = fmaxf(mx, __shfl_xor(mx, 16)); \
        mx = fmaxf(mx, __shfl_xor(mx, 32)); \
        float mnew = fmaxf(m, mx); \
        float resc = exp2f(m - mnew); \
        m = mnew; \
        float p_[8], ps = 0.f; \
        _Pragma("unroll") \
        for (int j = 0; j < 8; ++j) { p_[j] = exp2f(sv[j] - mnew); ps += p_[j]; } \
        ps += __shfl_xor(ps, 16); \
        ps += __shfl_xor(ps, 32); \
        lsum = lsum * resc + ps; \
        _Pragma("unroll") \
        for (int dt = 0; dt < 8; ++dt) \
            _Pragma("unroll") \
            for (int r = 0; r < 4; ++r) o[dt][r] *= resc; \
        uint2 w0_ = {pk2(f2h(p_[0]), f2h(p_[1])), pk2(f2h(p_[2]), f2h(p_[3]))}; \
        uint2 w1_ = {pk2(f2h(p_[4]), f2h(p_[5])), pk2(f2h(p_[6]), f2h(p_[7]))}; \
        *(uint2*)(pw + lr * 80 + lg * 8)      = w0_; \
        *(uint2*)(pw + lr * 80 + 32 + lg * 8) = w1_; \
        asm volatile("s_waitcnt lgkmcnt(0)" ::: "memory"); \
        half8v pf = *(const half8v*)(pw + lr * 80 + lg * 16); \
        _Pragma("unroll") \
        for (int dt = 0; dt < 8; ++dt) { \
            int dim = dt * 16 + lr; \
            half8v vf = *(const half8v*)((const char*)(VSS) + dim * 64 + ((lg * 16) ^ (((dim >> 1) & 3) << 4))); \
            o[dt] = __builtin_amdgcn_mfma_f32_16x16x32_f16(vf, pf, o[dt], 0, 0, 0); \
        } \
    }

    const int ntiles = qb * 2 + 2;   // always even

    ATTN_STAGE(Ks0, Vs0, 0);
    WAIT_VM(0);
    RAW_BARRIER;

    for (int kt = 0; kt < ntiles; kt += 2) {
        if (kt + 1 < ntiles) ATTN_STAGE(Ks1, Vs1, (kt + 1) * 32);
        ATTN_TILE(Ks0, Vs0, kt * 32);
        WAIT_VM(0);
        RAW_BARRIER;
        if (kt + 2 < ntiles) ATTN_STAGE(Ks0, Vs0, (kt + 2) * 32);
        ATTN_TILE(Ks1, Vs1, (kt + 1) * 32);
        WAIT_VM(0);
        RAW_BARRIER;
    }

    float inv = 1.f / lsum;
    ushort* dst = &AO[(size_t)q * (NH * HD) + h * HD];
#pragma unroll
    for (int dt = 0; dt < 8; ++dt) {
        uint2 ov = {pk2(f2h(o[dt][0] * inv), f2h(o[dt][1] * inv)),
                    pk2(f2h(o[dt][2] * inv), f2h(o[dt][3] * inv))};
        *(uint2*)(dst + dt * 16 + lg * 4) = ov;
    }
#undef ATTN_STAGE
#undef ATTN_TILE
}

// ---------------------------------------------------------------------------
extern "C" void kernel_launch(void* const* d_in, const int* in_sizes, int n_in,
                              void* d_out, int out_size, void* d_ws, size_t ws_size,
                              hipStream_t stream)
{
    const float* x    = (const float*)d_in[0];
    const float* cosb = (const float*)d_in[1];
    const float* sinb = (const float*)d_in[2];
    const float* q_sc = (const float*)d_in[3];
    const float* q_b  = (const float*)d_in[4];
    const float* k_sc = (const float*)d_in[5];
    const float* k_b  = (const float*)d_in[6];
    const float* v_sc = (const float*)d_in[7];
    const float* v_b  = (const float*)d_in[8];
    const float* o_sc = (const float*)d_in[9];
    const int* q_qw   = (const int*)d_in[10];
    const int* q_qz   = (const int*)d_in[11];
    const int* k_qw   = (const int*)d_in[12];
    const int* k_qz   = (const int*)d_in[13];
    const int* v_qw   = (const int*)d_in[14];
    const int* v_qz   = (const int*)d_in[15];
    const int* o_qw   = (const int*)d_in[16];
    const int* o_qz   = (const int*)d_in[17];
    float* out = (float*)d_out;

    // ws layout (MB):
    //   0..10   Xf16   [AOf16 (16MB) aliases 0..16 after qkv11]
    //   10..40  WT fp16 [6144][2560]  (dead after qkv11)
    //   40..56  Qf | 56..60 Kf | 60..64 Vrm | 64..68 VfT
    char* ws = (char*)d_ws;
    ushort* Xf   = (ushort*)ws;
    ushort* AOf  = (ushort*)ws;                                  // alias
    ushort* WT   = (ushort*)(ws + (size_t)10 * 1024 * 1024);
    ushort* Qf   = (ushort*)(ws + (size_t)40 * 1024 * 1024);
    ushort* Kf   = (ushort*)(ws + (size_t)56 * 1024 * 1024);
    ushort* Vrm  = (ushort*)(ws + (size_t)60 * 1024 * 1024);
    ushort* VfT  = (ushort*)(ws + (size_t)64 * 1024 * 1024);

    xcvt_kernel<<<S_LEN, 320, 0, stream>>>(x, Xf);

    wdq_kernel<<<dim3(96, 20), 256, 0, stream>>>(
        q_qw, q_sc, q_qz, k_qw, k_sc, k_qz, v_qw, v_sc, v_qz, WT);

    qkv11_kernel<<<768, 256, 0, stream>>>(
        Xf, WT, q_b, k_b, v_b, cosb, sinb, Qf, Kf, Vrm);

    vtrans_kernel<<<dim3(S_LEN / 64, (NKV * HD) / 64), 256, 0, stream>>>(Vrm, VfT);

    attn_mfma_kernel<<<dim3(NH, S_LEN / 64), 256, 0, stream>>>(Qf, Kf, VfT, AOf);

    oproj8_kernel<<<320, 256, 0, stream>>>(
        AOf, o_qw, o_sc, o_qz, out);
}

// Round 22
// 257.950 us; speedup vs baseline: 1.0698x; 1.0286x over previous
//
#include <hip/hip_runtime.h>
#include <hip/hip_bf16.h>
#include <cstdint>

#define S_LEN 2048
#define HIDDEN 2560
#define NH 32
#define NKV 8
#define HD 128
#define GS 128

typedef __attribute__((ext_vector_type(8))) _Float16 half8v;    // 8 x fp16
typedef __attribute__((ext_vector_type(2))) _Float16 half2v;    // 2 x fp16
typedef __attribute__((ext_vector_type(4))) float f32x4;
typedef unsigned int uint;
typedef unsigned short ushort;

__device__ inline ushort f2h(float f) {
    _Float16 h = (_Float16)f;
    return __builtin_bit_cast(ushort, h);
}
__device__ inline float h2f(ushort u) {
    return (float)__builtin_bit_cast(_Float16, u);
}
__device__ inline uint pk2(ushort a, ushort b) { return (uint)a | ((uint)b << 16); }

// async global->LDS, 16B per lane; lds base must be wave-uniform
__device__ __attribute__((always_inline)) inline void gl_lds16(const void* g, void* l) {
    __builtin_amdgcn_global_load_lds(
        (const __attribute__((address_space(1))) unsigned int*)g,
        (__attribute__((address_space(3))) unsigned int*)l, 16, 0, 0);
}

#define WAIT_LGKM0  asm volatile("s_waitcnt lgkmcnt(0)" ::: "memory")
#define WAIT_VM(N)  asm volatile("s_waitcnt vmcnt(" #N ")" ::: "memory")
#define RAW_BARRIER { __builtin_amdgcn_s_barrier(); __builtin_amdgcn_sched_barrier(0); }

// ===========================================================================
// Merged prepass: blocks [0,2560) convert X->fp16 (flat, 2048 els/block);
// blocks [2560,4480) dequant QKV weights -> fp16 transposed WT[6144][2560].
// Both memory-bound and independent -> co-run in one launch.
// ===========================================================================
__global__ __launch_bounds__(256) void prep_kernel(
    const float* __restrict__ X, ushort* __restrict__ Xf,
    const int* __restrict__ q_qw, const float* __restrict__ q_sc, const int* __restrict__ q_qz,
    const int* __restrict__ k_qw, const float* __restrict__ k_sc, const int* __restrict__ k_qz,
    const int* __restrict__ v_qw, const float* __restrict__ v_sc, const int* __restrict__ v_qz,
    ushort* __restrict__ WT)
{
    __shared__ __align__(16) char Ts[16384];
    const int bid = blockIdx.x;
    const int t   = threadIdx.x;

    if (bid < 2560) {
        // ---- X -> fp16, flat ----
        const size_t base = (size_t)bid * 2048 + (size_t)t * 8;
        float4 a = *(const float4*)&X[base];
        float4 b = *(const float4*)&X[base + 4];
        uint4 hw = {pk2(f2h(a.x), f2h(a.y)), pk2(f2h(a.z), f2h(a.w)),
                    pk2(f2h(b.x), f2h(b.y)), pk2(f2h(b.z), f2h(b.w))};
        *(uint4*)&Xf[base] = hw;
        return;
    }

    // ---- weight dequant (verified numerics) ----
    const int b2 = bid - 2560;
    const int bx = b2 % 96;
    const int kt = b2 / 96;

    int nloc0, wtbase, Nw;
    const int* QW; const float* SC; const int* QZ;
    if (bx < 64)      { Nw = NH * HD;  nloc0 = bx * 64;        wtbase = bx * 64;
                        QW = q_qw; SC = q_sc; QZ = q_qz; }
    else if (bx < 80) { Nw = NKV * HD; nloc0 = (bx - 64) * 64; wtbase = 4096 + nloc0;
                        QW = k_qw; SC = k_sc; QZ = k_qz; }
    else              { Nw = NKV * HD; nloc0 = (bx - 80) * 64; wtbase = 5120 + nloc0;
                        QW = v_qw; SC = v_sc; QZ = v_qz; }

    const int k80 = kt * 16;
    const int nn  = t & 63;
    const float scf = SC[(size_t)kt * Nw + nloc0 + nn];
    const float zf  = (float)QZ[(size_t)kt * Nw + nloc0 + nn];
    ushort sch = f2h(scf);
    float schf = h2f(sch);
    ushort msc = f2h(-128.0f * schf);   // exact exponent shift
    ushort nzs = f2h(-(zf * schf));
    half2v S2 = {__builtin_bit_cast(_Float16, sch), __builtin_bit_cast(_Float16, sch)};
    half2v M2 = {__builtin_bit_cast(_Float16, msc), __builtin_bit_cast(_Float16, msc)};
    half2v Z2 = {__builtin_bit_cast(_Float16, nzs), __builtin_bit_cast(_Float16, nzs)};

#pragma unroll
    for (int i = 0; i < 4; ++i) {
        int kw = i * 4 + (t >> 6);
        uint q = (uint)QW[(size_t)(k80 + kw) * Nw + nloc0 + nn];
        uint xn = q & 0x0F0F0F0Fu;
        uint yn = (q >> 4) & 0x0F0F0F0Fu;
        uint W0 = __builtin_amdgcn_perm(yn, xn, 0x0C040C00u);
        uint W1 = __builtin_amdgcn_perm(yn, xn, 0x0C050C01u);
        uint W2 = __builtin_amdgcn_perm(yn, xn, 0x0C060C02u);
        uint W3 = __builtin_amdgcn_perm(yn, xn, 0x0C070C03u);
        uint e0 = (W0 << 3) | 0x58005800u;
        uint e1 = (W1 << 3) | 0x58005800u;
        uint e2 = (W2 << 3) | 0x58005800u;
        uint e3 = (W3 << 3) | 0x58005800u;
        half2v w0 = __builtin_bit_cast(half2v, e0) * S2 + M2; w0 = w0 + Z2;
        half2v w1 = __builtin_bit_cast(half2v, e1) * S2 + M2; w1 = w1 + Z2;
        half2v w2 = __builtin_bit_cast(half2v, e2) * S2 + M2; w2 = w2 + Z2;
        half2v w3 = __builtin_bit_cast(half2v, e3) * S2 + M2; w3 = w3 + Z2;
        uint4 dw = {__builtin_bit_cast(uint, w0), __builtin_bit_cast(uint, w1),
                    __builtin_bit_cast(uint, w2), __builtin_bit_cast(uint, w3)};
        *(uint4*)(Ts + nn * 256 + ((kw * 16) ^ ((nn & 7) << 4))) = dw;
    }
    __syncthreads();
    const int kc = t & 15;
#pragma unroll
    for (int i = 0; i < 4; ++i) {
        int nr = i * 16 + (t >> 4);
        uint4 v = *(const uint4*)(Ts + nr * 256 + ((kc * 16) ^ ((nr & 7) << 4)));
        *(uint4*)&WT[(size_t)(wtbase + nr) * HIDDEN + kt * 128 + kc * 8] = v;
    }
}

// ===========================================================================
// Fused Q/K/V MFMA GEMM on fp16 WT (N-persistent XCD swizzle).
// Q epilogue scale folds log2(e) so attention can use raw v_exp_f32.
// ===========================================================================
__global__ __launch_bounds__(256) void qkv11_kernel(
    const ushort* __restrict__ Xf, const ushort* __restrict__ WT,
    const float* __restrict__ q_b, const float* __restrict__ k_b,
    const float* __restrict__ v_b,
    const float* __restrict__ cosb, const float* __restrict__ sinb,
    ushort* __restrict__ Qf, ushort* __restrict__ Kf,
    ushort* __restrict__ Vrm)
{
    __shared__ __align__(16) char LDSB[65536];
    ushort* A0 = (ushort*)(LDSB);
    ushort* A1 = (ushort*)(LDSB + 16384);
    ushort* B0 = (ushort*)(LDSB + 32768);
    ushort* B1 = (ushort*)(LDSB + 49152);

    const int t  = threadIdx.x;
    const int w  = t >> 6;
    const int l  = t & 63;
    const int lg = l >> 4;
    const int lr = l & 15;
    const int wr = w >> 1;
    const int wc = w & 1;
    const int K  = HIDDEN;

    const int bid  = blockIdx.x;
    const int xcd  = bid & 7;
    const int j    = bid >> 3;
    const int nblk = xcd * 6 + (j >> 4);
    const int m0   = (j & 15) * 128;
    const int wtrow = nblk * 128;

    int region, nbase;
    const float* BI;
    if (nblk < 32)      { region = 0; nbase = nblk * 128;        BI = q_b; }
    else if (nblk < 40) { region = 1; nbase = (nblk - 32) * 128; BI = k_b; }
    else                { region = 2; nbase = (nblk - 40) * 128; BI = v_b; }

    const int ldsAw = w * 1024;
    size_t aoff[4], boff[4];
#pragma unroll
    for (int i = 0; i < 4; ++i) {
        int slot = i * 256 + t;
        int rm = slot >> 3, rc = slot & 7;
        aoff[i] = (size_t)(m0 + rm) * K + (size_t)((rc ^ (rm & 7)) * 8);
        boff[i] = (size_t)(wtrow + rm) * K + (size_t)((rc ^ (rm & 7)) * 8);
    }

    int ncm[4];
#pragma unroll
    for (int nf = 0; nf < 4; ++nf)
        ncm[nf] = wc * 32 + (nf & 1) * 16 + lr + ((nf & 2) ? 64 : 0);

    const int xorA = (lr & 7) << 4;
    int aroff[4][2], broff[4][2];
#pragma unroll
    for (int mf = 0; mf < 4; ++mf)
#pragma unroll
        for (int ks = 0; ks < 2; ++ks)
            aroff[mf][ks] = (((wr * 64 + mf * 16 + lr) * 128) + lg * 16 + ks * 64) ^ xorA;
#pragma unroll
    for (int nf = 0; nf < 4; ++nf)
#pragma unroll
        for (int ks = 0; ks < 2; ++ks)
            broff[nf][ks] = ((ncm[nf] * 128) + lg * 16 + ks * 64) ^ xorA;

    f32x4 macc[4][4];
#pragma unroll
    for (int mf = 0; mf < 4; ++mf)
#pragma unroll
        for (int nf = 0; nf < 4; ++nf) macc[mf][nf] = f32x4{0.f, 0.f, 0.f, 0.f};

#define QKV_STAGE(AH, BH, k0) { \
    gl_lds16(Xf + (k0) + aoff[0], (char*)(AH) + ldsAw); \
    gl_lds16(Xf + (k0) + aoff[1], (char*)(AH) + 4096 + ldsAw); \
    gl_lds16(Xf + (k0) + aoff[2], (char*)(AH) + 8192 + ldsAw); \
    gl_lds16(Xf + (k0) + aoff[3], (char*)(AH) + 12288 + ldsAw); \
    gl_lds16(WT + (k0) + boff[0], (char*)(BH) + ldsAw); \
    gl_lds16(WT + (k0) + boff[1], (char*)(BH) + 4096 + ldsAw); \
    gl_lds16(WT + (k0) + boff[2], (char*)(BH) + 8192 + ldsAw); \
    gl_lds16(WT + (k0) + boff[3], (char*)(BH) + 12288 + ldsAw); }

#define QKV_COMPUTE(AH, BT) { \
    _Pragma("unroll") \
    for (int ks = 0; ks < 2; ++ks) { \
        half8v av[4], bv[4]; \
        _Pragma("unroll") \
        for (int mf = 0; mf < 4; ++mf) \
            av[mf] = *(const half8v*)((const char*)(AH) + aroff[mf][ks]); \
        _Pragma("unroll") \
        for (int nf = 0; nf < 4; ++nf) \
            bv[nf] = *(const half8v*)((const char*)(BT) + broff[nf][ks]); \
        _Pragma("unroll") \
        for (int mf = 0; mf < 4; ++mf) \
            _Pragma("unroll") \
            for (int nf = 0; nf < 4; ++nf) \
                macc[mf][nf] = __builtin_amdgcn_mfma_f32_16x16x32_f16(av[mf], bv[nf], macc[mf][nf], 0, 0, 0); \
    } }

    QKV_STAGE(A0, B0, 0);
    WAIT_VM(0);
    RAW_BARRIER;

    for (int g = 0; g < 19; ++g) {
        QKV_STAGE(A1, B1, (2 * g + 1) * 64);
        QKV_COMPUTE(A0, B0);
        WAIT_VM(0);
        RAW_BARRIER;
        QKV_STAGE(A0, B0, (2 * g + 2) * 64);
        QKV_COMPUTE(A1, B1);
        WAIT_VM(0);
        RAW_BARRIER;
    }
    QKV_STAGE(A1, B1, 39 * 64);
    QKV_COMPUTE(A0, B0);
    WAIT_VM(0);
    RAW_BARRIER;
    QKV_COMPUTE(A1, B1);

#pragma unroll
    for (int nf = 0; nf < 4; ++nf) {
        float bv = BI[nbase + ncm[nf]];
#pragma unroll
        for (int mf = 0; mf < 4; ++mf)
#pragma unroll
            for (int r = 0; r < 4; ++r) macc[mf][nf][r] += bv;
    }

    if (region == 2) {
#pragma unroll
        for (int mf = 0; mf < 4; ++mf)
#pragma unroll
            for (int r = 0; r < 4; ++r) {
                int row = m0 + wr * 64 + mf * 16 + lg * 4 + r;
#pragma unroll
                for (int nf = 0; nf < 4; ++nf)
                    Vrm[(size_t)row * (NKV * HD) + nbase + ncm[nf]] = f2h(macc[mf][nf][r]);
            }
    } else {
        ushort* OF = (region == 0) ? Qf : Kf;
        const int No = (region == 0) ? NH * HD : NKV * HD;
        // Q scale folds 1/sqrt(HD) AND log2(e) -> attention uses exp2 directly
        const float osc = (region == 0)
            ? 0.08838834764831845f * 1.44269504088896341f : 1.0f;
#pragma unroll
        for (int mf = 0; mf < 4; ++mf)
#pragma unroll
            for (int r = 0; r < 4; ++r) {
                int row = m0 + wr * 64 + mf * 16 + lg * 4 + r;
                const float* cb = &cosb[(size_t)row * HD];
                const float* sb = &sinb[(size_t)row * HD];
#pragma unroll
                for (int nf = 0; nf < 2; ++nf) {
                    int d = wc * 32 + nf * 16 + lr;
                    float a = macc[mf][nf][r];
                    float b = macc[mf][nf + 2][r];
                    float o1 = (a * cb[d]      - b * sb[d])      * osc;
                    float o2 = (b * cb[d + 64] + a * sb[d + 64]) * osc;
                    OF[(size_t)row * No + nbase + d]      = f2h(o1);
                    OF[(size_t)row * No + nbase + d + 64] = f2h(o2);
                }
            }
    }
#undef QKV_STAGE
#undef QKV_COMPUTE
}

// ---------------------------------------------------------------------------
// V transpose (unchanged).
// ---------------------------------------------------------------------------
__global__ __launch_bounds__(256) void vtrans_kernel(
    const ushort* __restrict__ Vrm, ushort* __restrict__ VfT)
{
    __shared__ ushort Ts[64][65];
    const int s0 = blockIdx.x * 64;
    const int n0 = blockIdx.y * 64;
    const int t  = threadIdx.x;
    {
        int r = t >> 2, c0 = (t & 3) * 16;
        uint4 v0 = *(const uint4*)&Vrm[(size_t)(s0 + r) * (NKV * HD) + n0 + c0];
        uint4 v1 = *(const uint4*)&Vrm[(size_t)(s0 + r) * (NKV * HD) + n0 + c0 + 8];
        const ushort* pv = (const ushort*)&v0;
#pragma unroll
        for (int j = 0; j < 8; ++j) Ts[r][c0 + j] = pv[j];
        pv = (const ushort*)&v1;
#pragma unroll
        for (int j = 0; j < 8; ++j) Ts[r][c0 + 8 + j] = pv[j];
    }
    __syncthreads();
    {
        int rn = t >> 2, cs0 = (t & 3) * 16;
        ushort ob[16];
#pragma unroll
        for (int j = 0; j < 16; ++j) ob[j] = Ts[cs0 + j][rn];
        ushort* dst = &VfT[(size_t)(n0 + rn) * S_LEN + s0 + cs0];
        *(uint4*)dst = ((uint4*)ob)[0];
        *(uint4*)(dst + 8) = ((uint4*)ob)[1];
    }
}

// ===========================================================================
// O-projection (unchanged — control).
// ===========================================================================
__global__ __launch_bounds__(256) void oproj8_kernel(
    const ushort* __restrict__ Xb, const int* __restrict__ QW,
    const float* __restrict__ SC, const int* __restrict__ QZ,
    float* __restrict__ Y)
{
    __shared__ __align__(16) char LDSB[65536];
    ushort* A0 = (ushort*)(LDSB);
    ushort* A1 = (ushort*)(LDSB + 16384);
    ushort* B0 = (ushort*)(LDSB + 32768);
    ushort* B1 = (ushort*)(LDSB + 49152);

    const int t  = threadIdx.x;
    const int w  = t >> 6;
    const int l  = t & 63;
    const int lg = l >> 4;
    const int lr = l & 15;
    const int wr = w >> 1;
    const int wc = w & 1;
    const int K  = NH * HD;
    const int N  = HIDDEN;

    const int bid = blockIdx.x;
    const int swz = (bid & 7) * 40 + (bid >> 3);
    const int n0  = (swz % 20) * 128;
    const int m0  = (swz / 20) * 128;

    const int ldsAw = w * 1024;
    size_t aoff[4];
#pragma unroll
    for (int i = 0; i < 4; ++i) {
        int slot = i * 256 + t;
        int am = slot >> 3, ac = slot & 7;
        aoff[i] = (size_t)(m0 + am) * K + (size_t)((ac ^ (am & 7)) * 8);
    }
    const int bn  = t & 127;
    const int bk0 = (t >> 7) * 4;
    int bwoff[4];
#pragma unroll
    for (int j = 0; j < 4; ++j)
        bwoff[j] = (bn * 128 + (bk0 + j) * 16) ^ ((bn & 7) << 4);

    const int xorA = (lr & 7) << 4;
    int aroff[4][2], broff[4][2];
#pragma unroll
    for (int mf = 0; mf < 4; ++mf)
#pragma unroll
        for (int ks = 0; ks < 2; ++ks)
            aroff[mf][ks] = (((wr * 64 + mf * 16 + lr) * 128) + lg * 16 + ks * 64) ^ xorA;
#pragma unroll
    for (int nf = 0; nf < 4; ++nf)
#pragma unroll
        for (int ks = 0; ks < 2; ++ks)
            broff[nf][ks] = (((wc * 64 + nf * 16 + lr) * 128) + lg * 16 + ks * 64) ^ xorA;

    f32x4 macc[4][4];
#pragma unroll
    for (int mf = 0; mf < 4; ++mf)
#pragma unroll
        for (int nf = 0; nf < 4; ++nf) macc[mf][nf] = f32x4{0.f, 0.f, 0.f, 0.f};
    uint qr[4];
    float scf, zf;

#define OP_QW(tile) { int g8 = (tile) * 8; int gg = (tile) >> 1; \
    _Pragma("unroll") \
    for (int j = 0; j < 4; ++j) \
        qr[j] = (uint)QW[(size_t)(g8 + bk0 + j) * N + n0 + bn]; \
    scf = SC[(size_t)gg * N + n0 + bn]; \
    zf  = (float)QZ[(size_t)gg * N + n0 + bn]; }

#define OP_STAGE_A(AH, k0) { \
    gl_lds16(Xb + (k0) + aoff[0], (char*)(AH) + ldsAw); \
    gl_lds16(Xb + (k0) + aoff[1], (char*)(AH) + 4096 + ldsAw); \
    gl_lds16(Xb + (k0) + aoff[2], (char*)(AH) + 8192 + ldsAw); \
    gl_lds16(Xb + (k0) + aoff[3], (char*)(AH) + 12288 + ldsAw); }

#define OP_BWRITE(BT) { \
    ushort sch = f2h(scf); \
    float schf = h2f(sch); \
    ushort msc = f2h(-128.0f * schf); \
    ushort nzs = f2h(-(zf * schf)); \
    half2v S2 = {__builtin_bit_cast(_Float16, sch), __builtin_bit_cast(_Float16, sch)}; \
    half2v M2 = {__builtin_bit_cast(_Float16, msc), __builtin_bit_cast(_Float16, msc)}; \
    half2v Z2 = {__builtin_bit_cast(_Float16, nzs), __builtin_bit_cast(_Float16, nzs)}; \
    _Pragma("unroll") \
    for (int j = 0; j < 4; ++j) { \
        uint q = qr[j]; \
        uint xn = q & 0x0F0F0F0Fu; \
        uint yn = (q >> 4) & 0x0F0F0F0Fu; \
        uint4 dw; \
        uint W0 = __builtin_amdgcn_perm(yn, xn, 0x0C040C00u); \
        uint W1 = __builtin_amdgcn_perm(yn, xn, 0x0C050C01u); \
        uint W2 = __builtin_amdgcn_perm(yn, xn, 0x0C060C02u); \
        uint W3 = __builtin_amdgcn_perm(yn, xn, 0x0C070C03u); \
        uint e0 = (W0 << 3) | 0x58005800u; \
        uint e1 = (W1 << 3) | 0x58005800u; \
        uint e2 = (W2 << 3) | 0x58005800u; \
        uint e3 = (W3 << 3) | 0x58005800u; \
        half2v w0 = __builtin_bit_cast(half2v, e0) * S2 + M2; w0 = w0 + Z2; \
        half2v w1 = __builtin_bit_cast(half2v, e1) * S2 + M2; w1 = w1 + Z2; \
        half2v w2 = __builtin_bit_cast(half2v, e2) * S2 + M2; w2 = w2 + Z2; \
        half2v w3 = __builtin_bit_cast(half2v, e3) * S2 + M2; w3 = w3 + Z2; \
        dw.x = __builtin_bit_cast(uint, w0); \
        dw.y = __builtin_bit_cast(uint, w1); \
        dw.z = __builtin_bit_cast(uint, w2); \
        dw.w = __builtin_bit_cast(uint, w3); \
        *(uint4*)((char*)(BT) + bwoff[j]) = dw; \
    } }

#define OP_COMPUTE(AH, BT) { \
    _Pragma("unroll") \
    for (int ks = 0; ks < 2; ++ks) { \
        half8v av[4], bv[4]; \
        _Pragma("unroll") \
        for (int mf = 0; mf < 4; ++mf) \
            av[mf] = *(const half8v*)((const char*)(AH) + aroff[mf][ks]); \
        _Pragma("unroll") \
        for (int nf = 0; nf < 4; ++nf) \
            bv[nf] = *(const half8v*)((const char*)(BT) + broff[nf][ks]); \
        _Pragma("unroll") \
        for (int mf = 0; mf < 4; ++mf) \
            _Pragma("unroll") \
            for (int nf = 0; nf < 4; ++nf) \
                macc[mf][nf] = __builtin_amdgcn_mfma_f32_16x16x32_f16(av[mf], bv[nf], macc[mf][nf], 0, 0, 0); \
    } }

    OP_QW(0);
    OP_BWRITE(B0);
    OP_STAGE_A(A0, 0);
    OP_QW(1);
    WAIT_LGKM0;
    WAIT_VM(6);
    RAW_BARRIER;

    for (int g = 0; g < 31; ++g) {
        OP_STAGE_A(A1, (2 * g + 1) * 64);
        OP_COMPUTE(A0, B0);
        OP_BWRITE(B1);
        OP_QW(2 * g + 2);
        WAIT_LGKM0;
        WAIT_VM(6);
        RAW_BARRIER;
        OP_STAGE_A(A0, (2 * g + 2) * 64);
        OP_COMPUTE(A1, B1);
        OP_BWRITE(B0);
        OP_QW(2 * g + 3);
        WAIT_LGKM0;
        WAIT_VM(6);
        RAW_BARRIER;
    }
    OP_STAGE_A(A1, 63 * 64);
    OP_COMPUTE(A0, B0);
    OP_BWRITE(B1);
    WAIT_LGKM0;
    WAIT_VM(0);
    RAW_BARRIER;
    OP_COMPUTE(A1, B1);

#pragma unroll
    for (int mf = 0; mf < 4; ++mf)
#pragma unroll
        for (int r = 0; r < 4; ++r) {
            int row = m0 + wr * 64 + mf * 16 + lg * 4 + r;
#pragma unroll
            for (int nf = 0; nf < 4; ++nf)
                Y[(size_t)row * N + n0 + wc * 64 + nf * 16 + lr] = macc[mf][nf][r];
        }
#undef OP_QW
#undef OP_STAGE_A
#undef OP_BWRITE
#undef OP_COMPUTE
}

// ---------------------------------------------------------------------------
// Causal GQA flash attention, fp16 MFMA, swapped operands; dbuf K/V staging.
// exp2 softmax via RAW __builtin_amdgcn_exp2f (single v_exp_f32); Q carries
// log2e fold from qkv epilogue.
// ---------------------------------------------------------------------------
__global__ __launch_bounds__(256) void attn_mfma_kernel(
    const ushort* __restrict__ Qh,   // [S][NH*HD] fp16, roped, *log2e/sqrt(HD)
    const ushort* __restrict__ Kh,   // [S][NKV*HD] fp16, roped
    const ushort* __restrict__ Vt,   // [NKV*HD][S] fp16 (transposed)
    ushort* __restrict__ AO)         // [S][NH*HD] fp16
{
    __shared__ ushort Ks0[32 * 128];           // swz ^((row&7)<<4)
    __shared__ ushort Ks1[32 * 128];
    __shared__ ushort Vs0[128 * 32];           // swz ^(((dim>>1)&3)<<4)
    __shared__ ushort Vs1[128 * 32];
    __shared__ __align__(16) char PsB[4 * 1280];  // P: 16 rows x 80B per wave

    const int h  = blockIdx.x;
    const int qb = gridDim.y - 1 - blockIdx.y;   // long blocks dispatch first
    const int s0 = qb * 64;
    const int t  = threadIdx.x;
    const int w  = t >> 6;
    const int l  = t & 63;
    const int lg = l >> 4;
    const int lr = l & 15;
    const int kvh = h >> 2;
    const int qw = s0 + w * 16;
    const int q  = qw + lr;          // this lane's q-row

    half8v qf[4];
#pragma unroll
    for (int d = 0; d < 4; ++d) {
        size_t off = (size_t)q * (NH * HD) + h * HD + d * 32 + lg * 8;
        qf[d] = *(const half8v*)&Qh[off];
    }

    f32x4 o[8];
#pragma unroll
    for (int i = 0; i < 8; ++i) o[i] = f32x4{0.f, 0.f, 0.f, 0.f};
    float m = -1e30f, lsum = 0.f;
    char* pw = PsB + w * 1280;

#define ATTN_STAGE(KB, VB, k0) { \
    _Pragma("unroll") \
    for (int i = 0; i < 2; ++i) { \
        int slot = w * 128 + i * 64 + l; \
        int mr = slot >> 4, c = slot & 15; \
        size_t goff = (size_t)((k0) + mr) * (NKV * HD) + kvh * HD + ((c ^ (mr & 7)) * 8); \
        gl_lds16(Kh + goff, (char*)(KB) + (w * 128 + i * 64) * 16); \
    } \
    _Pragma("unroll") \
    for (int i = 0; i < 2; ++i) { \
        int slot = w * 128 + i * 64 + l; \
        int dim = slot >> 2, c = slot & 3; \
        size_t goff = (size_t)(kvh * HD + dim) * S_LEN + (k0) + ((c ^ ((dim >> 1) & 3)) * 8); \
        gl_lds16(Vt + goff, (char*)(VB) + (w * 128 + i * 64) * 16); \
    } }

#define ATTN_TILE(KSF, VSS, k0) \
    if ((k0) <= qw + 15) { \
        f32x4 s_[2]; \
        s_[0] = f32x4{0.f, 0.f, 0.f, 0.f}; \
        s_[1] = f32x4{0.f, 0.f, 0.f, 0.f}; \
        _Pragma("unroll") \
        for (int d = 0; d < 4; ++d) { \
            _Pragma("unroll") \
            for (int nt2 = 0; nt2 < 2; ++nt2) { \
                int row = nt2 * 16 + lr; \
                int off = row * 256 + ((d * 64 + lg * 16) ^ ((row & 7) << 4)); \
                half8v kf = *(const half8v*)((const char*)(KSF) + off); \
                s_[nt2] = __builtin_amdgcn_mfma_f32_16x16x32_f16(kf, qf[d], s_[nt2], 0, 0, 0); \
            } \
        } \
        float sv[8]; \
        _Pragma("unroll") \
        for (int nt2 = 0; nt2 < 2; ++nt2) \
            _Pragma("unroll") \
            for (int r = 0; r < 4; ++r) { \
                int kv = (k0) + nt2 * 16 + lg * 4 + r; \
                sv[nt2 * 4 + r] = (kv <= q) ? s_[nt2][r] : -1e30f; \
            } \
        float mx = sv[0]; \
        _Pragma("unroll") \
        for (int j = 1; j < 8; ++j) mx = fmaxf(mx, sv[j]); \
        mx = fmaxf(mx, __shfl_xor(mx, 16)); \
        mx = fmaxf(mx, __shfl_xor(mx, 32)); \
        float mnew = fmaxf(m, mx); \
        float resc = __builtin_amdgcn_exp2f(m - mnew); \
        m = mnew; \
        float p_[8], ps = 0.f; \
        _Pragma("unroll") \
        for (int j = 0; j < 8; ++j) { p_[j] = __builtin_amdgcn_exp2f(sv[j] - mnew); ps += p_[j]; } \
        ps += __shfl_xor(ps, 16); \
        ps += __shfl_xor(ps, 32); \
        lsum = lsum * resc + ps; \
        _Pragma("unroll") \
        for (int dt = 0; dt < 8; ++dt) \
            _Pragma("unroll") \
            for (int r = 0; r < 4; ++r) o[dt][r] *= resc; \
        uint2 w0_ = {pk2(f2h(p_[0]), f2h(p_[1])), pk2(f2h(p_[2]), f2h(p_[3]))}; \
        uint2 w1_ = {pk2(f2h(p_[4]), f2h(p_[5])), pk2(f2h(p_[6]), f2h(p_[7]))}; \
        *(uint2*)(pw + lr * 80 + lg * 8)      = w0_; \
        *(uint2*)(pw + lr * 80 + 32 + lg * 8) = w1_; \
        asm volatile("s_waitcnt lgkmcnt(0)" ::: "memory"); \
        half8v pf = *(const half8v*)(pw + lr * 80 + lg * 16); \
        _Pragma("unroll") \
        for (int dt = 0; dt < 8; ++dt) { \
            int dim = dt * 16 + lr; \
            half8v vf = *(const half8v*)((const char*)(VSS) + dim * 64 + ((lg * 16) ^ (((dim >> 1) & 3) << 4))); \
            o[dt] = __builtin_amdgcn_mfma_f32_16x16x32_f16(vf, pf, o[dt], 0, 0, 0); \
        } \
    }

    const int ntiles = qb * 2 + 2;   // always even

    ATTN_STAGE(Ks0, Vs0, 0);
    WAIT_VM(0);
    RAW_BARRIER;

    for (int kt = 0; kt < ntiles; kt += 2) {
        if (kt + 1 < ntiles) ATTN_STAGE(Ks1, Vs1, (kt + 1) * 32);
        ATTN_TILE(Ks0, Vs0, kt * 32);
        WAIT_VM(0);
        RAW_BARRIER;
        if (kt + 2 < ntiles) ATTN_STAGE(Ks0, Vs0, (kt + 2) * 32);
        ATTN_TILE(Ks1, Vs1, (kt + 1) * 32);
        WAIT_VM(0);
        RAW_BARRIER;
    }

    float inv = 1.f / lsum;
    ushort* dst = &AO[(size_t)q * (NH * HD) + h * HD];
#pragma unroll
    for (int dt = 0; dt < 8; ++dt) {
        uint2 ov = {pk2(f2h(o[dt][0] * inv), f2h(o[dt][1] * inv)),
                    pk2(f2h(o[dt][2] * inv), f2h(o[dt][3] * inv))};
        *(uint2*)(dst + dt * 16 + lg * 4) = ov;
    }
#undef ATTN_STAGE
#undef ATTN_TILE
}

// ---------------------------------------------------------------------------
extern "C" void kernel_launch(void* const* d_in, const int* in_sizes, int n_in,
                              void* d_out, int out_size, void* d_ws, size_t ws_size,
                              hipStream_t stream)
{
    const float* x    = (const float*)d_in[0];
    const float* cosb = (const float*)d_in[1];
    const float* sinb = (const float*)d_in[2];
    const float* q_sc = (const float*)d_in[3];
    const float* q_b  = (const float*)d_in[4];
    const float* k_sc = (const float*)d_in[5];
    const float* k_b  = (const float*)d_in[6];
    const float* v_sc = (const float*)d_in[7];
    const float* v_b  = (const float*)d_in[8];
    const float* o_sc = (const float*)d_in[9];
    const int* q_qw   = (const int*)d_in[10];
    const int* q_qz   = (const int*)d_in[11];
    const int* k_qw   = (const int*)d_in[12];
    const int* k_qz   = (const int*)d_in[13];
    const int* v_qw   = (const int*)d_in[14];
    const int* v_qz   = (const int*)d_in[15];
    const int* o_qw   = (const int*)d_in[16];
    const int* o_qz   = (const int*)d_in[17];
    float* out = (float*)d_out;

    // ws layout (MB):
    //   0..10   Xf16   [AOf16 (16MB) aliases 0..16 after qkv11]
    //   10..40  WT fp16 [6144][2560]  (dead after qkv11)
    //   40..56  Qf | 56..60 Kf | 60..64 Vrm | 64..68 VfT
    char* ws = (char*)d_ws;
    ushort* Xf   = (ushort*)ws;
    ushort* AOf  = (ushort*)ws;                                  // alias
    ushort* WT   = (ushort*)(ws + (size_t)10 * 1024 * 1024);
    ushort* Qf   = (ushort*)(ws + (size_t)40 * 1024 * 1024);
    ushort* Kf   = (ushort*)(ws + (size_t)56 * 1024 * 1024);
    ushort* Vrm  = (ushort*)(ws + (size_t)60 * 1024 * 1024);
    ushort* VfT  = (ushort*)(ws + (size_t)64 * 1024 * 1024);

    prep_kernel<<<4480, 256, 0, stream>>>(
        x, Xf,
        q_qw, q_sc, q_qz, k_qw, k_sc, k_qz, v_qw, v_sc, v_qz, WT);

    qkv11_kernel<<<768, 256, 0, stream>>>(
        Xf, WT, q_b, k_b, v_b, cosb, sinb, Qf, Kf, Vrm);

    vtrans_kernel<<<dim3(S_LEN / 64, (NKV * HD) / 64), 256, 0, stream>>>(Vrm, VfT);

    attn_mfma_kernel<<<dim3(NH, S_LEN / 64), 256, 0, stream>>>(Qf, Kf, VfT, AOf);

    oproj8_kernel<<<320, 256, 0, stream>>>(
        AOf, o_qw, o_sc, o_qz, out);
}

// Round 23
// 254.304 us; speedup vs baseline: 1.0851x; 1.0143x over previous
//
#include <hip/hip_runtime.h>
#include <hip/hip_bf16.h>
#include <cstdint>

#define S_LEN 2048
#define HIDDEN 2560
#define NH 32
#define NKV 8
#define HD 128
#define GS 128

typedef __attribute__((ext_vector_type(8))) _Float16 half8v;    // 8 x fp16
typedef __attribute__((ext_vector_type(2))) _Float16 half2v;    // 2 x fp16
typedef __attribute__((ext_vector_type(4))) float f32x4;
typedef unsigned int uint;
typedef unsigned short ushort;

__device__ inline ushort f2h(float f) {
    _Float16 h = (_Float16)f;
    return __builtin_bit_cast(ushort, h);
}
__device__ inline float h2f(ushort u) {
    return (float)__builtin_bit_cast(_Float16, u);
}
__device__ inline uint pk2(ushort a, ushort b) { return (uint)a | ((uint)b << 16); }

// async global->LDS, 16B per lane; lds base must be wave-uniform
__device__ __attribute__((always_inline)) inline void gl_lds16(const void* g, void* l) {
    __builtin_amdgcn_global_load_lds(
        (const __attribute__((address_space(1))) unsigned int*)g,
        (__attribute__((address_space(3))) unsigned int*)l, 16, 0, 0);
}

#define WAIT_LGKM0  asm volatile("s_waitcnt lgkmcnt(0)" ::: "memory")
#define WAIT_VM(N)  asm volatile("s_waitcnt vmcnt(" #N ")" ::: "memory")
#define RAW_BARRIER { __builtin_amdgcn_s_barrier(); __builtin_amdgcn_sched_barrier(0); }

// ===========================================================================
// Merged prepass: blocks [0,2560) convert X->fp16 (flat, 2048 els/block);
// blocks [2560,4480) dequant QKV weights -> fp16 transposed WT[6144][2560].
// ===========================================================================
__global__ __launch_bounds__(256) void prep_kernel(
    const float* __restrict__ X, ushort* __restrict__ Xf,
    const int* __restrict__ q_qw, const float* __restrict__ q_sc, const int* __restrict__ q_qz,
    const int* __restrict__ k_qw, const float* __restrict__ k_sc, const int* __restrict__ k_qz,
    const int* __restrict__ v_qw, const float* __restrict__ v_sc, const int* __restrict__ v_qz,
    ushort* __restrict__ WT)
{
    __shared__ __align__(16) char Ts[16384];
    const int bid = blockIdx.x;
    const int t   = threadIdx.x;

    if (bid < 2560) {
        const size_t base = (size_t)bid * 2048 + (size_t)t * 8;
        float4 a = *(const float4*)&X[base];
        float4 b = *(const float4*)&X[base + 4];
        uint4 hw = {pk2(f2h(a.x), f2h(a.y)), pk2(f2h(a.z), f2h(a.w)),
                    pk2(f2h(b.x), f2h(b.y)), pk2(f2h(b.z), f2h(b.w))};
        *(uint4*)&Xf[base] = hw;
        return;
    }

    const int b2 = bid - 2560;
    const int bx = b2 % 96;
    const int kt = b2 / 96;

    int nloc0, wtbase, Nw;
    const int* QW; const float* SC; const int* QZ;
    if (bx < 64)      { Nw = NH * HD;  nloc0 = bx * 64;        wtbase = bx * 64;
                        QW = q_qw; SC = q_sc; QZ = q_qz; }
    else if (bx < 80) { Nw = NKV * HD; nloc0 = (bx - 64) * 64; wtbase = 4096 + nloc0;
                        QW = k_qw; SC = k_sc; QZ = k_qz; }
    else              { Nw = NKV * HD; nloc0 = (bx - 80) * 64; wtbase = 5120 + nloc0;
                        QW = v_qw; SC = v_sc; QZ = v_qz; }

    const int k80 = kt * 16;
    const int nn  = t & 63;
    const float scf = SC[(size_t)kt * Nw + nloc0 + nn];
    const float zf  = (float)QZ[(size_t)kt * Nw + nloc0 + nn];
    ushort sch = f2h(scf);
    float schf = h2f(sch);
    ushort msc = f2h(-128.0f * schf);   // exact exponent shift
    ushort nzs = f2h(-(zf * schf));
    half2v S2 = {__builtin_bit_cast(_Float16, sch), __builtin_bit_cast(_Float16, sch)};
    half2v M2 = {__builtin_bit_cast(_Float16, msc), __builtin_bit_cast(_Float16, msc)};
    half2v Z2 = {__builtin_bit_cast(_Float16, nzs), __builtin_bit_cast(_Float16, nzs)};

#pragma unroll
    for (int i = 0; i < 4; ++i) {
        int kw = i * 4 + (t >> 6);
        uint q = (uint)QW[(size_t)(k80 + kw) * Nw + nloc0 + nn];
        uint xn = q & 0x0F0F0F0Fu;
        uint yn = (q >> 4) & 0x0F0F0F0Fu;
        uint W0 = __builtin_amdgcn_perm(yn, xn, 0x0C040C00u);
        uint W1 = __builtin_amdgcn_perm(yn, xn, 0x0C050C01u);
        uint W2 = __builtin_amdgcn_perm(yn, xn, 0x0C060C02u);
        uint W3 = __builtin_amdgcn_perm(yn, xn, 0x0C070C03u);
        uint e0 = (W0 << 3) | 0x58005800u;
        uint e1 = (W1 << 3) | 0x58005800u;
        uint e2 = (W2 << 3) | 0x58005800u;
        uint e3 = (W3 << 3) | 0x58005800u;
        half2v w0 = __builtin_bit_cast(half2v, e0) * S2 + M2; w0 = w0 + Z2;
        half2v w1 = __builtin_bit_cast(half2v, e1) * S2 + M2; w1 = w1 + Z2;
        half2v w2 = __builtin_bit_cast(half2v, e2) * S2 + M2; w2 = w2 + Z2;
        half2v w3 = __builtin_bit_cast(half2v, e3) * S2 + M2; w3 = w3 + Z2;
        uint4 dw = {__builtin_bit_cast(uint, w0), __builtin_bit_cast(uint, w1),
                    __builtin_bit_cast(uint, w2), __builtin_bit_cast(uint, w3)};
        *(uint4*)(Ts + nn * 256 + ((kw * 16) ^ ((nn & 7) << 4))) = dw;
    }
    __syncthreads();
    const int kc = t & 15;
#pragma unroll
    for (int i = 0; i < 4; ++i) {
        int nr = i * 16 + (t >> 4);
        uint4 v = *(const uint4*)(Ts + nr * 256 + ((kc * 16) ^ ((nr & 7) << 4)));
        *(uint4*)&WT[(size_t)(wtbase + nr) * HIDDEN + kt * 128 + kc * 8] = v;
    }
}

// ===========================================================================
// Fused Q/K/V MFMA GEMM on fp16 WT (N-persistent XCD swizzle).
// Q scale folds log2(e). NEW: V epilogue writes VfT DIRECTLY (transposed)
// via an LDS exchange — eliminates the Vrm buffer + vtrans kernel.
// ===========================================================================
__global__ __launch_bounds__(256) void qkv12_kernel(
    const ushort* __restrict__ Xf, const ushort* __restrict__ WT,
    const float* __restrict__ q_b, const float* __restrict__ k_b,
    const float* __restrict__ v_b,
    const float* __restrict__ cosb, const float* __restrict__ sinb,
    ushort* __restrict__ Qf, ushort* __restrict__ Kf,
    ushort* __restrict__ VfT)
{
    __shared__ __align__(16) char LDSB[65536];
    ushort* A0 = (ushort*)(LDSB);
    ushort* A1 = (ushort*)(LDSB + 16384);
    ushort* B0 = (ushort*)(LDSB + 32768);
    ushort* B1 = (ushort*)(LDSB + 49152);

    const int t  = threadIdx.x;
    const int w  = t >> 6;
    const int l  = t & 63;
    const int lg = l >> 4;
    const int lr = l & 15;
    const int wr = w >> 1;
    const int wc = w & 1;
    const int K  = HIDDEN;

    const int bid  = blockIdx.x;
    const int xcd  = bid & 7;
    const int j    = bid >> 3;
    const int nblk = xcd * 6 + (j >> 4);
    const int m0   = (j & 15) * 128;
    const int wtrow = nblk * 128;

    int region, nbase;
    const float* BI;
    if (nblk < 32)      { region = 0; nbase = nblk * 128;        BI = q_b; }
    else if (nblk < 40) { region = 1; nbase = (nblk - 32) * 128; BI = k_b; }
    else                { region = 2; nbase = (nblk - 40) * 128; BI = v_b; }

    const int ldsAw = w * 1024;
    size_t aoff[4], boff[4];
#pragma unroll
    for (int i = 0; i < 4; ++i) {
        int slot = i * 256 + t;
        int rm = slot >> 3, rc = slot & 7;
        aoff[i] = (size_t)(m0 + rm) * K + (size_t)((rc ^ (rm & 7)) * 8);
        boff[i] = (size_t)(wtrow + rm) * K + (size_t)((rc ^ (rm & 7)) * 8);
    }

    int ncm[4];
#pragma unroll
    for (int nf = 0; nf < 4; ++nf)
        ncm[nf] = wc * 32 + (nf & 1) * 16 + lr + ((nf & 2) ? 64 : 0);

    const int xorA = (lr & 7) << 4;
    int aroff[4][2], broff[4][2];
#pragma unroll
    for (int mf = 0; mf < 4; ++mf)
#pragma unroll
        for (int ks = 0; ks < 2; ++ks)
            aroff[mf][ks] = (((wr * 64 + mf * 16 + lr) * 128) + lg * 16 + ks * 64) ^ xorA;
#pragma unroll
    for (int nf = 0; nf < 4; ++nf)
#pragma unroll
        for (int ks = 0; ks < 2; ++ks)
            broff[nf][ks] = ((ncm[nf] * 128) + lg * 16 + ks * 64) ^ xorA;

    f32x4 macc[4][4];
#pragma unroll
    for (int mf = 0; mf < 4; ++mf)
#pragma unroll
        for (int nf = 0; nf < 4; ++nf) macc[mf][nf] = f32x4{0.f, 0.f, 0.f, 0.f};

#define QKV_STAGE(AH, BH, k0) { \
    gl_lds16(Xf + (k0) + aoff[0], (char*)(AH) + ldsAw); \
    gl_lds16(Xf + (k0) + aoff[1], (char*)(AH) + 4096 + ldsAw); \
    gl_lds16(Xf + (k0) + aoff[2], (char*)(AH) + 8192 + ldsAw); \
    gl_lds16(Xf + (k0) + aoff[3], (char*)(AH) + 12288 + ldsAw); \
    gl_lds16(WT + (k0) + boff[0], (char*)(BH) + ldsAw); \
    gl_lds16(WT + (k0) + boff[1], (char*)(BH) + 4096 + ldsAw); \
    gl_lds16(WT + (k0) + boff[2], (char*)(BH) + 8192 + ldsAw); \
    gl_lds16(WT + (k0) + boff[3], (char*)(BH) + 12288 + ldsAw); }

#define QKV_COMPUTE(AH, BT) { \
    _Pragma("unroll") \
    for (int ks = 0; ks < 2; ++ks) { \
        half8v av[4], bv[4]; \
        _Pragma("unroll") \
        for (int mf = 0; mf < 4; ++mf) \
            av[mf] = *(const half8v*)((const char*)(AH) + aroff[mf][ks]); \
        _Pragma("unroll") \
        for (int nf = 0; nf < 4; ++nf) \
            bv[nf] = *(const half8v*)((const char*)(BT) + broff[nf][ks]); \
        _Pragma("unroll") \
        for (int mf = 0; mf < 4; ++mf) \
            _Pragma("unroll") \
            for (int nf = 0; nf < 4; ++nf) \
                macc[mf][nf] = __builtin_amdgcn_mfma_f32_16x16x32_f16(av[mf], bv[nf], macc[mf][nf], 0, 0, 0); \
    } }

    QKV_STAGE(A0, B0, 0);
    WAIT_VM(0);
    RAW_BARRIER;

    for (int g = 0; g < 19; ++g) {
        QKV_STAGE(A1, B1, (2 * g + 1) * 64);
        QKV_COMPUTE(A0, B0);
        WAIT_VM(0);
        RAW_BARRIER;
        QKV_STAGE(A0, B0, (2 * g + 2) * 64);
        QKV_COMPUTE(A1, B1);
        WAIT_VM(0);
        RAW_BARRIER;
    }
    QKV_STAGE(A1, B1, 39 * 64);
    QKV_COMPUTE(A0, B0);
    WAIT_VM(0);
    RAW_BARRIER;
    QKV_COMPUTE(A1, B1);

#pragma unroll
    for (int nf = 0; nf < 4; ++nf) {
        float bv = BI[nbase + ncm[nf]];
#pragma unroll
        for (int mf = 0; mf < 4; ++mf)
#pragma unroll
            for (int r = 0; r < 4; ++r) macc[mf][nf][r] += bv;
    }

    if (region == 2) {
        // ---- V: transpose in LDS (all compute done; barrier-protect reuse) ----
        WAIT_LGKM0;
        RAW_BARRIER;                       // all waves done reading A1/B1
        ushort* EP = (ushort*)LDSB;        // [128][130] padded
#pragma unroll
        for (int mf = 0; mf < 4; ++mf)
#pragma unroll
            for (int r = 0; r < 4; ++r) {
                int row = wr * 64 + mf * 16 + lg * 4 + r;
#pragma unroll
                for (int nf = 0; nf < 4; ++nf)
                    EP[row * 130 + ncm[nf]] = f2h(macc[mf][nf][r]);
            }
        WAIT_LGKM0;
        RAW_BARRIER;
        const int c   = t >> 1;            // 0..127: column of tile = VfT row
        const int seg = (t & 1) * 64;      // half of the m-band
        ushort* dst = &VfT[(size_t)(nbase + c) * S_LEN + m0 + seg];
#pragma unroll
        for (int g8 = 0; g8 < 8; ++g8) {
            ushort buf[8];
#pragma unroll
            for (int jj = 0; jj < 8; ++jj)
                buf[jj] = EP[(seg + g8 * 8 + jj) * 130 + c];
            *(uint4*)(dst + g8 * 8) = *(uint4*)buf;
        }
    } else {
        ushort* OF = (region == 0) ? Qf : Kf;
        const int No = (region == 0) ? NH * HD : NKV * HD;
        // Q scale folds 1/sqrt(HD) AND log2(e) -> attention uses exp2 directly
        const float osc = (region == 0)
            ? 0.08838834764831845f * 1.44269504088896341f : 1.0f;
#pragma unroll
        for (int mf = 0; mf < 4; ++mf)
#pragma unroll
            for (int r = 0; r < 4; ++r) {
                int row = m0 + wr * 64 + mf * 16 + lg * 4 + r;
                const float* cb = &cosb[(size_t)row * HD];
                const float* sb = &sinb[(size_t)row * HD];
#pragma unroll
                for (int nf = 0; nf < 2; ++nf) {
                    int d = wc * 32 + nf * 16 + lr;
                    float a = macc[mf][nf][r];
                    float b = macc[mf][nf + 2][r];
                    float o1 = (a * cb[d]      - b * sb[d])      * osc;
                    float o2 = (b * cb[d + 64] + a * sb[d + 64]) * osc;
                    OF[(size_t)row * No + nbase + d]      = f2h(o1);
                    OF[(size_t)row * No + nbase + d + 64] = f2h(o2);
                }
            }
    }
#undef QKV_STAGE
#undef QKV_COMPUTE
}

// ===========================================================================
// O-projection (unchanged — control).
// ===========================================================================
__global__ __launch_bounds__(256) void oproj8_kernel(
    const ushort* __restrict__ Xb, const int* __restrict__ QW,
    const float* __restrict__ SC, const int* __restrict__ QZ,
    float* __restrict__ Y)
{
    __shared__ __align__(16) char LDSB[65536];
    ushort* A0 = (ushort*)(LDSB);
    ushort* A1 = (ushort*)(LDSB + 16384);
    ushort* B0 = (ushort*)(LDSB + 32768);
    ushort* B1 = (ushort*)(LDSB + 49152);

    const int t  = threadIdx.x;
    const int w  = t >> 6;
    const int l  = t & 63;
    const int lg = l >> 4;
    const int lr = l & 15;
    const int wr = w >> 1;
    const int wc = w & 1;
    const int K  = NH * HD;
    const int N  = HIDDEN;

    const int bid = blockIdx.x;
    const int swz = (bid & 7) * 40 + (bid >> 3);
    const int n0  = (swz % 20) * 128;
    const int m0  = (swz / 20) * 128;

    const int ldsAw = w * 1024;
    size_t aoff[4];
#pragma unroll
    for (int i = 0; i < 4; ++i) {
        int slot = i * 256 + t;
        int am = slot >> 3, ac = slot & 7;
        aoff[i] = (size_t)(m0 + am) * K + (size_t)((ac ^ (am & 7)) * 8);
    }
    const int bn  = t & 127;
    const int bk0 = (t >> 7) * 4;
    int bwoff[4];
#pragma unroll
    for (int j = 0; j < 4; ++j)
        bwoff[j] = (bn * 128 + (bk0 + j) * 16) ^ ((bn & 7) << 4);

    const int xorA = (lr & 7) << 4;
    int aroff[4][2], broff[4][2];
#pragma unroll
    for (int mf = 0; mf < 4; ++mf)
#pragma unroll
        for (int ks = 0; ks < 2; ++ks)
            aroff[mf][ks] = (((wr * 64 + mf * 16 + lr) * 128) + lg * 16 + ks * 64) ^ xorA;
#pragma unroll
    for (int nf = 0; nf < 4; ++nf)
#pragma unroll
        for (int ks = 0; ks < 2; ++ks)
            broff[nf][ks] = (((wc * 64 + nf * 16 + lr) * 128) + lg * 16 + ks * 64) ^ xorA;

    f32x4 macc[4][4];
#pragma unroll
    for (int mf = 0; mf < 4; ++mf)
#pragma unroll
        for (int nf = 0; nf < 4; ++nf) macc[mf][nf] = f32x4{0.f, 0.f, 0.f, 0.f};
    uint qr[4];
    float scf, zf;

#define OP_QW(tile) { int g8 = (tile) * 8; int gg = (tile) >> 1; \
    _Pragma("unroll") \
    for (int j = 0; j < 4; ++j) \
        qr[j] = (uint)QW[(size_t)(g8 + bk0 + j) * N + n0 + bn]; \
    scf = SC[(size_t)gg * N + n0 + bn]; \
    zf  = (float)QZ[(size_t)gg * N + n0 + bn]; }

#define OP_STAGE_A(AH, k0) { \
    gl_lds16(Xb + (k0) + aoff[0], (char*)(AH) + ldsAw); \
    gl_lds16(Xb + (k0) + aoff[1], (char*)(AH) + 4096 + ldsAw); \
    gl_lds16(Xb + (k0) + aoff[2], (char*)(AH) + 8192 + ldsAw); \
    gl_lds16(Xb + (k0) + aoff[3], (char*)(AH) + 12288 + ldsAw); }

#define OP_BWRITE(BT) { \
    ushort sch = f2h(scf); \
    float schf = h2f(sch); \
    ushort msc = f2h(-128.0f * schf); \
    ushort nzs = f2h(-(zf * schf)); \
    half2v S2 = {__builtin_bit_cast(_Float16, sch), __builtin_bit_cast(_Float16, sch)}; \
    half2v M2 = {__builtin_bit_cast(_Float16, msc), __builtin_bit_cast(_Float16, msc)}; \
    half2v Z2 = {__builtin_bit_cast(_Float16, nzs), __builtin_bit_cast(_Float16, nzs)}; \
    _Pragma("unroll") \
    for (int j = 0; j < 4; ++j) { \
        uint q = qr[j]; \
        uint xn = q & 0x0F0F0F0Fu; \
        uint yn = (q >> 4) & 0x0F0F0F0Fu; \
        uint4 dw; \
        uint W0 = __builtin_amdgcn_perm(yn, xn, 0x0C040C00u); \
        uint W1 = __builtin_amdgcn_perm(yn, xn, 0x0C050C01u); \
        uint W2 = __builtin_amdgcn_perm(yn, xn, 0x0C060C02u); \
        uint W3 = __builtin_amdgcn_perm(yn, xn, 0x0C070C03u); \
        uint e0 = (W0 << 3) | 0x58005800u; \
        uint e1 = (W1 << 3) | 0x58005800u; \
        uint e2 = (W2 << 3) | 0x58005800u; \
        uint e3 = (W3 << 3) | 0x58005800u; \
        half2v w0 = __builtin_bit_cast(half2v, e0) * S2 + M2; w0 = w0 + Z2; \
        half2v w1 = __builtin_bit_cast(half2v, e1) * S2 + M2; w1 = w1 + Z2; \
        half2v w2 = __builtin_bit_cast(half2v, e2) * S2 + M2; w2 = w2 + Z2; \
        half2v w3 = __builtin_bit_cast(half2v, e3) * S2 + M2; w3 = w3 + Z2; \
        dw.x = __builtin_bit_cast(uint, w0); \
        dw.y = __builtin_bit_cast(uint, w1); \
        dw.z = __builtin_bit_cast(uint, w2); \
        dw.w = __builtin_bit_cast(uint, w3); \
        *(uint4*)((char*)(BT) + bwoff[j]) = dw; \
    } }

#define OP_COMPUTE(AH, BT) { \
    _Pragma("unroll") \
    for (int ks = 0; ks < 2; ++ks) { \
        half8v av[4], bv[4]; \
        _Pragma("unroll") \
        for (int mf = 0; mf < 4; ++mf) \
            av[mf] = *(const half8v*)((const char*)(AH) + aroff[mf][ks]); \
        _Pragma("unroll") \
        for (int nf = 0; nf < 4; ++nf) \
            bv[nf] = *(const half8v*)((const char*)(BT) + broff[nf][ks]); \
        _Pragma("unroll") \
        for (int mf = 0; mf < 4; ++mf) \
            _Pragma("unroll") \
            for (int nf = 0; nf < 4; ++nf) \
                macc[mf][nf] = __builtin_amdgcn_mfma_f32_16x16x32_f16(av[mf], bv[nf], macc[mf][nf], 0, 0, 0); \
    } }

    OP_QW(0);
    OP_BWRITE(B0);
    OP_STAGE_A(A0, 0);
    OP_QW(1);
    WAIT_LGKM0;
    WAIT_VM(6);
    RAW_BARRIER;

    for (int g = 0; g < 31; ++g) {
        OP_STAGE_A(A1, (2 * g + 1) * 64);
        OP_COMPUTE(A0, B0);
        OP_BWRITE(B1);
        OP_QW(2 * g + 2);
        WAIT_LGKM0;
        WAIT_VM(6);
        RAW_BARRIER;
        OP_STAGE_A(A0, (2 * g + 2) * 64);
        OP_COMPUTE(A1, B1);
        OP_BWRITE(B0);
        OP_QW(2 * g + 3);
        WAIT_LGKM0;
        WAIT_VM(6);
        RAW_BARRIER;
    }
    OP_STAGE_A(A1, 63 * 64);
    OP_COMPUTE(A0, B0);
    OP_BWRITE(B1);
    WAIT_LGKM0;
    WAIT_VM(0);
    RAW_BARRIER;
    OP_COMPUTE(A1, B1);

#pragma unroll
    for (int mf = 0; mf < 4; ++mf)
#pragma unroll
        for (int r = 0; r < 4; ++r) {
            int row = m0 + wr * 64 + mf * 16 + lg * 4 + r;
#pragma unroll
            for (int nf = 0; nf < 4; ++nf)
                Y[(size_t)row * N + n0 + wc * 64 + nf * 16 + lr] = macc[mf][nf][r];
        }
#undef OP_QW
#undef OP_STAGE_A
#undef OP_BWRITE
#undef OP_COMPUTE
}

// ---------------------------------------------------------------------------
// Causal GQA flash attention (unchanged round 22 — verified 89 us).
// ---------------------------------------------------------------------------
__global__ __launch_bounds__(256) void attn_mfma_kernel(
    const ushort* __restrict__ Qh,   // [S][NH*HD] fp16, roped, *log2e/sqrt(HD)
    const ushort* __restrict__ Kh,   // [S][NKV*HD] fp16, roped
    const ushort* __restrict__ Vt,   // [NKV*HD][S] fp16 (transposed)
    ushort* __restrict__ AO)         // [S][NH*HD] fp16
{
    __shared__ ushort Ks0[32 * 128];           // swz ^((row&7)<<4)
    __shared__ ushort Ks1[32 * 128];
    __shared__ ushort Vs0[128 * 32];           // swz ^(((dim>>1)&3)<<4)
    __shared__ ushort Vs1[128 * 32];
    __shared__ __align__(16) char PsB[4 * 1280];  // P: 16 rows x 80B per wave

    const int h  = blockIdx.x;
    const int qb = gridDim.y - 1 - blockIdx.y;   // long blocks dispatch first
    const int s0 = qb * 64;
    const int t  = threadIdx.x;
    const int w  = t >> 6;
    const int l  = t & 63;
    const int lg = l >> 4;
    const int lr = l & 15;
    const int kvh = h >> 2;
    const int qw = s0 + w * 16;
    const int q  = qw + lr;          // this lane's q-row

    half8v qf[4];
#pragma unroll
    for (int d = 0; d < 4; ++d) {
        size_t off = (size_t)q * (NH * HD) + h * HD + d * 32 + lg * 8;
        qf[d] = *(const half8v*)&Qh[off];
    }

    f32x4 o[8];
#pragma unroll
    for (int i = 0; i < 8; ++i) o[i] = f32x4{0.f, 0.f, 0.f, 0.f};
    float m = -1e30f, lsum = 0.f;
    char* pw = PsB + w * 1280;

#define ATTN_STAGE(KB, VB, k0) { \
    _Pragma("unroll") \
    for (int i = 0; i < 2; ++i) { \
        int slot = w * 128 + i * 64 + l; \
        int mr = slot >> 4, c = slot & 15; \
        size_t goff = (size_t)((k0) + mr) * (NKV * HD) + kvh * HD + ((c ^ (mr & 7)) * 8); \
        gl_lds16(Kh + goff, (char*)(KB) + (w * 128 + i * 64) * 16); \
    } \
    _Pragma("unroll") \
    for (int i = 0; i < 2; ++i) { \
        int slot = w * 128 + i * 64 + l; \
        int dim = slot >> 2, c = slot & 3; \
        size_t goff = (size_t)(kvh * HD + dim) * S_LEN + (k0) + ((c ^ ((dim >> 1) & 3)) * 8); \
        gl_lds16(Vt + goff, (char*)(VB) + (w * 128 + i * 64) * 16); \
    } }

#define ATTN_TILE(KSF, VSS, k0) \
    if ((k0) <= qw + 15) { \
        f32x4 s_[2]; \
        s_[0] = f32x4{0.f, 0.f, 0.f, 0.f}; \
        s_[1] = f32x4{0.f, 0.f, 0.f, 0.f}; \
        _Pragma("unroll") \
        for (int d = 0; d < 4; ++d) { \
            _Pragma("unroll") \
            for (int nt2 = 0; nt2 < 2; ++nt2) { \
                int row = nt2 * 16 + lr; \
                int off = row * 256 + ((d * 64 + lg * 16) ^ ((row & 7) << 4)); \
                half8v kf = *(const half8v*)((const char*)(KSF) + off); \
                s_[nt2] = __builtin_amdgcn_mfma_f32_16x16x32_f16(kf, qf[d], s_[nt2], 0, 0, 0); \
            } \
        } \
        float sv[8]; \
        _Pragma("unroll") \
        for (int nt2 = 0; nt2 < 2; ++nt2) \
            _Pragma("unroll") \
            for (int r = 0; r < 4; ++r) { \
                int kv = (k0) + nt2 * 16 + lg * 4 + r; \
                sv[nt2 * 4 + r] = (kv <= q) ? s_[nt2][r] : -1e30f; \
            } \
        float mx = sv[0]; \
        _Pragma("unroll") \
        for (int j = 1; j < 8; ++j) mx = fmaxf(mx, sv[j]); \
        mx = fmaxf(mx, __shfl_xor(mx, 16)); \
        mx = fmaxf(mx, __shfl_xor(mx, 32)); \
        float mnew = fmaxf(m, mx); \
        float resc = __builtin_amdgcn_exp2f(m - mnew); \
        m = mnew; \
        float p_[8], ps = 0.f; \
        _Pragma("unroll") \
        for (int j = 0; j < 8; ++j) { p_[j] = __builtin_amdgcn_exp2f(sv[j] - mnew); ps += p_[j]; } \
        ps += __shfl_xor(ps, 16); \
        ps += __shfl_xor(ps, 32); \
        lsum = lsum * resc + ps; \
        _Pragma("unroll") \
        for (int dt = 0; dt < 8; ++dt) \
            _Pragma("unroll") \
            for (int r = 0; r < 4; ++r) o[dt][r] *= resc; \
        uint2 w0_ = {pk2(f2h(p_[0]), f2h(p_[1])), pk2(f2h(p_[2]), f2h(p_[3]))}; \
        uint2 w1_ = {pk2(f2h(p_[4]), f2h(p_[5])), pk2(f2h(p_[6]), f2h(p_[7]))}; \
        *(uint2*)(pw + lr * 80 + lg * 8)      = w0_; \
        *(uint2*)(pw + lr * 80 + 32 + lg * 8) = w1_; \
        asm volatile("s_waitcnt lgkmcnt(0)" ::: "memory"); \
        half8v pf = *(const half8v*)(pw + lr * 80 + lg * 16); \
        _Pragma("unroll") \
        for (int dt = 0; dt < 8; ++dt) { \
            int dim = dt * 16 + lr; \
            half8v vf = *(const half8v*)((const char*)(VSS) + dim * 64 + ((lg * 16) ^ (((dim >> 1) & 3) << 4))); \
            o[dt] = __builtin_amdgcn_mfma_f32_16x16x32_f16(vf, pf, o[dt], 0, 0, 0); \
        } \
    }

    const int ntiles = qb * 2 + 2;   // always even

    ATTN_STAGE(Ks0, Vs0, 0);
    WAIT_VM(0);
    RAW_BARRIER;

    for (int kt = 0; kt < ntiles; kt += 2) {
        if (kt + 1 < ntiles) ATTN_STAGE(Ks1, Vs1, (kt + 1) * 32);
        ATTN_TILE(Ks0, Vs0, kt * 32);
        WAIT_VM(0);
        RAW_BARRIER;
        if (kt + 2 < ntiles) ATTN_STAGE(Ks0, Vs0, (kt + 2) * 32);
        ATTN_TILE(Ks1, Vs1, (kt + 1) * 32);
        WAIT_VM(0);
        RAW_BARRIER;
    }

    float inv = 1.f / lsum;
    ushort* dst = &AO[(size_t)q * (NH * HD) + h * HD];
#pragma unroll
    for (int dt = 0; dt < 8; ++dt) {
        uint2 ov = {pk2(f2h(o[dt][0] * inv), f2h(o[dt][1] * inv)),
                    pk2(f2h(o[dt][2] * inv), f2h(o[dt][3] * inv))};
        *(uint2*)(dst + dt * 16 + lg * 4) = ov;
    }
#undef ATTN_STAGE
#undef ATTN_TILE
}

// ---------------------------------------------------------------------------
extern "C" void kernel_launch(void* const* d_in, const int* in_sizes, int n_in,
                              void* d_out, int out_size, void* d_ws, size_t ws_size,
                              hipStream_t stream)
{
    const float* x    = (const float*)d_in[0];
    const float* cosb = (const float*)d_in[1];
    const float* sinb = (const float*)d_in[2];
    const float* q_sc = (const float*)d_in[3];
    const float* q_b  = (const float*)d_in[4];
    const float* k_sc = (const float*)d_in[5];
    const float* k_b  = (const float*)d_in[6];
    const float* v_sc = (const float*)d_in[7];
    const float* v_b  = (const float*)d_in[8];
    const float* o_sc = (const float*)d_in[9];
    const int* q_qw   = (const int*)d_in[10];
    const int* q_qz   = (const int*)d_in[11];
    const int* k_qw   = (const int*)d_in[12];
    const int* k_qz   = (const int*)d_in[13];
    const int* v_qw   = (const int*)d_in[14];
    const int* v_qz   = (const int*)d_in[15];
    const int* o_qw   = (const int*)d_in[16];
    const int* o_qz   = (const int*)d_in[17];
    float* out = (float*)d_out;

    // ws layout (MB):
    //   0..10   Xf16   [AOf16 (16MB) aliases 0..16 after qkv12]
    //   10..40  WT fp16 [6144][2560]  (dead after qkv12)
    //   40..56  Qf | 56..60 Kf | 64..68 VfT   (60..64 free)
    char* ws = (char*)d_ws;
    ushort* Xf   = (ushort*)ws;
    ushort* AOf  = (ushort*)ws;                                  // alias
    ushort* WT   = (ushort*)(ws + (size_t)10 * 1024 * 1024);
    ushort* Qf   = (ushort*)(ws + (size_t)40 * 1024 * 1024);
    ushort* Kf   = (ushort*)(ws + (size_t)56 * 1024 * 1024);
    ushort* VfT  = (ushort*)(ws + (size_t)64 * 1024 * 1024);

    prep_kernel<<<4480, 256, 0, stream>>>(
        x, Xf,
        q_qw, q_sc, q_qz, k_qw, k_sc, k_qz, v_qw, v_sc, v_qz, WT);

    qkv12_kernel<<<768, 256, 0, stream>>>(
        Xf, WT, q_b, k_b, v_b, cosb, sinb, Qf, Kf, VfT);

    attn_mfma_kernel<<<dim3(NH, S_LEN / 64), 256, 0, stream>>>(Qf, Kf, VfT, AOf);

    oproj8_kernel<<<320, 256, 0, stream>>>(
        AOf, o_qw, o_sc, o_qz, out);
}

// Round 24
// 238.692 us; speedup vs baseline: 1.1561x; 1.0654x over previous
//
#include <hip/hip_runtime.h>
#include <hip/hip_bf16.h>
#include <cstdint>

#define S_LEN 2048
#define HIDDEN 2560
#define NH 32
#define NKV 8
#define HD 128
#define GS 128

typedef __attribute__((ext_vector_type(8))) _Float16 half8v;    // 8 x fp16
typedef __attribute__((ext_vector_type(2))) _Float16 half2v;    // 2 x fp16
typedef __attribute__((ext_vector_type(4))) float f32x4;
typedef unsigned int uint;
typedef unsigned short ushort;

__device__ inline ushort f2h(float f) {
    _Float16 h = (_Float16)f;
    return __builtin_bit_cast(ushort, h);
}
__device__ inline float h2f(ushort u) {
    return (float)__builtin_bit_cast(_Float16, u);
}
__device__ inline uint pk2(ushort a, ushort b) { return (uint)a | ((uint)b << 16); }

// async global->LDS, 16B per lane; lds base must be wave-uniform
__device__ __attribute__((always_inline)) inline void gl_lds16(const void* g, void* l) {
    __builtin_amdgcn_global_load_lds(
        (const __attribute__((address_space(1))) unsigned int*)g,
        (__attribute__((address_space(3))) unsigned int*)l, 16, 0, 0);
}

#define WAIT_LGKM0  asm volatile("s_waitcnt lgkmcnt(0)" ::: "memory")
#define WAIT_VM(N)  asm volatile("s_waitcnt vmcnt(" #N ")" ::: "memory")
#define RAW_BARRIER { __builtin_amdgcn_s_barrier(); __builtin_amdgcn_sched_barrier(0); }

// ---------------------------------------------------------------------------
// Shared weight-dequant tile body (verified numerics): one 64n x 128k tile.
// ---------------------------------------------------------------------------
__device__ __attribute__((always_inline)) inline void wdq_tile(
    const int* __restrict__ QW, const float* __restrict__ SC,
    const int* __restrict__ QZ, ushort* __restrict__ Wout,
    int Nw, int Kout, int nloc0, int wtbase, int kt, int t, char* Ts)
{
    const int k80 = kt * 16;
    const int nn  = t & 63;
    const float scf = SC[(size_t)kt * Nw + nloc0 + nn];
    const float zf  = (float)QZ[(size_t)kt * Nw + nloc0 + nn];
    ushort sch = f2h(scf);
    float schf = h2f(sch);
    ushort msc = f2h(-128.0f * schf);   // exact exponent shift
    ushort nzs = f2h(-(zf * schf));
    half2v S2 = {__builtin_bit_cast(_Float16, sch), __builtin_bit_cast(_Float16, sch)};
    half2v M2 = {__builtin_bit_cast(_Float16, msc), __builtin_bit_cast(_Float16, msc)};
    half2v Z2 = {__builtin_bit_cast(_Float16, nzs), __builtin_bit_cast(_Float16, nzs)};

#pragma unroll
    for (int i = 0; i < 4; ++i) {
        int kw = i * 4 + (t >> 6);
        uint q = (uint)QW[(size_t)(k80 + kw) * Nw + nloc0 + nn];
        uint xn = q & 0x0F0F0F0Fu;
        uint yn = (q >> 4) & 0x0F0F0F0Fu;
        uint W0 = __builtin_amdgcn_perm(yn, xn, 0x0C040C00u);
        uint W1 = __builtin_amdgcn_perm(yn, xn, 0x0C050C01u);
        uint W2 = __builtin_amdgcn_perm(yn, xn, 0x0C060C02u);
        uint W3 = __builtin_amdgcn_perm(yn, xn, 0x0C070C03u);
        uint e0 = (W0 << 3) | 0x58005800u;
        uint e1 = (W1 << 3) | 0x58005800u;
        uint e2 = (W2 << 3) | 0x58005800u;
        uint e3 = (W3 << 3) | 0x58005800u;
        half2v w0 = __builtin_bit_cast(half2v, e0) * S2 + M2; w0 = w0 + Z2;
        half2v w1 = __builtin_bit_cast(half2v, e1) * S2 + M2; w1 = w1 + Z2;
        half2v w2 = __builtin_bit_cast(half2v, e2) * S2 + M2; w2 = w2 + Z2;
        half2v w3 = __builtin_bit_cast(half2v, e3) * S2 + M2; w3 = w3 + Z2;
        uint4 dw = {__builtin_bit_cast(uint, w0), __builtin_bit_cast(uint, w1),
                    __builtin_bit_cast(uint, w2), __builtin_bit_cast(uint, w3)};
        *(uint4*)(Ts + nn * 256 + ((kw * 16) ^ ((nn & 7) << 4))) = dw;
    }
    __syncthreads();
    const int kc = t & 15;
#pragma unroll
    for (int i = 0; i < 4; ++i) {
        int nr = i * 16 + (t >> 4);
        uint4 v = *(const uint4*)(Ts + nr * 256 + ((kc * 16) ^ ((nr & 7) << 4)));
        *(uint4*)&Wout[(size_t)(wtbase + nr) * Kout + kt * 128 + kc * 8] = v;
    }
}

// ===========================================================================
// Prepass 1: blocks [0,2560) X->fp16; [2560,4480) QKV weight dequant -> WT.
// ===========================================================================
__global__ __launch_bounds__(256) void prep_kernel(
    const float* __restrict__ X, ushort* __restrict__ Xf,
    const int* __restrict__ q_qw, const float* __restrict__ q_sc, const int* __restrict__ q_qz,
    const int* __restrict__ k_qw, const float* __restrict__ k_sc, const int* __restrict__ k_qz,
    const int* __restrict__ v_qw, const float* __restrict__ v_sc, const int* __restrict__ v_qz,
    ushort* __restrict__ WT)
{
    __shared__ __align__(16) char Ts[16384];
    const int bid = blockIdx.x;
    const int t   = threadIdx.x;

    if (bid < 2560) {
        const size_t base = (size_t)bid * 2048 + (size_t)t * 8;
        float4 a = *(const float4*)&X[base];
        float4 b = *(const float4*)&X[base + 4];
        uint4 hw = {pk2(f2h(a.x), f2h(a.y)), pk2(f2h(a.z), f2h(a.w)),
                    pk2(f2h(b.x), f2h(b.y)), pk2(f2h(b.z), f2h(b.w))};
        *(uint4*)&Xf[base] = hw;
        return;
    }

    const int b2 = bid - 2560;
    const int bx = b2 % 96;
    const int kt = b2 / 96;

    int nloc0, wtbase, Nw;
    const int* QW; const float* SC; const int* QZ;
    if (bx < 64)      { Nw = NH * HD;  nloc0 = bx * 64;        wtbase = bx * 64;
                        QW = q_qw; SC = q_sc; QZ = q_qz; }
    else if (bx < 80) { Nw = NKV * HD; nloc0 = (bx - 64) * 64; wtbase = 4096 + nloc0;
                        QW = k_qw; SC = k_sc; QZ = k_qz; }
    else              { Nw = NKV * HD; nloc0 = (bx - 80) * 64; wtbase = 5120 + nloc0;
                        QW = v_qw; SC = v_sc; QZ = v_qz; }

    wdq_tile(QW, SC, QZ, WT, Nw, HIDDEN, nloc0, wtbase, kt, t, Ts);
}

// ===========================================================================
// Prepass 2 (after qkv12): O-weight dequant -> WTO[2560][4096] fp16.
// 1280 blocks: n-blocks of 64 (40) x k-tiles of 128 (32).
// ===========================================================================
__global__ __launch_bounds__(256) void prep2_kernel(
    const int* __restrict__ o_qw, const float* __restrict__ o_sc,
    const int* __restrict__ o_qz, ushort* __restrict__ WTO)
{
    __shared__ __align__(16) char Ts[16384];
    const int bid = blockIdx.x;
    const int t   = threadIdx.x;
    const int bx  = bid % 40;
    const int kt  = bid / 40;
    wdq_tile(o_qw, o_sc, o_qz, WTO, HIDDEN, NH * HD, bx * 64, bx * 64, kt, t, Ts);
}

// ===========================================================================
// Fused Q/K/V MFMA GEMM on fp16 WT (unchanged round 23 — verified).
// ===========================================================================
__global__ __launch_bounds__(256) void qkv12_kernel(
    const ushort* __restrict__ Xf, const ushort* __restrict__ WT,
    const float* __restrict__ q_b, const float* __restrict__ k_b,
    const float* __restrict__ v_b,
    const float* __restrict__ cosb, const float* __restrict__ sinb,
    ushort* __restrict__ Qf, ushort* __restrict__ Kf,
    ushort* __restrict__ VfT)
{
    __shared__ __align__(16) char LDSB[65536];
    ushort* A0 = (ushort*)(LDSB);
    ushort* A1 = (ushort*)(LDSB + 16384);
    ushort* B0 = (ushort*)(LDSB + 32768);
    ushort* B1 = (ushort*)(LDSB + 49152);

    const int t  = threadIdx.x;
    const int w  = t >> 6;
    const int l  = t & 63;
    const int lg = l >> 4;
    const int lr = l & 15;
    const int wr = w >> 1;
    const int wc = w & 1;
    const int K  = HIDDEN;

    const int bid  = blockIdx.x;
    const int xcd  = bid & 7;
    const int j    = bid >> 3;
    const int nblk = xcd * 6 + (j >> 4);
    const int m0   = (j & 15) * 128;
    const int wtrow = nblk * 128;

    int region, nbase;
    const float* BI;
    if (nblk < 32)      { region = 0; nbase = nblk * 128;        BI = q_b; }
    else if (nblk < 40) { region = 1; nbase = (nblk - 32) * 128; BI = k_b; }
    else                { region = 2; nbase = (nblk - 40) * 128; BI = v_b; }

    const int ldsAw = w * 1024;
    size_t aoff[4], boff[4];
#pragma unroll
    for (int i = 0; i < 4; ++i) {
        int slot = i * 256 + t;
        int rm = slot >> 3, rc = slot & 7;
        aoff[i] = (size_t)(m0 + rm) * K + (size_t)((rc ^ (rm & 7)) * 8);
        boff[i] = (size_t)(wtrow + rm) * K + (size_t)((rc ^ (rm & 7)) * 8);
    }

    int ncm[4];
#pragma unroll
    for (int nf = 0; nf < 4; ++nf)
        ncm[nf] = wc * 32 + (nf & 1) * 16 + lr + ((nf & 2) ? 64 : 0);

    const int xorA = (lr & 7) << 4;
    int aroff[4][2], broff[4][2];
#pragma unroll
    for (int mf = 0; mf < 4; ++mf)
#pragma unroll
        for (int ks = 0; ks < 2; ++ks)
            aroff[mf][ks] = (((wr * 64 + mf * 16 + lr) * 128) + lg * 16 + ks * 64) ^ xorA;
#pragma unroll
    for (int nf = 0; nf < 4; ++nf)
#pragma unroll
        for (int ks = 0; ks < 2; ++ks)
            broff[nf][ks] = ((ncm[nf] * 128) + lg * 16 + ks * 64) ^ xorA;

    f32x4 macc[4][4];
#pragma unroll
    for (int mf = 0; mf < 4; ++mf)
#pragma unroll
        for (int nf = 0; nf < 4; ++nf) macc[mf][nf] = f32x4{0.f, 0.f, 0.f, 0.f};

#define QKV_STAGE(AH, BH, k0) { \
    gl_lds16(Xf + (k0) + aoff[0], (char*)(AH) + ldsAw); \
    gl_lds16(Xf + (k0) + aoff[1], (char*)(AH) + 4096 + ldsAw); \
    gl_lds16(Xf + (k0) + aoff[2], (char*)(AH) + 8192 + ldsAw); \
    gl_lds16(Xf + (k0) + aoff[3], (char*)(AH) + 12288 + ldsAw); \
    gl_lds16(WT + (k0) + boff[0], (char*)(BH) + ldsAw); \
    gl_lds16(WT + (k0) + boff[1], (char*)(BH) + 4096 + ldsAw); \
    gl_lds16(WT + (k0) + boff[2], (char*)(BH) + 8192 + ldsAw); \
    gl_lds16(WT + (k0) + boff[3], (char*)(BH) + 12288 + ldsAw); }

#define QKV_COMPUTE(AH, BT) { \
    _Pragma("unroll") \
    for (int ks = 0; ks < 2; ++ks) { \
        half8v av[4], bv[4]; \
        _Pragma("unroll") \
        for (int mf = 0; mf < 4; ++mf) \
            av[mf] = *(const half8v*)((const char*)(AH) + aroff[mf][ks]); \
        _Pragma("unroll") \
        for (int nf = 0; nf < 4; ++nf) \
            bv[nf] = *(const half8v*)((const char*)(BT) + broff[nf][ks]); \
        _Pragma("unroll") \
        for (int mf = 0; mf < 4; ++mf) \
            _Pragma("unroll") \
            for (int nf = 0; nf < 4; ++nf) \
                macc[mf][nf] = __builtin_amdgcn_mfma_f32_16x16x32_f16(av[mf], bv[nf], macc[mf][nf], 0, 0, 0); \
    } }

    QKV_STAGE(A0, B0, 0);
    WAIT_VM(0);
    RAW_BARRIER;

    for (int g = 0; g < 19; ++g) {
        QKV_STAGE(A1, B1, (2 * g + 1) * 64);
        QKV_COMPUTE(A0, B0);
        WAIT_VM(0);
        RAW_BARRIER;
        QKV_STAGE(A0, B0, (2 * g + 2) * 64);
        QKV_COMPUTE(A1, B1);
        WAIT_VM(0);
        RAW_BARRIER;
    }
    QKV_STAGE(A1, B1, 39 * 64);
    QKV_COMPUTE(A0, B0);
    WAIT_VM(0);
    RAW_BARRIER;
    QKV_COMPUTE(A1, B1);

#pragma unroll
    for (int nf = 0; nf < 4; ++nf) {
        float bv = BI[nbase + ncm[nf]];
#pragma unroll
        for (int mf = 0; mf < 4; ++mf)
#pragma unroll
            for (int r = 0; r < 4; ++r) macc[mf][nf][r] += bv;
    }

    if (region == 2) {
        // ---- V: transpose in LDS -> VfT directly ----
        WAIT_LGKM0;
        RAW_BARRIER;
        ushort* EP = (ushort*)LDSB;        // [128][130] padded
#pragma unroll
        for (int mf = 0; mf < 4; ++mf)
#pragma unroll
            for (int r = 0; r < 4; ++r) {
                int row = wr * 64 + mf * 16 + lg * 4 + r;
#pragma unroll
                for (int nf = 0; nf < 4; ++nf)
                    EP[row * 130 + ncm[nf]] = f2h(macc[mf][nf][r]);
            }
        WAIT_LGKM0;
        RAW_BARRIER;
        const int c   = t >> 1;
        const int seg = (t & 1) * 64;
        ushort* dst = &VfT[(size_t)(nbase + c) * S_LEN + m0 + seg];
#pragma unroll
        for (int g8 = 0; g8 < 8; ++g8) {
            ushort buf[8];
#pragma unroll
            for (int jj = 0; jj < 8; ++jj)
                buf[jj] = EP[(seg + g8 * 8 + jj) * 130 + c];
            *(uint4*)(dst + g8 * 8) = *(uint4*)buf;
        }
    } else {
        ushort* OF = (region == 0) ? Qf : Kf;
        const int No = (region == 0) ? NH * HD : NKV * HD;
        const float osc = (region == 0)
            ? 0.08838834764831845f * 1.44269504088896341f : 1.0f;
#pragma unroll
        for (int mf = 0; mf < 4; ++mf)
#pragma unroll
            for (int r = 0; r < 4; ++r) {
                int row = m0 + wr * 64 + mf * 16 + lg * 4 + r;
                const float* cb = &cosb[(size_t)row * HD];
                const float* sb = &sinb[(size_t)row * HD];
#pragma unroll
                for (int nf = 0; nf < 2; ++nf) {
                    int d = wc * 32 + nf * 16 + lr;
                    float a = macc[mf][nf][r];
                    float b = macc[mf][nf + 2][r];
                    float o1 = (a * cb[d]      - b * sb[d])      * osc;
                    float o2 = (b * cb[d + 64] + a * sb[d + 64]) * osc;
                    OF[(size_t)row * No + nbase + d]      = f2h(o1);
                    OF[(size_t)row * No + nbase + d + 64] = f2h(o2);
                }
            }
    }
#undef QKV_STAGE
#undef QKV_COMPUTE
}

// ===========================================================================
// O-projection on pre-dequanted WTO: pure gl_lds A+B, counted vmcnt, zero
// in-loop VALU. Block 128x128, 64 K-tiles. Group-of-2-XCD swizzle: 4 groups
// x (5 nblk x 16 mband); each group's 5MB WTO slice stays L2-resident.
// ===========================================================================
__global__ __launch_bounds__(256) void oproj9_kernel(
    const ushort* __restrict__ Xb, const ushort* __restrict__ WTO,
    float* __restrict__ Y)
{
    __shared__ __align__(16) char LDSB[65536];
    ushort* A0 = (ushort*)(LDSB);
    ushort* A1 = (ushort*)(LDSB + 16384);
    ushort* B0 = (ushort*)(LDSB + 32768);
    ushort* B1 = (ushort*)(LDSB + 49152);

    const int t  = threadIdx.x;
    const int w  = t >> 6;
    const int l  = t & 63;
    const int lg = l >> 4;
    const int lr = l & 15;
    const int wr = w >> 1;
    const int wc = w & 1;
    const int K  = NH * HD;      // 4096
    const int N  = HIDDEN;       // 2560

    const int bid  = blockIdx.x;
    const int xcd  = bid & 7;
    const int grp  = xcd >> 1;                       // 0..3
    const int j    = (bid >> 3) * 2 + (xcd & 1);     // 0..79
    const int nblk = grp * 5 + (j % 5);              // 0..19
    const int m0   = (j / 5) * 128;
    const int n0   = nblk * 128;

    const int ldsAw = w * 1024;
    size_t aoff[4], boff[4];
#pragma unroll
    for (int i = 0; i < 4; ++i) {
        int slot = i * 256 + t;
        int rm = slot >> 3, rc = slot & 7;
        aoff[i] = (size_t)(m0 + rm) * K + (size_t)((rc ^ (rm & 7)) * 8);
        boff[i] = (size_t)(n0 + rm) * K + (size_t)((rc ^ (rm & 7)) * 8);
    }

    const int xorA = (lr & 7) << 4;
    int aroff[4][2], broff[4][2];
#pragma unroll
    for (int mf = 0; mf < 4; ++mf)
#pragma unroll
        for (int ks = 0; ks < 2; ++ks)
            aroff[mf][ks] = (((wr * 64 + mf * 16 + lr) * 128) + lg * 16 + ks * 64) ^ xorA;
#pragma unroll
    for (int nf = 0; nf < 4; ++nf)
#pragma unroll
        for (int ks = 0; ks < 2; ++ks)
            broff[nf][ks] = (((wc * 64 + nf * 16 + lr) * 128) + lg * 16 + ks * 64) ^ xorA;

    f32x4 macc[4][4];
#pragma unroll
    for (int mf = 0; mf < 4; ++mf)
#pragma unroll
        for (int nf = 0; nf < 4; ++nf) macc[mf][nf] = f32x4{0.f, 0.f, 0.f, 0.f};

#define OP_STAGE(AH, BH, k0) { \
    gl_lds16(Xb + (k0) + aoff[0], (char*)(AH) + ldsAw); \
    gl_lds16(Xb + (k0) + aoff[1], (char*)(AH) + 4096 + ldsAw); \
    gl_lds16(Xb + (k0) + aoff[2], (char*)(AH) + 8192 + ldsAw); \
    gl_lds16(Xb + (k0) + aoff[3], (char*)(AH) + 12288 + ldsAw); \
    gl_lds16(WTO + (k0) + boff[0], (char*)(BH) + ldsAw); \
    gl_lds16(WTO + (k0) + boff[1], (char*)(BH) + 4096 + ldsAw); \
    gl_lds16(WTO + (k0) + boff[2], (char*)(BH) + 8192 + ldsAw); \
    gl_lds16(WTO + (k0) + boff[3], (char*)(BH) + 12288 + ldsAw); }

#define OP_COMPUTE(AH, BT) { \
    _Pragma("unroll") \
    for (int ks = 0; ks < 2; ++ks) { \
        half8v av[4], bv[4]; \
        _Pragma("unroll") \
        for (int mf = 0; mf < 4; ++mf) \
            av[mf] = *(const half8v*)((const char*)(AH) + aroff[mf][ks]); \
        _Pragma("unroll") \
        for (int nf = 0; nf < 4; ++nf) \
            bv[nf] = *(const half8v*)((const char*)(BT) + broff[nf][ks]); \
        _Pragma("unroll") \
        for (int mf = 0; mf < 4; ++mf) \
            _Pragma("unroll") \
            for (int nf = 0; nf < 4; ++nf) \
                macc[mf][nf] = __builtin_amdgcn_mfma_f32_16x16x32_f16(av[mf], bv[nf], macc[mf][nf], 0, 0, 0); \
    } }

    OP_STAGE(A0, B0, 0);
    WAIT_VM(0);
    RAW_BARRIER;

    for (int g = 0; g < 31; ++g) {
        OP_STAGE(A1, B1, (2 * g + 1) * 64);
        OP_COMPUTE(A0, B0);
        WAIT_VM(0);
        RAW_BARRIER;
        OP_STAGE(A0, B0, (2 * g + 2) * 64);
        OP_COMPUTE(A1, B1);
        WAIT_VM(0);
        RAW_BARRIER;
    }
    OP_STAGE(A1, B1, 63 * 64);
    OP_COMPUTE(A0, B0);
    WAIT_VM(0);
    RAW_BARRIER;
    OP_COMPUTE(A1, B1);

#pragma unroll
    for (int mf = 0; mf < 4; ++mf)
#pragma unroll
        for (int r = 0; r < 4; ++r) {
            int row = m0 + wr * 64 + mf * 16 + lg * 4 + r;
#pragma unroll
            for (int nf = 0; nf < 4; ++nf)
                Y[(size_t)row * N + n0 + wc * 64 + nf * 16 + lr] = macc[mf][nf][r];
        }
#undef OP_STAGE
#undef OP_COMPUTE
}

// ---------------------------------------------------------------------------
// Causal GQA flash attention (unchanged round 23 — verified 89 us).
// ---------------------------------------------------------------------------
__global__ __launch_bounds__(256) void attn_mfma_kernel(
    const ushort* __restrict__ Qh,   // [S][NH*HD] fp16, roped, *log2e/sqrt(HD)
    const ushort* __restrict__ Kh,   // [S][NKV*HD] fp16, roped
    const ushort* __restrict__ Vt,   // [NKV*HD][S] fp16 (transposed)
    ushort* __restrict__ AO)         // [S][NH*HD] fp16
{
    __shared__ ushort Ks0[32 * 128];           // swz ^((row&7)<<4)
    __shared__ ushort Ks1[32 * 128];
    __shared__ ushort Vs0[128 * 32];           // swz ^(((dim>>1)&3)<<4)
    __shared__ ushort Vs1[128 * 32];
    __shared__ __align__(16) char PsB[4 * 1280];  // P: 16 rows x 80B per wave

    const int h  = blockIdx.x;
    const int qb = gridDim.y - 1 - blockIdx.y;   // long blocks dispatch first
    const int s0 = qb * 64;
    const int t  = threadIdx.x;
    const int w  = t >> 6;
    const int l  = t & 63;
    const int lg = l >> 4;
    const int lr = l & 15;
    const int kvh = h >> 2;
    const int qw = s0 + w * 16;
    const int q  = qw + lr;          // this lane's q-row

    half8v qf[4];
#pragma unroll
    for (int d = 0; d < 4; ++d) {
        size_t off = (size_t)q * (NH * HD) + h * HD + d * 32 + lg * 8;
        qf[d] = *(const half8v*)&Qh[off];
    }

    f32x4 o[8];
#pragma unroll
    for (int i = 0; i < 8; ++i) o[i] = f32x4{0.f, 0.f, 0.f, 0.f};
    float m = -1e30f, lsum = 0.f;
    char* pw = PsB + w * 1280;

#define ATTN_STAGE(KB, VB, k0) { \
    _Pragma("unroll") \
    for (int i = 0; i < 2; ++i) { \
        int slot = w * 128 + i * 64 + l; \
        int mr = slot >> 4, c = slot & 15; \
        size_t goff = (size_t)((k0) + mr) * (NKV * HD) + kvh * HD + ((c ^ (mr & 7)) * 8); \
        gl_lds16(Kh + goff, (char*)(KB) + (w * 128 + i * 64) * 16); \
    } \
    _Pragma("unroll") \
    for (int i = 0; i < 2; ++i) { \
        int slot = w * 128 + i * 64 + l; \
        int dim = slot >> 2, c = slot & 3; \
        size_t goff = (size_t)(kvh * HD + dim) * S_LEN + (k0) + ((c ^ ((dim >> 1) & 3)) * 8); \
        gl_lds16(Vt + goff, (char*)(VB) + (w * 128 + i * 64) * 16); \
    } }

#define ATTN_TILE(KSF, VSS, k0) \
    if ((k0) <= qw + 15) { \
        f32x4 s_[2]; \
        s_[0] = f32x4{0.f, 0.f, 0.f, 0.f}; \
        s_[1] = f32x4{0.f, 0.f, 0.f, 0.f}; \
        _Pragma("unroll") \
        for (int d = 0; d < 4; ++d) { \
            _Pragma("unroll") \
            for (int nt2 = 0; nt2 < 2; ++nt2) { \
                int row = nt2 * 16 + lr; \
                int off = row * 256 + ((d * 64 + lg * 16) ^ ((row & 7) << 4)); \
                half8v kf = *(const half8v*)((const char*)(KSF) + off); \
                s_[nt2] = __builtin_amdgcn_mfma_f32_16x16x32_f16(kf, qf[d], s_[nt2], 0, 0, 0); \
            } \
        } \
        float sv[8]; \
        _Pragma("unroll") \
        for (int nt2 = 0; nt2 < 2; ++nt2) \
            _Pragma("unroll") \
            for (int r = 0; r < 4; ++r) { \
                int kv = (k0) + nt2 * 16 + lg * 4 + r; \
                sv[nt2 * 4 + r] = (kv <= q) ? s_[nt2][r] : -1e30f; \
            } \
        float mx = sv[0]; \
        _Pragma("unroll") \
        for (int j = 1; j < 8; ++j) mx = fmaxf(mx, sv[j]); \
        mx = fmaxf(mx, __shfl_xor(mx, 16)); \
        mx = fmaxf(mx, __shfl_xor(mx, 32)); \
        float mnew = fmaxf(m, mx); \
        float resc = __builtin_amdgcn_exp2f(m - mnew); \
        m = mnew; \
        float p_[8], ps = 0.f; \
        _Pragma("unroll") \
        for (int j = 0; j < 8; ++j) { p_[j] = __builtin_amdgcn_exp2f(sv[j] - mnew); ps += p_[j]; } \
        ps += __shfl_xor(ps, 16); \
        ps += __shfl_xor(ps, 32); \
        lsum = lsum * resc + ps; \
        _Pragma("unroll") \
        for (int dt = 0; dt < 8; ++dt) \
            _Pragma("unroll") \
            for (int r = 0; r < 4; ++r) o[dt][r] *= resc; \
        uint2 w0_ = {pk2(f2h(p_[0]), f2h(p_[1])), pk2(f2h(p_[2]), f2h(p_[3]))}; \
        uint2 w1_ = {pk2(f2h(p_[4]), f2h(p_[5])), pk2(f2h(p_[6]), f2h(p_[7]))}; \
        *(uint2*)(pw + lr * 80 + lg * 8)      = w0_; \
        *(uint2*)(pw + lr * 80 + 32 + lg * 8) = w1_; \
        asm volatile("s_waitcnt lgkmcnt(0)" ::: "memory"); \
        half8v pf = *(const half8v*)(pw + lr * 80 + lg * 16); \
        _Pragma("unroll") \
        for (int dt = 0; dt < 8; ++dt) { \
            int dim = dt * 16 + lr; \
            half8v vf = *(const half8v*)((const char*)(VSS) + dim * 64 + ((lg * 16) ^ (((dim >> 1) & 3) << 4))); \
            o[dt] = __builtin_amdgcn_mfma_f32_16x16x32_f16(vf, pf, o[dt], 0, 0, 0); \
        } \
    }

    const int ntiles = qb * 2 + 2;   // always even

    ATTN_STAGE(Ks0, Vs0, 0);
    WAIT_VM(0);
    RAW_BARRIER;

    for (int kt = 0; kt < ntiles; kt += 2) {
        if (kt + 1 < ntiles) ATTN_STAGE(Ks1, Vs1, (kt + 1) * 32);
        ATTN_TILE(Ks0, Vs0, kt * 32);
        WAIT_VM(0);
        RAW_BARRIER;
        if (kt + 2 < ntiles) ATTN_STAGE(Ks0, Vs0, (kt + 2) * 32);
        ATTN_TILE(Ks1, Vs1, (kt + 1) * 32);
        WAIT_VM(0);
        RAW_BARRIER;
    }

    float inv = 1.f / lsum;
    ushort* dst = &AO[(size_t)q * (NH * HD) + h * HD];
#pragma unroll
    for (int dt = 0; dt < 8; ++dt) {
        uint2 ov = {pk2(f2h(o[dt][0] * inv), f2h(o[dt][1] * inv)),
                    pk2(f2h(o[dt][2] * inv), f2h(o[dt][3] * inv))};
        *(uint2*)(dst + dt * 16 + lg * 4) = ov;
    }
#undef ATTN_STAGE
#undef ATTN_TILE
}

// ---------------------------------------------------------------------------
extern "C" void kernel_launch(void* const* d_in, const int* in_sizes, int n_in,
                              void* d_out, int out_size, void* d_ws, size_t ws_size,
                              hipStream_t stream)
{
    const float* x    = (const float*)d_in[0];
    const float* cosb = (const float*)d_in[1];
    const float* sinb = (const float*)d_in[2];
    const float* q_sc = (const float*)d_in[3];
    const float* q_b  = (const float*)d_in[4];
    const float* k_sc = (const float*)d_in[5];
    const float* k_b  = (const float*)d_in[6];
    const float* v_sc = (const float*)d_in[7];
    const float* v_b  = (const float*)d_in[8];
    const float* o_sc = (const float*)d_in[9];
    const int* q_qw   = (const int*)d_in[10];
    const int* q_qz   = (const int*)d_in[11];
    const int* k_qw   = (const int*)d_in[12];
    const int* k_qz   = (const int*)d_in[13];
    const int* v_qw   = (const int*)d_in[14];
    const int* v_qz   = (const int*)d_in[15];
    const int* o_qw   = (const int*)d_in[16];
    const int* o_qz   = (const int*)d_in[17];
    float* out = (float*)d_out;

    // ws layout (MB), lifetimes:
    //   0..10   Xf16 (prep -> qkv12)  [AOf16 0..16 written by attn, read oproj]
    //   10..40  WT (prep -> qkv12, dead after)
    //   16..36  WTO (prep2, AFTER qkv12; inside dead WT region, above AOf? no:
    //           AOf is 0..16, WTO 16..36 -> disjoint)
    //   40..56  Qf | 56..60 Kf | 64..68 VfT
    char* ws = (char*)d_ws;
    ushort* Xf   = (ushort*)ws;
    ushort* AOf  = (ushort*)ws;                                  // alias 0..16
    ushort* WT   = (ushort*)(ws + (size_t)10 * 1024 * 1024);
    ushort* WTO  = (ushort*)(ws + (size_t)16 * 1024 * 1024);
    ushort* Qf   = (ushort*)(ws + (size_t)40 * 1024 * 1024);
    ushort* Kf   = (ushort*)(ws + (size_t)56 * 1024 * 1024);
    ushort* VfT  = (ushort*)(ws + (size_t)64 * 1024 * 1024);

    prep_kernel<<<4480, 256, 0, stream>>>(
        x, Xf,
        q_qw, q_sc, q_qz, k_qw, k_sc, k_qz, v_qw, v_sc, v_qz, WT);

    qkv12_kernel<<<768, 256, 0, stream>>>(
        Xf, WT, q_b, k_b, v_b, cosb, sinb, Qf, Kf, VfT);

    prep2_kernel<<<1280, 256, 0, stream>>>(o_qw, o_sc, o_qz, WTO);

    attn_mfma_kernel<<<dim3(NH, S_LEN / 64), 256, 0, stream>>>(Qf, Kf, VfT, AOf);

    oproj9_kernel<<<320, 256, 0, stream>>>(AOf, WTO, out);
}

// Round 26
// 237.877 us; speedup vs baseline: 1.1600x; 1.0034x over previous
//
#include <hip/hip_runtime.h>
#include <hip/hip_bf16.h>
#include <cstdint>

#define S_LEN 2048
#define HIDDEN 2560
#define NH 32
#define NKV 8
#define HD 128
#define GS 128

typedef __attribute__((ext_vector_type(8))) _Float16 half8v;    // 8 x fp16
typedef __attribute__((ext_vector_type(2))) _Float16 half2v;    // 2 x fp16
typedef __attribute__((ext_vector_type(4))) float f32x4;
typedef unsigned int uint;
typedef unsigned short ushort;

__device__ inline ushort f2h(float f) {
    _Float16 h = (_Float16)f;
    return __builtin_bit_cast(ushort, h);
}
__device__ inline float h2f(ushort u) {
    return (float)__builtin_bit_cast(_Float16, u);
}
__device__ inline uint pk2(ushort a, ushort b) { return (uint)a | ((uint)b << 16); }

// async global->LDS, 16B per lane; lds base must be wave-uniform
__device__ __attribute__((always_inline)) inline void gl_lds16(const void* g, void* l) {
    __builtin_amdgcn_global_load_lds(
        (const __attribute__((address_space(1))) unsigned int*)g,
        (__attribute__((address_space(3))) unsigned int*)l, 16, 0, 0);
}

#define WAIT_LGKM0  asm volatile("s_waitcnt lgkmcnt(0)" ::: "memory")
#define WAIT_VM(N)  asm volatile("s_waitcnt vmcnt(" #N ")" ::: "memory")
#define RAW_BARRIER { __builtin_amdgcn_s_barrier(); __builtin_amdgcn_sched_barrier(0); }

// ---------------------------------------------------------------------------
// Shared weight-dequant tile body (verified numerics): one 64n x 128k tile.
// ---------------------------------------------------------------------------
__device__ __attribute__((always_inline)) inline void wdq_tile(
    const int* __restrict__ QW, const float* __restrict__ SC,
    const int* __restrict__ QZ, ushort* __restrict__ Wout,
    int Nw, int Kout, int nloc0, int wtbase, int kt, int t, char* Ts)
{
    const int k80 = kt * 16;
    const int nn  = t & 63;
    const float scf = SC[(size_t)kt * Nw + nloc0 + nn];
    const float zf  = (float)QZ[(size_t)kt * Nw + nloc0 + nn];
    ushort sch = f2h(scf);
    float schf = h2f(sch);
    ushort msc = f2h(-128.0f * schf);   // exact exponent shift
    ushort nzs = f2h(-(zf * schf));
    half2v S2 = {__builtin_bit_cast(_Float16, sch), __builtin_bit_cast(_Float16, sch)};
    half2v M2 = {__builtin_bit_cast(_Float16, msc), __builtin_bit_cast(_Float16, msc)};
    half2v Z2 = {__builtin_bit_cast(_Float16, nzs), __builtin_bit_cast(_Float16, nzs)};

#pragma unroll
    for (int i = 0; i < 4; ++i) {
        int kw = i * 4 + (t >> 6);
        uint q = (uint)QW[(size_t)(k80 + kw) * Nw + nloc0 + nn];
        uint xn = q & 0x0F0F0F0Fu;
        uint yn = (q >> 4) & 0x0F0F0F0Fu;
        uint W0 = __builtin_amdgcn_perm(yn, xn, 0x0C040C00u);
        uint W1 = __builtin_amdgcn_perm(yn, xn, 0x0C050C01u);
        uint W2 = __builtin_amdgcn_perm(yn, xn, 0x0C060C02u);
        uint W3 = __builtin_amdgcn_perm(yn, xn, 0x0C070C03u);
        uint e0 = (W0 << 3) | 0x58005800u;
        uint e1 = (W1 << 3) | 0x58005800u;
        uint e2 = (W2 << 3) | 0x58005800u;
        uint e3 = (W3 << 3) | 0x58005800u;
        half2v w0 = __builtin_bit_cast(half2v, e0) * S2 + M2; w0 = w0 + Z2;
        half2v w1 = __builtin_bit_cast(half2v, e1) * S2 + M2; w1 = w1 + Z2;
        half2v w2 = __builtin_bit_cast(half2v, e2) * S2 + M2; w2 = w2 + Z2;
        half2v w3 = __builtin_bit_cast(half2v, e3) * S2 + M2; w3 = w3 + Z2;
        uint4 dw = {__builtin_bit_cast(uint, w0), __builtin_bit_cast(uint, w1),
                    __builtin_bit_cast(uint, w2), __builtin_bit_cast(uint, w3)};
        *(uint4*)(Ts + nn * 256 + ((kw * 16) ^ ((nn & 7) << 4))) = dw;
    }
    __syncthreads();
    const int kc = t & 15;
#pragma unroll
    for (int i = 0; i < 4; ++i) {
        int nr = i * 16 + (t >> 4);
        uint4 v = *(const uint4*)(Ts + nr * 256 + ((kc * 16) ^ ((nr & 7) << 4)));
        *(uint4*)&Wout[(size_t)(wtbase + nr) * Kout + kt * 128 + kc * 8] = v;
    }
}

// ===========================================================================
// Prepass 1: blocks [0,2560) X->fp16; [2560,4480) QKV weight dequant -> WT.
// ===========================================================================
__global__ __launch_bounds__(256) void prep_kernel(
    const float* __restrict__ X, ushort* __restrict__ Xf,
    const int* __restrict__ q_qw, const float* __restrict__ q_sc, const int* __restrict__ q_qz,
    const int* __restrict__ k_qw, const float* __restrict__ k_sc, const int* __restrict__ k_qz,
    const int* __restrict__ v_qw, const float* __restrict__ v_sc, const int* __restrict__ v_qz,
    ushort* __restrict__ WT)
{
    __shared__ __align__(16) char Ts[16384];
    const int bid = blockIdx.x;
    const int t   = threadIdx.x;

    if (bid < 2560) {
        const size_t base = (size_t)bid * 2048 + (size_t)t * 8;
        float4 a = *(const float4*)&X[base];
        float4 b = *(const float4*)&X[base + 4];
        uint4 hw = {pk2(f2h(a.x), f2h(a.y)), pk2(f2h(a.z), f2h(a.w)),
                    pk2(f2h(b.x), f2h(b.y)), pk2(f2h(b.z), f2h(b.w))};
        *(uint4*)&Xf[base] = hw;
        return;
    }

    const int b2 = bid - 2560;
    const int bx = b2 % 96;
    const int kt = b2 / 96;

    int nloc0, wtbase, Nw;
    const int* QW; const float* SC; const int* QZ;
    if (bx < 64)      { Nw = NH * HD;  nloc0 = bx * 64;        wtbase = bx * 64;
                        QW = q_qw; SC = q_sc; QZ = q_qz; }
    else if (bx < 80) { Nw = NKV * HD; nloc0 = (bx - 64) * 64; wtbase = 4096 + nloc0;
                        QW = k_qw; SC = k_sc; QZ = k_qz; }
    else              { Nw = NKV * HD; nloc0 = (bx - 80) * 64; wtbase = 5120 + nloc0;
                        QW = v_qw; SC = v_sc; QZ = v_qz; }

    wdq_tile(QW, SC, QZ, WT, Nw, HIDDEN, nloc0, wtbase, kt, t, Ts);
}

// ===========================================================================
// Prepass 2 (after qkv12): O-weight dequant -> WTO[2560][4096] fp16.
// ===========================================================================
__global__ __launch_bounds__(256) void prep2_kernel(
    const int* __restrict__ o_qw, const float* __restrict__ o_sc,
    const int* __restrict__ o_qz, ushort* __restrict__ WTO)
{
    __shared__ __align__(16) char Ts[16384];
    const int bid = blockIdx.x;
    const int t   = threadIdx.x;
    const int bx  = bid % 40;
    const int kt  = bid / 40;
    wdq_tile(o_qw, o_sc, o_qz, WTO, HIDDEN, NH * HD, bx * 64, bx * 64, kt, t, Ts);
}

// ===========================================================================
// Fused Q/K/V MFMA GEMM on fp16 WT (unchanged — verified).
// ===========================================================================
__global__ __launch_bounds__(256) void qkv12_kernel(
    const ushort* __restrict__ Xf, const ushort* __restrict__ WT,
    const float* __restrict__ q_b, const float* __restrict__ k_b,
    const float* __restrict__ v_b,
    const float* __restrict__ cosb, const float* __restrict__ sinb,
    ushort* __restrict__ Qf, ushort* __restrict__ Kf,
    ushort* __restrict__ VfT)
{
    __shared__ __align__(16) char LDSB[65536];
    ushort* A0 = (ushort*)(LDSB);
    ushort* A1 = (ushort*)(LDSB + 16384);
    ushort* B0 = (ushort*)(LDSB + 32768);
    ushort* B1 = (ushort*)(LDSB + 49152);

    const int t  = threadIdx.x;
    const int w  = t >> 6;
    const int l  = t & 63;
    const int lg = l >> 4;
    const int lr = l & 15;
    const int wr = w >> 1;
    const int wc = w & 1;
    const int K  = HIDDEN;

    const int bid  = blockIdx.x;
    const int xcd  = bid & 7;
    const int j    = bid >> 3;
    const int nblk = xcd * 6 + (j >> 4);
    const int m0   = (j & 15) * 128;
    const int wtrow = nblk * 128;

    int region, nbase;
    const float* BI;
    if (nblk < 32)      { region = 0; nbase = nblk * 128;        BI = q_b; }
    else if (nblk < 40) { region = 1; nbase = (nblk - 32) * 128; BI = k_b; }
    else                { region = 2; nbase = (nblk - 40) * 128; BI = v_b; }

    const int ldsAw = w * 1024;
    size_t aoff[4], boff[4];
#pragma unroll
    for (int i = 0; i < 4; ++i) {
        int slot = i * 256 + t;
        int rm = slot >> 3, rc = slot & 7;
        aoff[i] = (size_t)(m0 + rm) * K + (size_t)((rc ^ (rm & 7)) * 8);
        boff[i] = (size_t)(wtrow + rm) * K + (size_t)((rc ^ (rm & 7)) * 8);
    }

    int ncm[4];
#pragma unroll
    for (int nf = 0; nf < 4; ++nf)
        ncm[nf] = wc * 32 + (nf & 1) * 16 + lr + ((nf & 2) ? 64 : 0);

    const int xorA = (lr & 7) << 4;
    int aroff[4][2], broff[4][2];
#pragma unroll
    for (int mf = 0; mf < 4; ++mf)
#pragma unroll
        for (int ks = 0; ks < 2; ++ks)
            aroff[mf][ks] = (((wr * 64 + mf * 16 + lr) * 128) + lg * 16 + ks * 64) ^ xorA;
#pragma unroll
    for (int nf = 0; nf < 4; ++nf)
#pragma unroll
        for (int ks = 0; ks < 2; ++ks)
            broff[nf][ks] = ((ncm[nf] * 128) + lg * 16 + ks * 64) ^ xorA;

    f32x4 macc[4][4];
#pragma unroll
    for (int mf = 0; mf < 4; ++mf)
#pragma unroll
        for (int nf = 0; nf < 4; ++nf) macc[mf][nf] = f32x4{0.f, 0.f, 0.f, 0.f};

#define QKV_STAGE(AH, BH, k0) { \
    gl_lds16(Xf + (k0) + aoff[0], (char*)(AH) + ldsAw); \
    gl_lds16(Xf + (k0) + aoff[1], (char*)(AH) + 4096 + ldsAw); \
    gl_lds16(Xf + (k0) + aoff[2], (char*)(AH) + 8192 + ldsAw); \
    gl_lds16(Xf + (k0) + aoff[3], (char*)(AH) + 12288 + ldsAw); \
    gl_lds16(WT + (k0) + boff[0], (char*)(BH) + ldsAw); \
    gl_lds16(WT + (k0) + boff[1], (char*)(BH) + 4096 + ldsAw); \
    gl_lds16(WT + (k0) + boff[2], (char*)(BH) + 8192 + ldsAw); \
    gl_lds16(WT + (k0) + boff[3], (char*)(BH) + 12288 + ldsAw); }

#define QKV_COMPUTE(AH, BT) { \
    _Pragma("unroll") \
    for (int ks = 0; ks < 2; ++ks) { \
        half8v av[4], bv[4]; \
        _Pragma("unroll") \
        for (int mf = 0; mf < 4; ++mf) \
            av[mf] = *(const half8v*)((const char*)(AH) + aroff[mf][ks]); \
        _Pragma("unroll") \
        for (int nf = 0; nf < 4; ++nf) \
            bv[nf] = *(const half8v*)((const char*)(BT) + broff[nf][ks]); \
        _Pragma("unroll") \
        for (int mf = 0; mf < 4; ++mf) \
            _Pragma("unroll") \
            for (int nf = 0; nf < 4; ++nf) \
                macc[mf][nf] = __builtin_amdgcn_mfma_f32_16x16x32_f16(av[mf], bv[nf], macc[mf][nf], 0, 0, 0); \
    } }

    QKV_STAGE(A0, B0, 0);
    WAIT_VM(0);
    RAW_BARRIER;

    for (int g = 0; g < 19; ++g) {
        QKV_STAGE(A1, B1, (2 * g + 1) * 64);
        QKV_COMPUTE(A0, B0);
        WAIT_VM(0);
        RAW_BARRIER;
        QKV_STAGE(A0, B0, (2 * g + 2) * 64);
        QKV_COMPUTE(A1, B1);
        WAIT_VM(0);
        RAW_BARRIER;
    }
    QKV_STAGE(A1, B1, 39 * 64);
    QKV_COMPUTE(A0, B0);
    WAIT_VM(0);
    RAW_BARRIER;
    QKV_COMPUTE(A1, B1);

#pragma unroll
    for (int nf = 0; nf < 4; ++nf) {
        float bv = BI[nbase + ncm[nf]];
#pragma unroll
        for (int mf = 0; mf < 4; ++mf)
#pragma unroll
            for (int r = 0; r < 4; ++r) macc[mf][nf][r] += bv;
    }

    if (region == 2) {
        WAIT_LGKM0;
        RAW_BARRIER;
        ushort* EP = (ushort*)LDSB;        // [128][130] padded
#pragma unroll
        for (int mf = 0; mf < 4; ++mf)
#pragma unroll
            for (int r = 0; r < 4; ++r) {
                int row = wr * 64 + mf * 16 + lg * 4 + r;
#pragma unroll
                for (int nf = 0; nf < 4; ++nf)
                    EP[row * 130 + ncm[nf]] = f2h(macc[mf][nf][r]);
            }
        WAIT_LGKM0;
        RAW_BARRIER;
        const int c   = t >> 1;
        const int seg = (t & 1) * 64;
        ushort* dst = &VfT[(size_t)(nbase + c) * S_LEN + m0 + seg];
#pragma unroll
        for (int g8 = 0; g8 < 8; ++g8) {
            ushort buf[8];
#pragma unroll
            for (int jj = 0; jj < 8; ++jj)
                buf[jj] = EP[(seg + g8 * 8 + jj) * 130 + c];
            *(uint4*)(dst + g8 * 8) = *(uint4*)buf;
        }
    } else {
        ushort* OF = (region == 0) ? Qf : Kf;
        const int No = (region == 0) ? NH * HD : NKV * HD;
        const float osc = (region == 0)
            ? 0.08838834764831845f * 1.44269504088896341f : 1.0f;
#pragma unroll
        for (int mf = 0; mf < 4; ++mf)
#pragma unroll
            for (int r = 0; r < 4; ++r) {
                int row = m0 + wr * 64 + mf * 16 + lg * 4 + r;
                const float* cb = &cosb[(size_t)row * HD];
                const float* sb = &sinb[(size_t)row * HD];
#pragma unroll
                for (int nf = 0; nf < 2; ++nf) {
                    int d = wc * 32 + nf * 16 + lr;
                    float a = macc[mf][nf][r];
                    float b = macc[mf][nf + 2][r];
                    float o1 = (a * cb[d]      - b * sb[d])      * osc;
                    float o2 = (b * cb[d + 64] + a * sb[d + 64]) * osc;
                    OF[(size_t)row * No + nbase + d]      = f2h(o1);
                    OF[(size_t)row * No + nbase + d + 64] = f2h(o2);
                }
            }
    }
#undef QKV_STAGE
#undef QKV_COMPUTE
}

// ===========================================================================
// O-projection on pre-dequanted WTO (unchanged — verified).
// ===========================================================================
__global__ __launch_bounds__(256) void oproj9_kernel(
    const ushort* __restrict__ Xb, const ushort* __restrict__ WTO,
    float* __restrict__ Y)
{
    __shared__ __align__(16) char LDSB[65536];
    ushort* A0 = (ushort*)(LDSB);
    ushort* A1 = (ushort*)(LDSB + 16384);
    ushort* B0 = (ushort*)(LDSB + 32768);
    ushort* B1 = (ushort*)(LDSB + 49152);

    const int t  = threadIdx.x;
    const int w  = t >> 6;
    const int l  = t & 63;
    const int lg = l >> 4;
    const int lr = l & 15;
    const int wr = w >> 1;
    const int wc = w & 1;
    const int K  = NH * HD;      // 4096
    const int N  = HIDDEN;       // 2560

    const int bid  = blockIdx.x;
    const int xcd  = bid & 7;
    const int grp  = xcd >> 1;
    const int j    = (bid >> 3) * 2 + (xcd & 1);
    const int nblk = grp * 5 + (j % 5);
    const int m0   = (j / 5) * 128;
    const int n0   = nblk * 128;

    const int ldsAw = w * 1024;
    size_t aoff[4], boff[4];
#pragma unroll
    for (int i = 0; i < 4; ++i) {
        int slot = i * 256 + t;
        int rm = slot >> 3, rc = slot & 7;
        aoff[i] = (size_t)(m0 + rm) * K + (size_t)((rc ^ (rm & 7)) * 8);
        boff[i] = (size_t)(n0 + rm) * K + (size_t)((rc ^ (rm & 7)) * 8);
    }

    const int xorA = (lr & 7) << 4;
    int aroff[4][2], broff[4][2];
#pragma unroll
    for (int mf = 0; mf < 4; ++mf)
#pragma unroll
        for (int ks = 0; ks < 2; ++ks)
            aroff[mf][ks] = (((wr * 64 + mf * 16 + lr) * 128) + lg * 16 + ks * 64) ^ xorA;
#pragma unroll
    for (int nf = 0; nf < 4; ++nf)
#pragma unroll
        for (int ks = 0; ks < 2; ++ks)
            broff[nf][ks] = (((wc * 64 + nf * 16 + lr) * 128) + lg * 16 + ks * 64) ^ xorA;

    f32x4 macc[4][4];
#pragma unroll
    for (int mf = 0; mf < 4; ++mf)
#pragma unroll
        for (int nf = 0; nf < 4; ++nf) macc[mf][nf] = f32x4{0.f, 0.f, 0.f, 0.f};

#define OP_STAGE(AH, BH, k0) { \
    gl_lds16(Xb + (k0) + aoff[0], (char*)(AH) + ldsAw); \
    gl_lds16(Xb + (k0) + aoff[1], (char*)(AH) + 4096 + ldsAw); \
    gl_lds16(Xb + (k0) + aoff[2], (char*)(AH) + 8192 + ldsAw); \
    gl_lds16(Xb + (k0) + aoff[3], (char*)(AH) + 12288 + ldsAw); \
    gl_lds16(WTO + (k0) + boff[0], (char*)(BH) + ldsAw); \
    gl_lds16(WTO + (k0) + boff[1], (char*)(BH) + 4096 + ldsAw); \
    gl_lds16(WTO + (k0) + boff[2], (char*)(BH) + 8192 + ldsAw); \
    gl_lds16(WTO + (k0) + boff[3], (char*)(BH) + 12288 + ldsAw); }

#define OP_COMPUTE(AH, BT) { \
    _Pragma("unroll") \
    for (int ks = 0; ks < 2; ++ks) { \
        half8v av[4], bv[4]; \
        _Pragma("unroll") \
        for (int mf = 0; mf < 4; ++mf) \
            av[mf] = *(const half8v*)((const char*)(AH) + aroff[mf][ks]); \
        _Pragma("unroll") \
        for (int nf = 0; nf < 4; ++nf) \
            bv[nf] = *(const half8v*)((const char*)(BT) + broff[nf][ks]); \
        _Pragma("unroll") \
        for (int mf = 0; mf < 4; ++mf) \
            _Pragma("unroll") \
            for (int nf = 0; nf < 4; ++nf) \
                macc[mf][nf] = __builtin_amdgcn_mfma_f32_16x16x32_f16(av[mf], bv[nf], macc[mf][nf], 0, 0, 0); \
    } }

    OP_STAGE(A0, B0, 0);
    WAIT_VM(0);
    RAW_BARRIER;

    for (int g = 0; g < 31; ++g) {
        OP_STAGE(A1, B1, (2 * g + 1) * 64);
        OP_COMPUTE(A0, B0);
        WAIT_VM(0);
        RAW_BARRIER;
        OP_STAGE(A0, B0, (2 * g + 2) * 64);
        OP_COMPUTE(A1, B1);
        WAIT_VM(0);
        RAW_BARRIER;
    }
    OP_STAGE(A1, B1, 63 * 64);
    OP_COMPUTE(A0, B0);
    WAIT_VM(0);
    RAW_BARRIER;
    OP_COMPUTE(A1, B1);

#pragma unroll
    for (int mf = 0; mf < 4; ++mf)
#pragma unroll
        for (int r = 0; r < 4; ++r) {
            int row = m0 + wr * 64 + mf * 16 + lg * 4 + r;
#pragma unroll
            for (int nf = 0; nf < 4; ++nf)
                Y[(size_t)row * N + n0 + wc * 64 + nf * 16 + lr] = macc[mf][nf][r];
        }
#undef OP_STAGE
#undef OP_COMPUTE
}

// ---------------------------------------------------------------------------
// Causal GQA flash attention (verified round-24 form, NO setprio).
// ---------------------------------------------------------------------------
__global__ __launch_bounds__(256) void attn_mfma_kernel(
    const ushort* __restrict__ Qh,   // [S][NH*HD] fp16, roped, *log2e/sqrt(HD)
    const ushort* __restrict__ Kh,   // [S][NKV*HD] fp16, roped
    const ushort* __restrict__ Vt,   // [NKV*HD][S] fp16 (transposed)
    ushort* __restrict__ AO)         // [S][NH*HD] fp16
{
    __shared__ ushort Ks0[32 * 128];           // swz ^((row&7)<<4)
    __shared__ ushort Ks1[32 * 128];
    __shared__ ushort Vs0[128 * 32];           // swz ^(((dim>>1)&3)<<4)
    __shared__ ushort Vs1[128 * 32];
    __shared__ __align__(16) char PsB[4 * 1280];  // P: 16 rows x 80B per wave

    const int h  = blockIdx.x;
    const int qb = gridDim.y - 1 - blockIdx.y;   // long blocks dispatch first
    const int s0 = qb * 64;
    const int t  = threadIdx.x;
    const int w  = t >> 6;
    const int l  = t & 63;
    const int lg = l >> 4;
    const int lr = l & 15;
    const int kvh = h >> 2;
    const int qw = s0 + w * 16;
    const int q  = qw + lr;          // this lane's q-row

    half8v qf[4];
#pragma unroll
    for (int d = 0; d < 4; ++d) {
        size_t off = (size_t)q * (NH * HD) + h * HD + d * 32 + lg * 8;
        qf[d] = *(const half8v*)&Qh[off];
    }

    f32x4 o[8];
#pragma unroll
    for (int i = 0; i < 8; ++i) o[i] = f32x4{0.f, 0.f, 0.f, 0.f};
    float m = -1e30f, lsum = 0.f;
    char* pw = PsB + w * 1280;

#define ATTN_STAGE(KB, VB, k0) { \
    _Pragma("unroll") \
    for (int i = 0; i < 2; ++i) { \
        int slot = w * 128 + i * 64 + l; \
        int mr = slot >> 4, c = slot & 15; \
        size_t goff = (size_t)((k0) + mr) * (NKV * HD) + kvh * HD + ((c ^ (mr & 7)) * 8); \
        gl_lds16(Kh + goff, (char*)(KB) + (w * 128 + i * 64) * 16); \
    } \
    _Pragma("unroll") \
    for (int i = 0; i < 2; ++i) { \
        int slot = w * 128 + i * 64 + l; \
        int dim = slot >> 2, c = slot & 3; \
        size_t goff = (size_t)(kvh * HD + dim) * S_LEN + (k0) + ((c ^ ((dim >> 1) & 3)) * 8); \
        gl_lds16(Vt + goff, (char*)(VB) + (w * 128 + i * 64) * 16); \
    } }

#define ATTN_TILE(KSF, VSS, k0) \
    if ((k0) <= qw + 15) { \
        f32x4 s_[2]; \
        s_[0] = f32x4{0.f, 0.f, 0.f, 0.f}; \
        s_[1] = f32x4{0.f, 0.f, 0.f, 0.f}; \
        _Pragma("unroll") \
        for (int d = 0; d < 4; ++d) { \
            _Pragma("unroll") \
            for (int nt2 = 0; nt2 < 2; ++nt2) { \
                int row = nt2 * 16 + lr; \
                int off = row * 256 + ((d * 64 + lg * 16) ^ ((row & 7) << 4)); \
                half8v kf = *(const half8v*)((const char*)(KSF) + off); \
                s_[nt2] = __builtin_amdgcn_mfma_f32_16x16x32_f16(kf, qf[d], s_[nt2], 0, 0, 0); \
            } \
        } \
        float sv[8]; \
        _Pragma("unroll") \
        for (int nt2 = 0; nt2 < 2; ++nt2) \
            _Pragma("unroll") \
            for (int r = 0; r < 4; ++r) { \
                int kv = (k0) + nt2 * 16 + lg * 4 + r; \
                sv[nt2 * 4 + r] = (kv <= q) ? s_[nt2][r] : -1e30f; \
            } \
        float mx = sv[0]; \
        _Pragma("unroll") \
        for (int j = 1; j < 8; ++j) mx = fmaxf(mx, sv[j]); \
        mx = fmaxf(mx, __shfl_xor(mx, 16)); \
        mx = fmaxf(mx, __shfl_xor(mx, 32)); \
        float mnew = fmaxf(m, mx); \
        float resc = __builtin_amdgcn_exp2f(m - mnew); \
        m = mnew; \
        float p_[8], ps = 0.f; \
        _Pragma("unroll") \
        for (int j = 0; j < 8; ++j) { p_[j] = __builtin_amdgcn_exp2f(sv[j] - mnew); ps += p_[j]; } \
        ps += __shfl_xor(ps, 16); \
        ps += __shfl_xor(ps, 32); \
        lsum = lsum * resc + ps; \
        _Pragma("unroll") \
        for (int dt = 0; dt < 8; ++dt) \
            _Pragma("unroll") \
            for (int r = 0; r < 4; ++r) o[dt][r] *= resc; \
        uint2 w0_ = {pk2(f2h(p_[0]), f2h(p_[1])), pk2(f2h(p_[2]), f2h(p_[3]))}; \
        uint2 w1_ = {pk2(f2h(p_[4]), f2h(p_[5])), pk2(f2h(p_[6]), f2h(p_[7]))}; \
        *(uint2*)(pw + lr * 80 + lg * 8)      = w0_; \
        *(uint2*)(pw + lr * 80 + 32 + lg * 8) = w1_; \
        asm volatile("s_waitcnt lgkmcnt(0)" ::: "memory"); \
        half8v pf = *(const half8v*)(pw + lr * 80 + lg * 16); \
        _Pragma("unroll") \
        for (int dt = 0; dt < 8; ++dt) { \
            int dim = dt * 16 + lr; \
            half8v vf = *(const half8v*)((const char*)(VSS) + dim * 64 + ((lg * 16) ^ (((dim >> 1) & 3) << 4))); \
            o[dt] = __builtin_amdgcn_mfma_f32_16x16x32_f16(vf, pf, o[dt], 0, 0, 0); \
        } \
    }

    const int ntiles = qb * 2 + 2;   // always even

    ATTN_STAGE(Ks0, Vs0, 0);
    WAIT_VM(0);
    RAW_BARRIER;

    for (int kt = 0; kt < ntiles; kt += 2) {
        if (kt + 1 < ntiles) ATTN_STAGE(Ks1, Vs1, (kt + 1) * 32);
        ATTN_TILE(Ks0, Vs0, kt * 32);
        WAIT_VM(0);
        RAW_BARRIER;
        if (kt + 2 < ntiles) ATTN_STAGE(Ks0, Vs0, (kt + 2) * 32);
        ATTN_TILE(Ks1, Vs1, (kt + 1) * 32);
        WAIT_VM(0);
        RAW_BARRIER;
    }

    float inv = 1.f / lsum;
    ushort* dst = &AO[(size_t)q * (NH * HD) + h * HD];
#pragma unroll
    for (int dt = 0; dt < 8; ++dt) {
        uint2 ov = {pk2(f2h(o[dt][0] * inv), f2h(o[dt][1] * inv)),
                    pk2(f2h(o[dt][2] * inv), f2h(o[dt][3] * inv))};
        *(uint2*)(dst + dt * 16 + lg * 4) = ov;
    }
#undef ATTN_STAGE
#undef ATTN_TILE
}

// ---------------------------------------------------------------------------
extern "C" void kernel_launch(void* const* d_in, const int* in_sizes, int n_in,
                              void* d_out, int out_size, void* d_ws, size_t ws_size,
                              hipStream_t stream)
{
    const float* x    = (const float*)d_in[0];
    const float* cosb = (const float*)d_in[1];
    const float* sinb = (const float*)d_in[2];
    const float* q_sc = (const float*)d_in[3];
    const float* q_b  = (const float*)d_in[4];
    const float* k_sc = (const float*)d_in[5];
    const float* k_b  = (const float*)d_in[6];
    const float* v_sc = (const float*)d_in[7];
    const float* v_b  = (const float*)d_in[8];
    const float* o_sc = (const float*)d_in[9];
    const int* q_qw   = (const int*)d_in[10];
    const int* q_qz   = (const int*)d_in[11];
    const int* k_qw   = (const int*)d_in[12];
    const int* k_qz   = (const int*)d_in[13];
    const int* v_qw   = (const int*)d_in[14];
    const int* v_qz   = (const int*)d_in[15];
    const int* o_qw   = (const int*)d_in[16];
    const int* o_qz   = (const int*)d_in[17];
    float* out = (float*)d_out;

    // ws layout (MB), lifetimes:
    //   0..10   Xf16 (prep -> qkv12)  [AOf16 0..16 written by attn, read oproj]
    //   10..40  WT (prep -> qkv12, dead after)
    //   16..36  WTO (prep2 AFTER qkv12; disjoint from AOf 0..16)
    //   40..56  Qf | 56..60 Kf | 64..68 VfT
    char* ws = (char*)d_ws;
    ushort* Xf   = (ushort*)ws;
    ushort* AOf  = (ushort*)ws;                                  // alias 0..16
    ushort* WT   = (ushort*)(ws + (size_t)10 * 1024 * 1024);
    ushort* WTO  = (ushort*)(ws + (size_t)16 * 1024 * 1024);
    ushort* Qf   = (ushort*)(ws + (size_t)40 * 1024 * 1024);
    ushort* Kf   = (ushort*)(ws + (size_t)56 * 1024 * 1024);
    ushort* VfT  = (ushort*)(ws + (size_t)64 * 1024 * 1024);

    prep_kernel<<<4480, 256, 0, stream>>>(
        x, Xf,
        q_qw, q_sc, q_qz, k_qw, k_sc, k_qz, v_qw, v_sc, v_qz, WT);

    qkv12_kernel<<<768, 256, 0, stream>>>(
        Xf, WT, q_b, k_b, v_b, cosb, sinb, Qf, Kf, VfT);

    prep2_kernel<<<1280, 256, 0, stream>>>(o_qw, o_sc, o_qz, WTO);

    attn_mfma_kernel<<<dim3(NH, S_LEN / 64), 256, 0, stream>>>(Qf, Kf, VfT, AOf);

    oproj9_kernel<<<320, 256, 0, stream>>>(AOf, WTO, out);
}

// Round 27
// 236.881 us; speedup vs baseline: 1.1649x; 1.0042x over previous
//
#include <hip/hip_runtime.h>
#include <hip/hip_bf16.h>
#include <cstdint>

#define S_LEN 2048
#define HIDDEN 2560
#define NH 32
#define NKV 8
#define HD 128
#define GS 128

typedef __attribute__((ext_vector_type(8))) _Float16 half8v;    // 8 x fp16
typedef __attribute__((ext_vector_type(2))) _Float16 half2v;    // 2 x fp16
typedef __attribute__((ext_vector_type(4))) float f32x4;
typedef unsigned int uint;
typedef unsigned short ushort;

__device__ inline ushort f2h(float f) {
    _Float16 h = (_Float16)f;
    return __builtin_bit_cast(ushort, h);
}
__device__ inline float h2f(ushort u) {
    return (float)__builtin_bit_cast(_Float16, u);
}
__device__ inline uint pk2(ushort a, ushort b) { return (uint)a | ((uint)b << 16); }

// async global->LDS, 16B per lane; lds base must be wave-uniform
__device__ __attribute__((always_inline)) inline void gl_lds16(const void* g, void* l) {
    __builtin_amdgcn_global_load_lds(
        (const __attribute__((address_space(1))) unsigned int*)g,
        (__attribute__((address_space(3))) unsigned int*)l, 16, 0, 0);
}

#define WAIT_LGKM0  asm volatile("s_waitcnt lgkmcnt(0)" ::: "memory")
#define WAIT_VM(N)  asm volatile("s_waitcnt vmcnt(" #N ")" ::: "memory")
#define RAW_BARRIER { __builtin_amdgcn_s_barrier(); __builtin_amdgcn_sched_barrier(0); }

// ---------------------------------------------------------------------------
// Shared weight-dequant tile body (verified numerics): one 64n x 128k tile.
// ---------------------------------------------------------------------------
__device__ __attribute__((always_inline)) inline void wdq_tile(
    const int* __restrict__ QW, const float* __restrict__ SC,
    const int* __restrict__ QZ, ushort* __restrict__ Wout,
    int Nw, int Kout, int nloc0, int wtbase, int kt, int t, char* Ts)
{
    const int k80 = kt * 16;
    const int nn  = t & 63;
    const float scf = SC[(size_t)kt * Nw + nloc0 + nn];
    const float zf  = (float)QZ[(size_t)kt * Nw + nloc0 + nn];
    ushort sch = f2h(scf);
    float schf = h2f(sch);
    ushort msc = f2h(-128.0f * schf);   // exact exponent shift
    ushort nzs = f2h(-(zf * schf));
    half2v S2 = {__builtin_bit_cast(_Float16, sch), __builtin_bit_cast(_Float16, sch)};
    half2v M2 = {__builtin_bit_cast(_Float16, msc), __builtin_bit_cast(_Float16, msc)};
    half2v Z2 = {__builtin_bit_cast(_Float16, nzs), __builtin_bit_cast(_Float16, nzs)};

#pragma unroll
    for (int i = 0; i < 4; ++i) {
        int kw = i * 4 + (t >> 6);
        uint q = (uint)QW[(size_t)(k80 + kw) * Nw + nloc0 + nn];
        uint xn = q & 0x0F0F0F0Fu;
        uint yn = (q >> 4) & 0x0F0F0F0Fu;
        uint W0 = __builtin_amdgcn_perm(yn, xn, 0x0C040C00u);
        uint W1 = __builtin_amdgcn_perm(yn, xn, 0x0C050C01u);
        uint W2 = __builtin_amdgcn_perm(yn, xn, 0x0C060C02u);
        uint W3 = __builtin_amdgcn_perm(yn, xn, 0x0C070C03u);
        uint e0 = (W0 << 3) | 0x58005800u;
        uint e1 = (W1 << 3) | 0x58005800u;
        uint e2 = (W2 << 3) | 0x58005800u;
        uint e3 = (W3 << 3) | 0x58005800u;
        half2v w0 = __builtin_bit_cast(half2v, e0) * S2 + M2; w0 = w0 + Z2;
        half2v w1 = __builtin_bit_cast(half2v, e1) * S2 + M2; w1 = w1 + Z2;
        half2v w2 = __builtin_bit_cast(half2v, e2) * S2 + M2; w2 = w2 + Z2;
        half2v w3 = __builtin_bit_cast(half2v, e3) * S2 + M2; w3 = w3 + Z2;
        uint4 dw = {__builtin_bit_cast(uint, w0), __builtin_bit_cast(uint, w1),
                    __builtin_bit_cast(uint, w2), __builtin_bit_cast(uint, w3)};
        *(uint4*)(Ts + nn * 256 + ((kw * 16) ^ ((nn & 7) << 4))) = dw;
    }
    __syncthreads();
    const int kc = t & 15;
#pragma unroll
    for (int i = 0; i < 4; ++i) {
        int nr = i * 16 + (t >> 4);
        uint4 v = *(const uint4*)(Ts + nr * 256 + ((kc * 16) ^ ((nr & 7) << 4)));
        *(uint4*)&Wout[(size_t)(wtbase + nr) * Kout + kt * 128 + kc * 8] = v;
    }
}

// ===========================================================================
// Prepass 1: blocks [0,2560) X->fp16; [2560,4480) QKV weight dequant -> WT.
// ===========================================================================
__global__ __launch_bounds__(256) void prep_kernel(
    const float* __restrict__ X, ushort* __restrict__ Xf,
    const int* __restrict__ q_qw, const float* __restrict__ q_sc, const int* __restrict__ q_qz,
    const int* __restrict__ k_qw, const float* __restrict__ k_sc, const int* __restrict__ k_qz,
    const int* __restrict__ v_qw, const float* __restrict__ v_sc, const int* __restrict__ v_qz,
    ushort* __restrict__ WT)
{
    __shared__ __align__(16) char Ts[16384];
    const int bid = blockIdx.x;
    const int t   = threadIdx.x;

    if (bid < 2560) {
        const size_t base = (size_t)bid * 2048 + (size_t)t * 8;
        float4 a = *(const float4*)&X[base];
        float4 b = *(const float4*)&X[base + 4];
        uint4 hw = {pk2(f2h(a.x), f2h(a.y)), pk2(f2h(a.z), f2h(a.w)),
                    pk2(f2h(b.x), f2h(b.y)), pk2(f2h(b.z), f2h(b.w))};
        *(uint4*)&Xf[base] = hw;
        return;
    }

    const int b2 = bid - 2560;
    const int bx = b2 % 96;
    const int kt = b2 / 96;

    int nloc0, wtbase, Nw;
    const int* QW; const float* SC; const int* QZ;
    if (bx < 64)      { Nw = NH * HD;  nloc0 = bx * 64;        wtbase = bx * 64;
                        QW = q_qw; SC = q_sc; QZ = q_qz; }
    else if (bx < 80) { Nw = NKV * HD; nloc0 = (bx - 64) * 64; wtbase = 4096 + nloc0;
                        QW = k_qw; SC = k_sc; QZ = k_qz; }
    else              { Nw = NKV * HD; nloc0 = (bx - 80) * 64; wtbase = 5120 + nloc0;
                        QW = v_qw; SC = v_sc; QZ = v_qz; }

    wdq_tile(QW, SC, QZ, WT, Nw, HIDDEN, nloc0, wtbase, kt, t, Ts);
}

// ===========================================================================
// Prepass 2 (after qkv12): O-weight dequant -> WTO[2560][4096] fp16.
// ===========================================================================
__global__ __launch_bounds__(256) void prep2_kernel(
    const int* __restrict__ o_qw, const float* __restrict__ o_sc,
    const int* __restrict__ o_qz, ushort* __restrict__ WTO)
{
    __shared__ __align__(16) char Ts[16384];
    const int bid = blockIdx.x;
    const int t   = threadIdx.x;
    const int bx  = bid % 40;
    const int kt  = bid / 40;
    wdq_tile(o_qw, o_sc, o_qz, WTO, HIDDEN, NH * HD, bx * 64, bx * 64, kt, t, Ts);
}

// ===========================================================================
// Fused Q/K/V MFMA GEMM on fp16 WT (unchanged — verified).
// ===========================================================================
__global__ __launch_bounds__(256) void qkv12_kernel(
    const ushort* __restrict__ Xf, const ushort* __restrict__ WT,
    const float* __restrict__ q_b, const float* __restrict__ k_b,
    const float* __restrict__ v_b,
    const float* __restrict__ cosb, const float* __restrict__ sinb,
    ushort* __restrict__ Qf, ushort* __restrict__ Kf,
    ushort* __restrict__ VfT)
{
    __shared__ __align__(16) char LDSB[65536];
    ushort* A0 = (ushort*)(LDSB);
    ushort* A1 = (ushort*)(LDSB + 16384);
    ushort* B0 = (ushort*)(LDSB + 32768);
    ushort* B1 = (ushort*)(LDSB + 49152);

    const int t  = threadIdx.x;
    const int w  = t >> 6;
    const int l  = t & 63;
    const int lg = l >> 4;
    const int lr = l & 15;
    const int wr = w >> 1;
    const int wc = w & 1;
    const int K  = HIDDEN;

    const int bid  = blockIdx.x;
    const int xcd  = bid & 7;
    const int j    = bid >> 3;
    const int nblk = xcd * 6 + (j >> 4);
    const int m0   = (j & 15) * 128;
    const int wtrow = nblk * 128;

    int region, nbase;
    const float* BI;
    if (nblk < 32)      { region = 0; nbase = nblk * 128;        BI = q_b; }
    else if (nblk < 40) { region = 1; nbase = (nblk - 32) * 128; BI = k_b; }
    else                { region = 2; nbase = (nblk - 40) * 128; BI = v_b; }

    const int ldsAw = w * 1024;
    size_t aoff[4], boff[4];
#pragma unroll
    for (int i = 0; i < 4; ++i) {
        int slot = i * 256 + t;
        int rm = slot >> 3, rc = slot & 7;
        aoff[i] = (size_t)(m0 + rm) * K + (size_t)((rc ^ (rm & 7)) * 8);
        boff[i] = (size_t)(wtrow + rm) * K + (size_t)((rc ^ (rm & 7)) * 8);
    }

    int ncm[4];
#pragma unroll
    for (int nf = 0; nf < 4; ++nf)
        ncm[nf] = wc * 32 + (nf & 1) * 16 + lr + ((nf & 2) ? 64 : 0);

    const int xorA = (lr & 7) << 4;
    int aroff[4][2], broff[4][2];
#pragma unroll
    for (int mf = 0; mf < 4; ++mf)
#pragma unroll
        for (int ks = 0; ks < 2; ++ks)
            aroff[mf][ks] = (((wr * 64 + mf * 16 + lr) * 128) + lg * 16 + ks * 64) ^ xorA;
#pragma unroll
    for (int nf = 0; nf < 4; ++nf)
#pragma unroll
        for (int ks = 0; ks < 2; ++ks)
            broff[nf][ks] = ((ncm[nf] * 128) + lg * 16 + ks * 64) ^ xorA;

    f32x4 macc[4][4];
#pragma unroll
    for (int mf = 0; mf < 4; ++mf)
#pragma unroll
        for (int nf = 0; nf < 4; ++nf) macc[mf][nf] = f32x4{0.f, 0.f, 0.f, 0.f};

#define QKV_STAGE(AH, BH, k0) { \
    gl_lds16(Xf + (k0) + aoff[0], (char*)(AH) + ldsAw); \
    gl_lds16(Xf + (k0) + aoff[1], (char*)(AH) + 4096 + ldsAw); \
    gl_lds16(Xf + (k0) + aoff[2], (char*)(AH) + 8192 + ldsAw); \
    gl_lds16(Xf + (k0) + aoff[3], (char*)(AH) + 12288 + ldsAw); \
    gl_lds16(WT + (k0) + boff[0], (char*)(BH) + ldsAw); \
    gl_lds16(WT + (k0) + boff[1], (char*)(BH) + 4096 + ldsAw); \
    gl_lds16(WT + (k0) + boff[2], (char*)(BH) + 8192 + ldsAw); \
    gl_lds16(WT + (k0) + boff[3], (char*)(BH) + 12288 + ldsAw); }

#define QKV_COMPUTE(AH, BT) { \
    _Pragma("unroll") \
    for (int ks = 0; ks < 2; ++ks) { \
        half8v av[4], bv[4]; \
        _Pragma("unroll") \
        for (int mf = 0; mf < 4; ++mf) \
            av[mf] = *(const half8v*)((const char*)(AH) + aroff[mf][ks]); \
        _Pragma("unroll") \
        for (int nf = 0; nf < 4; ++nf) \
            bv[nf] = *(const half8v*)((const char*)(BT) + broff[nf][ks]); \
        _Pragma("unroll") \
        for (int mf = 0; mf < 4; ++mf) \
            _Pragma("unroll") \
            for (int nf = 0; nf < 4; ++nf) \
                macc[mf][nf] = __builtin_amdgcn_mfma_f32_16x16x32_f16(av[mf], bv[nf], macc[mf][nf], 0, 0, 0); \
    } }

    QKV_STAGE(A0, B0, 0);
    WAIT_VM(0);
    RAW_BARRIER;

    for (int g = 0; g < 19; ++g) {
        QKV_STAGE(A1, B1, (2 * g + 1) * 64);
        QKV_COMPUTE(A0, B0);
        WAIT_VM(0);
        RAW_BARRIER;
        QKV_STAGE(A0, B0, (2 * g + 2) * 64);
        QKV_COMPUTE(A1, B1);
        WAIT_VM(0);
        RAW_BARRIER;
    }
    QKV_STAGE(A1, B1, 39 * 64);
    QKV_COMPUTE(A0, B0);
    WAIT_VM(0);
    RAW_BARRIER;
    QKV_COMPUTE(A1, B1);

#pragma unroll
    for (int nf = 0; nf < 4; ++nf) {
        float bv = BI[nbase + ncm[nf]];
#pragma unroll
        for (int mf = 0; mf < 4; ++mf)
#pragma unroll
            for (int r = 0; r < 4; ++r) macc[mf][nf][r] += bv;
    }

    if (region == 2) {
        WAIT_LGKM0;
        RAW_BARRIER;
        ushort* EP = (ushort*)LDSB;        // [128][130] padded
#pragma unroll
        for (int mf = 0; mf < 4; ++mf)
#pragma unroll
            for (int r = 0; r < 4; ++r) {
                int row = wr * 64 + mf * 16 + lg * 4 + r;
#pragma unroll
                for (int nf = 0; nf < 4; ++nf)
                    EP[row * 130 + ncm[nf]] = f2h(macc[mf][nf][r]);
            }
        WAIT_LGKM0;
        RAW_BARRIER;
        const int c   = t >> 1;
        const int seg = (t & 1) * 64;
        ushort* dst = &VfT[(size_t)(nbase + c) * S_LEN + m0 + seg];
#pragma unroll
        for (int g8 = 0; g8 < 8; ++g8) {
            ushort buf[8];
#pragma unroll
            for (int jj = 0; jj < 8; ++jj)
                buf[jj] = EP[(seg + g8 * 8 + jj) * 130 + c];
            *(uint4*)(dst + g8 * 8) = *(uint4*)buf;
        }
    } else {
        ushort* OF = (region == 0) ? Qf : Kf;
        const int No = (region == 0) ? NH * HD : NKV * HD;
        const float osc = (region == 0)
            ? 0.08838834764831845f * 1.44269504088896341f : 1.0f;
#pragma unroll
        for (int mf = 0; mf < 4; ++mf)
#pragma unroll
            for (int r = 0; r < 4; ++r) {
                int row = m0 + wr * 64 + mf * 16 + lg * 4 + r;
                const float* cb = &cosb[(size_t)row * HD];
                const float* sb = &sinb[(size_t)row * HD];
#pragma unroll
                for (int nf = 0; nf < 2; ++nf) {
                    int d = wc * 32 + nf * 16 + lr;
                    float a = macc[mf][nf][r];
                    float b = macc[mf][nf + 2][r];
                    float o1 = (a * cb[d]      - b * sb[d])      * osc;
                    float o2 = (b * cb[d + 64] + a * sb[d + 64]) * osc;
                    OF[(size_t)row * No + nbase + d]      = f2h(o1);
                    OF[(size_t)row * No + nbase + d + 64] = f2h(o2);
                }
            }
    }
#undef QKV_STAGE
#undef QKV_COMPUTE
}

// ===========================================================================
// O-projection on pre-dequanted WTO (unchanged — verified).
// ===========================================================================
__global__ __launch_bounds__(256) void oproj9_kernel(
    const ushort* __restrict__ Xb, const ushort* __restrict__ WTO,
    float* __restrict__ Y)
{
    __shared__ __align__(16) char LDSB[65536];
    ushort* A0 = (ushort*)(LDSB);
    ushort* A1 = (ushort*)(LDSB + 16384);
    ushort* B0 = (ushort*)(LDSB + 32768);
    ushort* B1 = (ushort*)(LDSB + 49152);

    const int t  = threadIdx.x;
    const int w  = t >> 6;
    const int l  = t & 63;
    const int lg = l >> 4;
    const int lr = l & 15;
    const int wr = w >> 1;
    const int wc = w & 1;
    const int K  = NH * HD;      // 4096
    const int N  = HIDDEN;       // 2560

    const int bid  = blockIdx.x;
    const int xcd  = bid & 7;
    const int grp  = xcd >> 1;
    const int j    = (bid >> 3) * 2 + (xcd & 1);
    const int nblk = grp * 5 + (j % 5);
    const int m0   = (j / 5) * 128;
    const int n0   = nblk * 128;

    const int ldsAw = w * 1024;
    size_t aoff[4], boff[4];
#pragma unroll
    for (int i = 0; i < 4; ++i) {
        int slot = i * 256 + t;
        int rm = slot >> 3, rc = slot & 7;
        aoff[i] = (size_t)(m0 + rm) * K + (size_t)((rc ^ (rm & 7)) * 8);
        boff[i] = (size_t)(n0 + rm) * K + (size_t)((rc ^ (rm & 7)) * 8);
    }

    const int xorA = (lr & 7) << 4;
    int aroff[4][2], broff[4][2];
#pragma unroll
    for (int mf = 0; mf < 4; ++mf)
#pragma unroll
        for (int ks = 0; ks < 2; ++ks)
            aroff[mf][ks] = (((wr * 64 + mf * 16 + lr) * 128) + lg * 16 + ks * 64) ^ xorA;
#pragma unroll
    for (int nf = 0; nf < 4; ++nf)
#pragma unroll
        for (int ks = 0; ks < 2; ++ks)
            broff[nf][ks] = (((wc * 64 + nf * 16 + lr) * 128) + lg * 16 + ks * 64) ^ xorA;

    f32x4 macc[4][4];
#pragma unroll
    for (int mf = 0; mf < 4; ++mf)
#pragma unroll
        for (int nf = 0; nf < 4; ++nf) macc[mf][nf] = f32x4{0.f, 0.f, 0.f, 0.f};

#define OP_STAGE(AH, BH, k0) { \
    gl_lds16(Xb + (k0) + aoff[0], (char*)(AH) + ldsAw); \
    gl_lds16(Xb + (k0) + aoff[1], (char*)(AH) + 4096 + ldsAw); \
    gl_lds16(Xb + (k0) + aoff[2], (char*)(AH) + 8192 + ldsAw); \
    gl_lds16(Xb + (k0) + aoff[3], (char*)(AH) + 12288 + ldsAw); \
    gl_lds16(WTO + (k0) + boff[0], (char*)(BH) + ldsAw); \
    gl_lds16(WTO + (k0) + boff[1], (char*)(BH) + 4096 + ldsAw); \
    gl_lds16(WTO + (k0) + boff[2], (char*)(BH) + 8192 + ldsAw); \
    gl_lds16(WTO + (k0) + boff[3], (char*)(BH) + 12288 + ldsAw); }

#define OP_COMPUTE(AH, BT) { \
    _Pragma("unroll") \
    for (int ks = 0; ks < 2; ++ks) { \
        half8v av[4], bv[4]; \
        _Pragma("unroll") \
        for (int mf = 0; mf < 4; ++mf) \
            av[mf] = *(const half8v*)((const char*)(AH) + aroff[mf][ks]); \
        _Pragma("unroll") \
        for (int nf = 0; nf < 4; ++nf) \
            bv[nf] = *(const half8v*)((const char*)(BT) + broff[nf][ks]); \
        _Pragma("unroll") \
        for (int mf = 0; mf < 4; ++mf) \
            _Pragma("unroll") \
            for (int nf = 0; nf < 4; ++nf) \
                macc[mf][nf] = __builtin_amdgcn_mfma_f32_16x16x32_f16(av[mf], bv[nf], macc[mf][nf], 0, 0, 0); \
    } }

    OP_STAGE(A0, B0, 0);
    WAIT_VM(0);
    RAW_BARRIER;

    for (int g = 0; g < 31; ++g) {
        OP_STAGE(A1, B1, (2 * g + 1) * 64);
        OP_COMPUTE(A0, B0);
        WAIT_VM(0);
        RAW_BARRIER;
        OP_STAGE(A0, B0, (2 * g + 2) * 64);
        OP_COMPUTE(A1, B1);
        WAIT_VM(0);
        RAW_BARRIER;
    }
    OP_STAGE(A1, B1, 63 * 64);
    OP_COMPUTE(A0, B0);
    WAIT_VM(0);
    RAW_BARRIER;
    OP_COMPUTE(A1, B1);

#pragma unroll
    for (int mf = 0; mf < 4; ++mf)
#pragma unroll
        for (int r = 0; r < 4; ++r) {
            int row = m0 + wr * 64 + mf * 16 + lg * 4 + r;
#pragma unroll
            for (int nf = 0; nf < 4; ++nf)
                Y[(size_t)row * N + n0 + wc * 64 + nf * 16 + lr] = macc[mf][nf][r];
        }
#undef OP_STAGE
#undef OP_COMPUTE
}

// ---------------------------------------------------------------------------
// Causal GQA flash attention (r24 base); ONLY change: wave-uniform interior
// fast path skips the vacuous causal mask when k0+31 <= qw (provably
// mask-free: kv <= k0+31 <= qw <= q for every lane). No sync change.
// ---------------------------------------------------------------------------
__global__ __launch_bounds__(256) void attn_mfma_kernel(
    const ushort* __restrict__ Qh,   // [S][NH*HD] fp16, roped, *log2e/sqrt(HD)
    const ushort* __restrict__ Kh,   // [S][NKV*HD] fp16, roped
    const ushort* __restrict__ Vt,   // [NKV*HD][S] fp16 (transposed)
    ushort* __restrict__ AO)         // [S][NH*HD] fp16
{
    __shared__ ushort Ks0[32 * 128];           // swz ^((row&7)<<4)
    __shared__ ushort Ks1[32 * 128];
    __shared__ ushort Vs0[128 * 32];           // swz ^(((dim>>1)&3)<<4)
    __shared__ ushort Vs1[128 * 32];
    __shared__ __align__(16) char PsB[4 * 1280];  // P: 16 rows x 80B per wave

    const int h  = blockIdx.x;
    const int qb = gridDim.y - 1 - blockIdx.y;   // long blocks dispatch first
    const int s0 = qb * 64;
    const int t  = threadIdx.x;
    const int w  = t >> 6;
    const int l  = t & 63;
    const int lg = l >> 4;
    const int lr = l & 15;
    const int kvh = h >> 2;
    const int qw = s0 + w * 16;
    const int q  = qw + lr;          // this lane's q-row

    half8v qf[4];
#pragma unroll
    for (int d = 0; d < 4; ++d) {
        size_t off = (size_t)q * (NH * HD) + h * HD + d * 32 + lg * 8;
        qf[d] = *(const half8v*)&Qh[off];
    }

    f32x4 o[8];
#pragma unroll
    for (int i = 0; i < 8; ++i) o[i] = f32x4{0.f, 0.f, 0.f, 0.f};
    float m = -1e30f, lsum = 0.f;
    char* pw = PsB + w * 1280;

#define ATTN_STAGE(KB, VB, k0) { \
    _Pragma("unroll") \
    for (int i = 0; i < 2; ++i) { \
        int slot = w * 128 + i * 64 + l; \
        int mr = slot >> 4, c = slot & 15; \
        size_t goff = (size_t)((k0) + mr) * (NKV * HD) + kvh * HD + ((c ^ (mr & 7)) * 8); \
        gl_lds16(Kh + goff, (char*)(KB) + (w * 128 + i * 64) * 16); \
    } \
    _Pragma("unroll") \
    for (int i = 0; i < 2; ++i) { \
        int slot = w * 128 + i * 64 + l; \
        int dim = slot >> 2, c = slot & 3; \
        size_t goff = (size_t)(kvh * HD + dim) * S_LEN + (k0) + ((c ^ ((dim >> 1) & 3)) * 8); \
        gl_lds16(Vt + goff, (char*)(VB) + (w * 128 + i * 64) * 16); \
    } }

#define ATTN_TILE(KSF, VSS, k0) \
    if ((k0) <= qw + 15) { \
        f32x4 s_[2]; \
        s_[0] = f32x4{0.f, 0.f, 0.f, 0.f}; \
        s_[1] = f32x4{0.f, 0.f, 0.f, 0.f}; \
        _Pragma("unroll") \
        for (int d = 0; d < 4; ++d) { \
            _Pragma("unroll") \
            for (int nt2 = 0; nt2 < 2; ++nt2) { \
                int row = nt2 * 16 + lr; \
                int off = row * 256 + ((d * 64 + lg * 16) ^ ((row & 7) << 4)); \
                half8v kf = *(const half8v*)((const char*)(KSF) + off); \
                s_[nt2] = __builtin_amdgcn_mfma_f32_16x16x32_f16(kf, qf[d], s_[nt2], 0, 0, 0); \
            } \
        } \
        float sv[8]; \
        if ((k0) + 31 <= qw) { \
            _Pragma("unroll") \
            for (int nt2 = 0; nt2 < 2; ++nt2) \
                _Pragma("unroll") \
                for (int r = 0; r < 4; ++r) sv[nt2 * 4 + r] = s_[nt2][r]; \
        } else { \
            _Pragma("unroll") \
            for (int nt2 = 0; nt2 < 2; ++nt2) \
                _Pragma("unroll") \
                for (int r = 0; r < 4; ++r) { \
                    int kv = (k0) + nt2 * 16 + lg * 4 + r; \
                    sv[nt2 * 4 + r] = (kv <= q) ? s_[nt2][r] : -1e30f; \
                } \
        } \
        float mx = sv[0]; \
        _Pragma("unroll") \
        for (int j = 1; j < 8; ++j) mx = fmaxf(mx, sv[j]); \
        mx = fmaxf(mx, __shfl_xor(mx, 16)); \
        mx = fmaxf(mx, __shfl_xor(mx, 32)); \
        float mnew = fmaxf(m, mx); \
        float resc = __builtin_amdgcn_exp2f(m - mnew); \
        m = mnew; \
        float p_[8], ps = 0.f; \
        _Pragma("unroll") \
        for (int j = 0; j < 8; ++j) { p_[j] = __builtin_amdgcn_exp2f(sv[j] - mnew); ps += p_[j]; } \
        ps += __shfl_xor(ps, 16); \
        ps += __shfl_xor(ps, 32); \
        lsum = lsum * resc + ps; \
        _Pragma("unroll") \
        for (int dt = 0; dt < 8; ++dt) \
            _Pragma("unroll") \
            for (int r = 0; r < 4; ++r) o[dt][r] *= resc; \
        uint2 w0_ = {pk2(f2h(p_[0]), f2h(p_[1])), pk2(f2h(p_[2]), f2h(p_[3]))}; \
        uint2 w1_ = {pk2(f2h(p_[4]), f2h(p_[5])), pk2(f2h(p_[6]), f2h(p_[7]))}; \
        *(uint2*)(pw + lr * 80 + lg * 8)      = w0_; \
        *(uint2*)(pw + lr * 80 + 32 + lg * 8) = w1_; \
        asm volatile("s_waitcnt lgkmcnt(0)" ::: "memory"); \
        half8v pf = *(const half8v*)(pw + lr * 80 + lg * 16); \
        _Pragma("unroll") \
        for (int dt = 0; dt < 8; ++dt) { \
            int dim = dt * 16 + lr; \
            half8v vf = *(const half8v*)((const char*)(VSS) + dim * 64 + ((lg * 16) ^ (((dim >> 1) & 3) << 4))); \
            o[dt] = __builtin_amdgcn_mfma_f32_16x16x32_f16(vf, pf, o[dt], 0, 0, 0); \
        } \
    }

    const int ntiles = qb * 2 + 2;   // always even

    ATTN_STAGE(Ks0, Vs0, 0);
    WAIT_VM(0);
    RAW_BARRIER;

    for (int kt = 0; kt < ntiles; kt += 2) {
        if (kt + 1 < ntiles) ATTN_STAGE(Ks1, Vs1, (kt + 1) * 32);
        ATTN_TILE(Ks0, Vs0, kt * 32);
        WAIT_VM(0);
        RAW_BARRIER;
        if (kt + 2 < ntiles) ATTN_STAGE(Ks0, Vs0, (kt + 2) * 32);
        ATTN_TILE(Ks1, Vs1, (kt + 1) * 32);
        WAIT_VM(0);
        RAW_BARRIER;
    }

    float inv = 1.f / lsum;
    ushort* dst = &AO[(size_t)q * (NH * HD) + h * HD];
#pragma unroll
    for (int dt = 0; dt < 8; ++dt) {
        uint2 ov = {pk2(f2h(o[dt][0] * inv), f2h(o[dt][1] * inv)),
                    pk2(f2h(o[dt][2] * inv), f2h(o[dt][3] * inv))};
        *(uint2*)(dst + dt * 16 + lg * 4) = ov;
    }
#undef ATTN_STAGE
#undef ATTN_TILE
}

// ---------------------------------------------------------------------------
extern "C" void kernel_launch(void* const* d_in, const int* in_sizes, int n_in,
                              void* d_out, int out_size, void* d_ws, size_t ws_size,
                              hipStream_t stream)
{
    const float* x    = (const float*)d_in[0];
    const float* cosb = (const float*)d_in[1];
    const float* sinb = (const float*)d_in[2];
    const float* q_sc = (const float*)d_in[3];
    const float* q_b  = (const float*)d_in[4];
    const float* k_sc = (const float*)d_in[5];
    const float* k_b  = (const float*)d_in[6];
    const float* v_sc = (const float*)d_in[7];
    const float* v_b  = (const float*)d_in[8];
    const float* o_sc = (const float*)d_in[9];
    const int* q_qw   = (const int*)d_in[10];
    const int* q_qz   = (const int*)d_in[11];
    const int* k_qw   = (const int*)d_in[12];
    const int* k_qz   = (const int*)d_in[13];
    const int* v_qw   = (const int*)d_in[14];
    const int* v_qz   = (const int*)d_in[15];
    const int* o_qw   = (const int*)d_in[16];
    const int* o_qz   = (const int*)d_in[17];
    float* out = (float*)d_out;

    // ws layout (MB), lifetimes:
    //   0..10   Xf16 (prep -> qkv12)  [AOf16 0..16 written by attn, read oproj]
    //   10..40  WT (prep -> qkv12, dead after)
    //   16..36  WTO (prep2 AFTER qkv12; disjoint from AOf 0..16)
    //   40..56  Qf | 56..60 Kf | 64..68 VfT
    char* ws = (char*)d_ws;
    ushort* Xf   = (ushort*)ws;
    ushort* AOf  = (ushort*)ws;                                  // alias 0..16
    ushort* WT   = (ushort*)(ws + (size_t)10 * 1024 * 1024);
    ushort* WTO  = (ushort*)(ws + (size_t)16 * 1024 * 1024);
    ushort* Qf   = (ushort*)(ws + (size_t)40 * 1024 * 1024);
    ushort* Kf   = (ushort*)(ws + (size_t)56 * 1024 * 1024);
    ushort* VfT  = (ushort*)(ws + (size_t)64 * 1024 * 1024);

    prep_kernel<<<4480, 256, 0, stream>>>(
        x, Xf,
        q_qw, q_sc, q_qz, k_qw, k_sc, k_qz, v_qw, v_sc, v_qz, WT);

    qkv12_kernel<<<768, 256, 0, stream>>>(
        Xf, WT, q_b, k_b, v_b, cosb, sinb, Qf, Kf, VfT);

    prep2_kernel<<<1280, 256, 0, stream>>>(o_qw, o_sc, o_qz, WTO);

    attn_mfma_kernel<<<dim3(NH, S_LEN / 64), 256, 0, stream>>>(Qf, Kf, VfT, AOf);

    oproj9_kernel<<<320, 256, 0, stream>>>(AOf, WTO, out);
}